// Round 1
// baseline (2571.845 us; speedup 1.0000x reference)
//
#include <hip/hip_runtime.h>
#include <math.h>

// TheRecurrentNet: B=512, K=16, H=500, A=64, nc=15.
// Factored: pair@fc2_w = P[r1]+Q[r2] with P=s1@fc2_w[:500], Q=s1@fc2_w[500:].
// fc3|fc4 weights concatenated into one N=600 GEMM.
// All f32 this round (correctness baseline); chunked (8 x 1024 pairs) to keep
// ws at ~173 MB.

#define EPSF 1e-5f

// ---------------- block-wide sum over 256 threads ----------------
__device__ __forceinline__ float block_sum256(float v) {
  __shared__ float red[4];
  int lane = threadIdx.x & 63;
  int wid  = threadIdx.x >> 6;
#pragma unroll
  for (int off = 32; off > 0; off >>= 1) v += __shfl_down(v, off);
  __syncthreads();                  // protect red[] from a previous call's readers
  if (lane == 0) red[wid] = v;
  __syncthreads();
  return red[0] + red[1] + red[2] + red[3];
}

// ---------------- generic f32 GEMM: C[M,N] = A[M,K] @ B[K,N] (+bias) (*rowscale) ---
// 128x128 tile, BK=16, 256 threads, 8x8 per thread (4+64 split for bank-friendly reads)
__global__ __launch_bounds__(256) void gemm128(
    const float* __restrict__ A, const float* __restrict__ B,
    const float* __restrict__ bias, const float* __restrict__ rowscale,
    float* __restrict__ C, int M, int N, int K)
{
  __shared__ float As[16][132];   // padded: store conflicts -> 2-way (free)
  __shared__ float Bs[16][128];
  const int tid = threadIdx.x;
  const int tx = tid & 15, ty = tid >> 4;
  const int row0 = blockIdx.y * 128, col0 = blockIdx.x * 128;
  float acc[8][8];
#pragma unroll
  for (int i = 0; i < 8; ++i)
#pragma unroll
    for (int j = 0; j < 8; ++j) acc[i][j] = 0.f;

  const int nkt = (K + 15) >> 4;
  for (int kt = 0; kt < nkt; ++kt) {
    const int k0 = kt << 4;
    // A tile: 128 rows x 16 k, one float4 per thread per half (K%4==0 always)
#pragma unroll
    for (int h = 0; h < 2; ++h) {
      int i = tid + h * 256;
      int m = i >> 2, kk = (i & 3) << 2;
      int gm = row0 + m, gk = k0 + kk;
      float4 v = make_float4(0.f, 0.f, 0.f, 0.f);
      if (gm < M && gk < K) v = *reinterpret_cast<const float4*>(A + (size_t)gm * K + gk);
      As[kk + 0][m] = v.x; As[kk + 1][m] = v.y; As[kk + 2][m] = v.z; As[kk + 3][m] = v.w;
    }
    // B tile: 16 k x 128 cols (N%4==0 always)
#pragma unroll
    for (int h = 0; h < 2; ++h) {
      int i = tid + h * 256;
      int kk = i >> 5, n = (i & 31) << 2;
      int gk = k0 + kk, gn = col0 + n;
      float4 v = make_float4(0.f, 0.f, 0.f, 0.f);
      if (gk < K && gn < N) v = *reinterpret_cast<const float4*>(B + (size_t)gk * N + gn);
      *reinterpret_cast<float4*>(&Bs[kk][n]) = v;
    }
    __syncthreads();
#pragma unroll
    for (int kk = 0; kk < 16; ++kk) {
      float4 a0 = *reinterpret_cast<const float4*>(&As[kk][ty * 4]);
      float4 a1 = *reinterpret_cast<const float4*>(&As[kk][ty * 4 + 64]);
      float4 b0 = *reinterpret_cast<const float4*>(&Bs[kk][tx * 4]);
      float4 b1 = *reinterpret_cast<const float4*>(&Bs[kk][tx * 4 + 64]);
      float av[8] = {a0.x, a0.y, a0.z, a0.w, a1.x, a1.y, a1.z, a1.w};
      float bv[8] = {b0.x, b0.y, b0.z, b0.w, b1.x, b1.y, b1.z, b1.w};
#pragma unroll
      for (int i = 0; i < 8; ++i)
#pragma unroll
        for (int j = 0; j < 8; ++j) acc[i][j] += av[i] * bv[j];
    }
    __syncthreads();
  }
#pragma unroll
  for (int i = 0; i < 8; ++i) {
    int gm = row0 + ty * 4 + ((i >> 2) << 6) + (i & 3);
    if (gm >= M) continue;
    float rs = rowscale ? rowscale[gm] : 1.f;
#pragma unroll
    for (int j = 0; j < 8; ++j) {
      int gn = col0 + tx * 4 + ((j >> 2) << 6) + (j & 3);
      if (gn < N) {
        float v = acc[i][j];
        if (bias) v += bias[gn];
        C[(size_t)gm * N + gn] = v * rs;
      }
    }
  }
}

// ---------------- LayerNorm over rows (cols<=512), optional relu -------------
template <int ACT>  // 0 = none, 1 = relu
__global__ __launch_bounds__(256) void ln_rows(
    const float* __restrict__ X, float* __restrict__ Y,
    const float* __restrict__ g, const float* __restrict__ b,
    int cols, int ldx, int ldy)
{
  int row = blockIdx.x;
  const float* x = X + (size_t)row * ldx;
  float* y = Y + (size_t)row * ldy;
  __shared__ float xs[512];
  float s = 0.f;
  for (int k = threadIdx.x; k < cols; k += 256) { float v = x[k]; xs[k] = v; s += v; }
  float mu = block_sum256(s) / cols;
  float s2 = 0.f;
  for (int k = threadIdx.x; k < cols; k += 256) { float d = xs[k] - mu; s2 += d * d; }
  float rstd = rsqrtf(block_sum256(s2) / cols + EPSF);
  for (int k = threadIdx.x; k < cols; k += 256) {
    float v = (xs[k] - mu) * rstd * g[k] + b[k];
    if (ACT == 1) v = fmaxf(v, 0.f);
    y[k] = v;
  }
}

// ---------------- concat_a[r] = [state[r], a[r>>4]] --------------------------
__global__ __launch_bounds__(256) void build_concat(
    const float* __restrict__ state, const float* __restrict__ a, float* __restrict__ cat)
{
  int r = blockIdx.x;
  int b = r >> 4;
  const float4* s4 = reinterpret_cast<const float4*>(state + (size_t)r * 500);
  const float4* a4 = reinterpret_cast<const float4*>(a + (size_t)b * 500);
  float4* c4 = reinterpret_cast<float4*>(cat + (size_t)r * 1000);
  for (int i = threadIdx.x; i < 125; i += 256) { c4[i] = s4[i]; c4[125 + i] = a4[i]; }
}

// ---------------- total[r] = [s1[r], esum[r]] --------------------------------
__global__ __launch_bounds__(256) void build_total(
    const float* __restrict__ s1, const float* __restrict__ esum, float* __restrict__ tot)
{
  int r = blockIdx.x;
  const float4* a4 = reinterpret_cast<const float4*>(s1 + (size_t)r * 500);
  const float4* b4 = reinterpret_cast<const float4*>(esum + (size_t)r * 500);
  float4* c4 = reinterpret_cast<float4*>(tot + (size_t)r * 1000);
  for (int i = threadIdx.x; i < 125; i += 256) { c4[i] = a4[i]; c4[125 + i] = b4[i]; }
}

// ---------------- att_a[r] = sigmoid(dot(cat[r], w3) + b3) -------------------
__global__ __launch_bounds__(256) void dot_sig(
    const float* __restrict__ cat, const float* __restrict__ w3,
    const float* __restrict__ b3, float* __restrict__ atta)
{
  int r = blockIdx.x;
  const float* x = cat + (size_t)r * 1000;
  float s = 0.f;
  for (int k = threadIdx.x; k < 1000; k += 256) s += x[k] * w3[k];
  s = block_sum256(s);
  if (threadIdx.x == 0) atta[r] = 1.f / (1.f + expf(-(s + b3[0])));
}

// -------- core chunk row = relu(LN(P[r1] + Q[r2], ln2)) ----------------------
__global__ __launch_bounds__(256) void core_build(
    const float* __restrict__ PQ, float* __restrict__ core,
    const float* __restrict__ g2, const float* __restrict__ b2, int c0)
{
  int cr = blockIdx.x;                 // 0..15359 within chunk
  int pp = cr / 15, j = cr - pp * 15;
  int gp = c0 + pp;                    // global (b,i) pair = row r1
  int i = gp & 15;
  int col = j + (j >= i);              // idx[i][j]
  int r2 = (gp & ~15) | col;
  const float* p = PQ + (size_t)gp * 1000;        // P part
  const float* q = PQ + (size_t)r2 * 1000 + 500;  // Q part
  __shared__ float xs[512];
  float s = 0.f;
  for (int k = threadIdx.x; k < 500; k += 256) { float v = p[k] + q[k]; xs[k] = v; s += v; }
  float mu = block_sum256(s) / 500.f;
  float s2 = 0.f;
  for (int k = threadIdx.x; k < 500; k += 256) { float d = xs[k] - mu; s2 += d * d; }
  float rstd = rsqrtf(block_sum256(s2) / 500.f + EPSF);
  float* o = core + (size_t)cr * 500;
  for (int k = threadIdx.x; k < 500; k += 256)
    o[k] = fmaxf((xs[k] - mu) * rstd * g2[k] + b2[k], 0.f);
}

// -------- att_c[cr] = sigmoid(dot(tanh(LN(v[cr,500:600], ln4)), w5) + b5) ----
__global__ __launch_bounds__(256) void att_row(
    const float* __restrict__ V, float* __restrict__ attc,
    const float* __restrict__ g4, const float* __restrict__ b4,
    const float* __restrict__ w5, const float* __restrict__ b5)
{
  int cr = blockIdx.x;
  const float* x = V + (size_t)cr * 600 + 500;
  __shared__ float xs[128];
  float s = 0.f;
  for (int k = threadIdx.x; k < 100; k += 256) { float v = x[k]; xs[k] = v; s += v; }
  float mu = block_sum256(s) / 100.f;
  float s2 = 0.f;
  for (int k = threadIdx.x; k < 100; k += 256) { float d = xs[k] - mu; s2 += d * d; }
  float rstd = rsqrtf(block_sum256(s2) / 100.f + EPSF);
  float dot = 0.f;
  for (int k = threadIdx.x; k < 100; k += 256) {
    float t = tanhf((xs[k] - mu) * rstd * g4[k] + b4[k]);
    dot += t * w5[k];
  }
  float d = block_sum256(dot);
  if (threadIdx.x == 0) attc[cr] = 1.f / (1.f + expf(-(d + b5[0])));
}

// -------- esum[gp] = sum_j ctx[pp*15+j] * att_c[pp*15+j] ---------------------
__global__ __launch_bounds__(256) void reduce_esum(
    const float* __restrict__ V, const float* __restrict__ attc,
    float* __restrict__ esum, int c0)
{
  int pp = blockIdx.x;
  int gp = c0 + pp;
  __shared__ float av[15];
  if (threadIdx.x < 15) av[threadIdx.x] = attc[pp * 15 + threadIdx.x];
  __syncthreads();
  for (int n = threadIdx.x; n < 500; n += 256) {
    float acc = 0.f;
#pragma unroll
    for (int j = 0; j < 15; ++j)
      acc += V[(size_t)(pp * 15 + j) * 600 + n] * av[j];
    esum[(size_t)gp * 500 + n] = acc;
  }
}

// -------- weight rearrangement: B2 = [fc2_w[:500] | fc2_w[500:]], B34 = [fc3 | fc4]
__global__ __launch_bounds__(256) void setup_weights(
    const float* __restrict__ fc2w, const float* __restrict__ fc2b,
    const float* __restrict__ fc3w, const float* __restrict__ fc3b,
    const float* __restrict__ fc4w, const float* __restrict__ fc4b,
    float* __restrict__ B2, float* __restrict__ bias2,
    float* __restrict__ B34, float* __restrict__ bias34)
{
  int k = blockIdx.x;
  if (k < 500) {
    for (int n = threadIdx.x; n < 1000; n += 256)
      B2[(size_t)k * 1000 + n] = (n < 500) ? fc2w[(size_t)k * 500 + n]
                                           : fc2w[(size_t)(500 + k) * 500 + (n - 500)];
    for (int n = threadIdx.x; n < 600; n += 256)
      B34[(size_t)k * 600 + n] = (n < 500) ? fc3w[(size_t)k * 500 + n]
                                           : fc4w[(size_t)k * 100 + (n - 500)];
  } else {
    for (int n = threadIdx.x; n < 1000; n += 256) bias2[n] = (n < 500) ? fc2b[n] : 0.f;
    for (int n = threadIdx.x; n < 600; n += 256) bias34[n] = (n < 500) ? fc3b[n] : fc4b[n - 500];
  }
}

extern "C" void kernel_launch(void* const* d_in, const int* in_sizes, int n_in,
                              void* d_out, int out_size, void* d_ws, size_t ws_size,
                              hipStream_t stream)
{
  const float* state    = (const float*)d_in[0];
  const float* actions  = (const float*)d_in[1];
  const float* ac_fc1_w = (const float*)d_in[2];
  const float* ac_fc1_b = (const float*)d_in[3];
  const float* ac_ln1_g = (const float*)d_in[4];
  const float* ac_ln1_b = (const float*)d_in[5];
  const float* ac_fc2_w = (const float*)d_in[6];
  const float* ac_fc2_b = (const float*)d_in[7];
  const float* ac_lnf2_w= (const float*)d_in[8];
  const float* ac_lnf2_b= (const float*)d_in[9];
  const float* ac_fc3_w = (const float*)d_in[10];
  const float* ac_fc3_b = (const float*)d_in[11];
  const float* fc1_w = (const float*)d_in[12];
  const float* fc1_b = (const float*)d_in[13];
  const float* ln1_g = (const float*)d_in[14];
  const float* ln1_b = (const float*)d_in[15];
  const float* fc2_w = (const float*)d_in[16];
  const float* fc2_b = (const float*)d_in[17];
  const float* ln2_g = (const float*)d_in[18];
  const float* ln2_b = (const float*)d_in[19];
  const float* fc3_w = (const float*)d_in[20];
  const float* fc3_b = (const float*)d_in[21];
  const float* ln3_g = (const float*)d_in[22];
  const float* ln3_b = (const float*)d_in[23];
  const float* fc4_w = (const float*)d_in[24];
  const float* fc4_b = (const float*)d_in[25];
  const float* ln4_g = (const float*)d_in[26];
  const float* ln4_b = (const float*)d_in[27];
  const float* fc5_w = (const float*)d_in[28];
  const float* fc5_b = (const float*)d_in[29];
  const float* fc6_w = (const float*)d_in[30];
  const float* fc6_b = (const float*)d_in[31];
  const float* ln6_g = (const float*)d_in[32];
  const float* ln6_b = (const float*)d_in[33];
  float* out = (float*)d_out;
  float* ws  = (float*)d_ws;

  // ws layout (floats) — total 43,321,600 floats = 173.3 MB
  float* cat_core = ws;              // 8,192,000  concat_a, then core chunk (7.68M)
  float* t_buf    = ws + 8192000;    // 4,096,000  t1 / s1pre / hpre
  float* s2_buf   = ws + 12288000;   // 4,096,000  state2
  float* s1_buf   = ws + 16384000;   // 4,096,000  s1
  float* PQ_tot   = ws + 20480000;   // 8,192,000  PQ, then total
  float* v_buf    = ws + 28672000;   // 9,216,000  v chunk (15360 x 600)
  float* esum     = ws + 37888000;   // 4,096,000
  float* tmp_a    = ws + 41984000;   //   256,000
  float* a_buf    = ws + 42240000;   //   256,000
  float* att_a    = ws + 42496000;   //     8,192
  float* B2       = ws + 42504192;   //   500,000  (500 x 1000)
  float* bias2    = ws + 43004192;   //     1,024
  float* B34      = ws + 43005216;   //   300,000  (500 x 600)
  float* bias34   = ws + 43305216;   //     1,024
  float* att_c    = ws + 43306240;   //    15,360

  dim3 blk(256);
  setup_weights<<<501, blk, 0, stream>>>(fc2_w, fc2_b, fc3_w, fc3_b, fc4_w, fc4_b,
                                         B2, bias2, B34, bias34);
  // a = LN(actions @ ac_fc1_w + b)
  gemm128<<<dim3(4, 4), blk, 0, stream>>>(actions, ac_fc1_w, ac_fc1_b, nullptr, tmp_a, 512, 500, 64);
  ln_rows<0><<<512, blk, 0, stream>>>(tmp_a, a_buf, ac_ln1_g, ac_ln1_b, 500, 500, 500);
  build_concat<<<8192, blk, 0, stream>>>(state, a_buf, cat_core);
  // t1 = cat @ ac_fc2_w + b ; att_a = sigmoid(cat @ ac_fc3_w + b)
  gemm128<<<dim3(4, 64), blk, 0, stream>>>(cat_core, ac_fc2_w, ac_fc2_b, nullptr, t_buf, 8192, 500, 1000);
  dot_sig<<<8192, blk, 0, stream>>>(cat_core, ac_fc3_w, ac_fc3_b, att_a);
  // state2 = (t1 @ ac_lnf2_w + b) * att_a
  gemm128<<<dim3(4, 64), blk, 0, stream>>>(t_buf, ac_lnf2_w, ac_lnf2_b, att_a, s2_buf, 8192, 500, 500);
  // s1 = relu(LN(state2 @ fc1_w + b, ln1))
  gemm128<<<dim3(4, 64), blk, 0, stream>>>(s2_buf, fc1_w, fc1_b, nullptr, t_buf, 8192, 500, 500);
  ln_rows<1><<<8192, blk, 0, stream>>>(t_buf, s1_buf, ln1_g, ln1_b, 500, 500, 500);
  // PQ = s1 @ [fc2_w[:500] | fc2_w[500:]]  (bias only on P half)
  gemm128<<<dim3(8, 64), blk, 0, stream>>>(s1_buf, B2, bias2, nullptr, PQ_tot, 8192, 1000, 500);

  for (int c = 0; c < 8; ++c) {
    int c0 = c * 1024;
    core_build<<<15360, blk, 0, stream>>>(PQ_tot, cat_core, ln2_g, ln2_b, c0);
    // v = core @ [fc3_w | fc4_w] + [b3 | b4]   (15360 x 600)
    gemm128<<<dim3(5, 120), blk, 0, stream>>>(cat_core, B34, bias34, nullptr, v_buf, 15360, 600, 500);
    // ctx = relu(LN(v[:, :500], ln3)) in place
    ln_rows<1><<<15360, blk, 0, stream>>>(v_buf, v_buf, ln3_g, ln3_b, 500, 600, 600);
    att_row<<<15360, blk, 0, stream>>>(v_buf, att_c, ln4_g, ln4_b, fc5_w, fc5_b);
    reduce_esum<<<1024, blk, 0, stream>>>(v_buf, att_c, esum, c0);
  }

  build_total<<<8192, blk, 0, stream>>>(s1_buf, esum, PQ_tot);
  gemm128<<<dim3(4, 64), blk, 0, stream>>>(PQ_tot, fc6_w, fc6_b, nullptr, t_buf, 8192, 500, 1000);
  ln_rows<0><<<8192, blk, 0, stream>>>(t_buf, out, ln6_g, ln6_b, 500, 500, 500);
}

// Round 2
// 934.898 us; speedup vs baseline: 2.7509x; 2.7509x over previous
//
#include <hip/hip_runtime.h>
#include <math.h>

// TheRecurrentNet: B=512, K=16, H=500, A=64, nc=15.
// Round 2: bf16 MFMA GEMMs (m97 structure), transposed+padded weights,
// fused chunk tail (ln3+att+esum in one kernel). f32 only for LN stats,
// accumulators, and the tiny first GEMM.

#define EPSF 1e-5f
typedef unsigned short u16;
typedef unsigned int u32;

typedef __bf16 bf16x8 __attribute__((ext_vector_type(8)));
typedef float f32x4 __attribute__((ext_vector_type(4)));

__device__ __forceinline__ float bf2f(u16 u) {
  return __builtin_bit_cast(float, (u32)u << 16);
}
__device__ __forceinline__ u16 f2bf(float f) {
  u32 u = __builtin_bit_cast(u32, f);
  return (u16)((u + 0x7FFFu + ((u >> 16) & 1u)) >> 16);   // RNE
}

#define GLOAD16(g, l) __builtin_amdgcn_global_load_lds( \
    (__attribute__((address_space(1))) u32*)(g), \
    (__attribute__((address_space(3))) u32*)(l), 16, 0, 0)

// ---------------- block-wide sum over 256 threads ----------------
__device__ __forceinline__ float block_sum256(float v) {
  __shared__ float red[4];
  int lane = threadIdx.x & 63;
  int wid  = threadIdx.x >> 6;
#pragma unroll
  for (int off = 32; off > 0; off >>= 1) v += __shfl_down(v, off);
  __syncthreads();
  if (lane == 0) red[wid] = v;
  __syncthreads();
  return red[0] + red[1] + red[2] + red[3];
}

// ======================= bf16 MFMA GEMM =======================
// C[M,Npad] = A[M,K](bf16) @ Bt[Npad,K]^T(bf16) + bias, optional *rowscale.
// lda = ldb = K. M%128==0, Npad%128==0, K%32==0. 128x128 tile, BK=32,
// 4 waves each computing a 64x64 quadrant as 4x4 16x16x32 fragments.
template <typename TOUT>
__global__ __launch_bounds__(256) void gemm_mfma(
    const u16* __restrict__ A, const u16* __restrict__ Bt,
    const float* __restrict__ bias, const float* __restrict__ rowscale,
    TOUT* __restrict__ C, int M, int Npad, int K)
{
  __shared__ __align__(16) u16 As[128 * 32];   // [row][k]
  __shared__ __align__(16) u16 Bs[128 * 32];   // [col][k]
  const int tid = threadIdx.x;
  const int lane = tid & 63, wid = tid >> 6;
  const int wr = wid >> 1, wc = wid & 1;
  const size_t row0 = (size_t)blockIdx.y * 128, col0 = (size_t)blockIdx.x * 128;

  f32x4 acc[4][4] = {};

  // staging: slot s = h*256 + tid covers ushorts [s*8, s*8+8); row=s>>2, ch=s&3
  const int s_row = tid >> 2, s_ch = tid & 3;
  const u16* gA0 = A + (row0 + s_row) * (size_t)K + s_ch * 8;
  const u16* gA1 = gA0 + (size_t)64 * K;
  const u16* gB0 = Bt + (col0 + s_row) * (size_t)K + s_ch * 8;
  const u16* gB1 = gB0 + (size_t)64 * K;
  u16* lA0 = As + tid * 8;
  u16* lA1 = As + 2048 + tid * 8;
  u16* lB0 = Bs + tid * 8;
  u16* lB1 = Bs + 2048 + tid * 8;

  const int fr = lane & 15, fq = lane >> 4;
  const u16* pAf = As + (wr * 64 + fr) * 32 + fq * 8;
  const u16* pBf = Bs + (wc * 64 + fr) * 32 + fq * 8;

  for (int k0 = 0; k0 < K; k0 += 32) {
    GLOAD16(gA0 + k0, lA0);
    GLOAD16(gA1 + k0, lA1);
    GLOAD16(gB0 + k0, lB0);
    GLOAD16(gB1 + k0, lB1);
    __syncthreads();   // drains vmcnt before reads
    bf16x8 af[4], bfv[4];
#pragma unroll
    for (int m = 0; m < 4; ++m) af[m] = *reinterpret_cast<const bf16x8*>(pAf + m * 16 * 32);
#pragma unroll
    for (int n = 0; n < 4; ++n) bfv[n] = *reinterpret_cast<const bf16x8*>(pBf + n * 16 * 32);
#pragma unroll
    for (int m = 0; m < 4; ++m)
#pragma unroll
      for (int n = 0; n < 4; ++n)
        acc[m][n] = __builtin_amdgcn_mfma_f32_16x16x32_bf16(af[m], bfv[n], acc[m][n], 0, 0, 0);
    __syncthreads();   // reads done before next stage
  }

  // epilogue: C/D layout col=lane&15, row=(lane>>4)*4+reg
  const int cl = lane & 15, rg = lane >> 4;
#pragma unroll
  for (int m = 0; m < 4; ++m) {
#pragma unroll
    for (int n = 0; n < 4; ++n) {
      size_t col = col0 + wc * 64 + n * 16 + cl;
      float bv = bias[col];
#pragma unroll
      for (int r = 0; r < 4; ++r) {
        size_t row = row0 + wr * 64 + m * 16 + rg * 4 + r;
        float v = acc[m][n][r] + bv;
        if (rowscale) v *= rowscale[row];
        if constexpr (sizeof(TOUT) == 2) C[row * Npad + col] = f2bf(v);
        else                             C[row * Npad + col] = v;
      }
    }
  }
}

// ---------------- small f32 GEMM (kept for actions @ ac_fc1_w) ---------------
__global__ __launch_bounds__(256) void gemm128(
    const float* __restrict__ A, const float* __restrict__ B,
    const float* __restrict__ bias, const float* __restrict__ rowscale,
    float* __restrict__ C, int M, int N, int K)
{
  __shared__ float As[16][132];
  __shared__ float Bs[16][128];
  const int tid = threadIdx.x;
  const int tx = tid & 15, ty = tid >> 4;
  const int row0 = blockIdx.y * 128, col0 = blockIdx.x * 128;
  float acc[8][8];
#pragma unroll
  for (int i = 0; i < 8; ++i)
#pragma unroll
    for (int j = 0; j < 8; ++j) acc[i][j] = 0.f;

  const int nkt = (K + 15) >> 4;
  for (int kt = 0; kt < nkt; ++kt) {
    const int k0 = kt << 4;
#pragma unroll
    for (int h = 0; h < 2; ++h) {
      int i = tid + h * 256;
      int m = i >> 2, kk = (i & 3) << 2;
      int gm = row0 + m, gk = k0 + kk;
      float4 v = make_float4(0.f, 0.f, 0.f, 0.f);
      if (gm < M && gk < K) v = *reinterpret_cast<const float4*>(A + (size_t)gm * K + gk);
      As[kk + 0][m] = v.x; As[kk + 1][m] = v.y; As[kk + 2][m] = v.z; As[kk + 3][m] = v.w;
    }
#pragma unroll
    for (int h = 0; h < 2; ++h) {
      int i = tid + h * 256;
      int kk = i >> 5, n = (i & 31) << 2;
      int gk = k0 + kk, gn = col0 + n;
      float4 v = make_float4(0.f, 0.f, 0.f, 0.f);
      if (gk < K && gn < N) v = *reinterpret_cast<const float4*>(B + (size_t)gk * N + gn);
      *reinterpret_cast<float4*>(&Bs[kk][n]) = v;
    }
    __syncthreads();
#pragma unroll
    for (int kk = 0; kk < 16; ++kk) {
      float4 a0 = *reinterpret_cast<const float4*>(&As[kk][ty * 4]);
      float4 a1 = *reinterpret_cast<const float4*>(&As[kk][ty * 4 + 64]);
      float4 b0 = *reinterpret_cast<const float4*>(&Bs[kk][tx * 4]);
      float4 b1 = *reinterpret_cast<const float4*>(&Bs[kk][tx * 4 + 64]);
      float av[8] = {a0.x, a0.y, a0.z, a0.w, a1.x, a1.y, a1.z, a1.w};
      float bv[8] = {b0.x, b0.y, b0.z, b0.w, b1.x, b1.y, b1.z, b1.w};
#pragma unroll
      for (int i = 0; i < 8; ++i)
#pragma unroll
        for (int j = 0; j < 8; ++j) acc[i][j] += av[i] * bv[j];
    }
    __syncthreads();
  }
#pragma unroll
  for (int i = 0; i < 8; ++i) {
    int gm = row0 + ty * 4 + ((i >> 2) << 6) + (i & 3);
    if (gm >= M) continue;
    float rs = rowscale ? rowscale[gm] : 1.f;
#pragma unroll
    for (int j = 0; j < 8; ++j) {
      int gn = col0 + tx * 4 + ((j >> 2) << 6) + (j & 3);
      if (gn < N) {
        float v = acc[i][j];
        if (bias) v += bias[gn];
        C[(size_t)gm * N + gn] = v * rs;
      }
    }
  }
}

// ---------------- LayerNorm over rows, f32 in, f32/bf16 out ------------------
template <int ACT, typename TOUT>  // ACT: 0=none, 1=relu
__global__ __launch_bounds__(256) void ln_rows(
    const float* __restrict__ X, TOUT* __restrict__ Y,
    const float* __restrict__ g, const float* __restrict__ b,
    int cols, int ldx, int ldy, int padto)
{
  int row = blockIdx.x;
  const float* x = X + (size_t)row * ldx;
  TOUT* y = Y + (size_t)row * ldy;
  __shared__ float xs[512];
  float s = 0.f;
  for (int k = threadIdx.x; k < cols; k += 256) { float v = x[k]; xs[k] = v; s += v; }
  float mu = block_sum256(s) / cols;
  float s2 = 0.f;
  for (int k = threadIdx.x; k < cols; k += 256) { float d = xs[k] - mu; s2 += d * d; }
  float rstd = rsqrtf(block_sum256(s2) / cols + EPSF);
  for (int k = threadIdx.x; k < cols; k += 256) {
    float v = (xs[k] - mu) * rstd * g[k] + b[k];
    if (ACT == 1) v = fmaxf(v, 0.f);
    if constexpr (sizeof(TOUT) == 2) y[k] = f2bf(v); else y[k] = v;
  }
  for (int k = cols + threadIdx.x; k < padto; k += 256) y[k] = (TOUT)0;
}

// ---------------- cat[r] = [bf16(state[r]) | a[r>>4] | 0pad] -----------------
__global__ __launch_bounds__(256) void build_concat(
    const float* __restrict__ state, const u16* __restrict__ a, u16* __restrict__ cat)
{
  int r = blockIdx.x, t = threadIdx.x;
  int b = r >> 4;
  u16* c = cat + (size_t)r * 1024;
  if (t < 125) {
    float4 v = *reinterpret_cast<const float4*>(state + (size_t)r * 500 + t * 4);
    ushort4 o; o.x = f2bf(v.x); o.y = f2bf(v.y); o.z = f2bf(v.z); o.w = f2bf(v.w);
    *reinterpret_cast<ushort4*>(c + t * 4) = o;
    *reinterpret_cast<ushort4*>(c + 500 + t * 4) =
        *reinterpret_cast<const ushort4*>(a + (size_t)b * 512 + t * 4);
  }
  if (t < 24) c[1000 + t] = 0;
}

// ---------------- total[r] = [s1[r] | 0 | bf16(esum[r]) | 0] -----------------
__global__ __launch_bounds__(256) void build_total(
    const u16* __restrict__ s1, const float* __restrict__ esum, u16* __restrict__ tot)
{
  int r = blockIdx.x, t = threadIdx.x;
  u16* c = tot + (size_t)r * 1024;
  if (t < 125) {
    *reinterpret_cast<ushort4*>(c + t * 4) =
        *reinterpret_cast<const ushort4*>(s1 + (size_t)r * 512 + t * 4);
    float4 v = *reinterpret_cast<const float4*>(esum + (size_t)r * 500 + t * 4);
    ushort4 o; o.x = f2bf(v.x); o.y = f2bf(v.y); o.z = f2bf(v.z); o.w = f2bf(v.w);
    *reinterpret_cast<ushort4*>(c + 512 + t * 4) = o;
  }
  if (t < 12) { c[500 + t] = 0; c[1012 + t] = 0; }
}

// ---------------- att_a[r] = sigmoid(dot(cat[r,0:1000], w3) + b3) ------------
__global__ __launch_bounds__(256) void dot_sig(
    const u16* __restrict__ cat, const float* __restrict__ w3,
    const float* __restrict__ b3, float* __restrict__ atta)
{
  int r = blockIdx.x, t = threadIdx.x;
  const u16* x = cat + (size_t)r * 1024;
  float s = 0.f;
  if (t < 125) {
    ushort4 u0 = *reinterpret_cast<const ushort4*>(x + t * 8);
    ushort4 u1 = *reinterpret_cast<const ushort4*>(x + t * 8 + 4);
    float4 w0 = *reinterpret_cast<const float4*>(w3 + t * 8);
    float4 w1 = *reinterpret_cast<const float4*>(w3 + t * 8 + 4);
    s = bf2f(u0.x) * w0.x + bf2f(u0.y) * w0.y + bf2f(u0.z) * w0.z + bf2f(u0.w) * w0.w
      + bf2f(u1.x) * w1.x + bf2f(u1.y) * w1.y + bf2f(u1.z) * w1.z + bf2f(u1.w) * w1.w;
  }
  s = block_sum256(s);
  if (t == 0) atta[r] = 1.f / (1.f + expf(-(s + b3[0])));
}

// -------- core chunk row = relu(LN(P[r1] + Q[r2], ln2)), bf16 out ------------
__global__ __launch_bounds__(256) void core_build(
    const float* __restrict__ PQ, u16* __restrict__ core,
    const float* __restrict__ g2, const float* __restrict__ b2, int c0)
{
  int cr = blockIdx.x, t = threadIdx.x;
  int pp = cr / 15, j = cr - pp * 15;
  int gp = c0 + pp;
  int i = gp & 15;
  int col = j + (j >= i);
  int r2 = (gp & ~15) | col;
  const float* pP = PQ + (size_t)gp * 1024;
  const float* pQ = PQ + (size_t)r2 * 1024 + 512;
  __shared__ float xs[512];
  float s = 0.f, s2 = 0.f;
  if (t < 125) {
    float4 a = *reinterpret_cast<const float4*>(pP + t * 4);
    float4 q = *reinterpret_cast<const float4*>(pQ + t * 4);
    float4 v = make_float4(a.x + q.x, a.y + q.y, a.z + q.z, a.w + q.w);
    *reinterpret_cast<float4*>(&xs[t * 4]) = v;
    s = v.x + v.y + v.z + v.w;
    s2 = v.x * v.x + v.y * v.y + v.z * v.z + v.w * v.w;
  }
  float S = block_sum256(s), S2 = block_sum256(s2);
  float mu = S / 500.f;
  float rstd = rsqrtf(S2 / 500.f - mu * mu + EPSF);
  u16* o = core + (size_t)cr * 512;
  if (t < 125) {
    float4 v = *reinterpret_cast<const float4*>(&xs[t * 4]);
    ushort4 w;
    w.x = f2bf(fmaxf((v.x - mu) * rstd * g2[t * 4 + 0] + b2[t * 4 + 0], 0.f));
    w.y = f2bf(fmaxf((v.y - mu) * rstd * g2[t * 4 + 1] + b2[t * 4 + 1], 0.f));
    w.z = f2bf(fmaxf((v.z - mu) * rstd * g2[t * 4 + 2] + b2[t * 4 + 2], 0.f));
    w.w = f2bf(fmaxf((v.w - mu) * rstd * g2[t * 4 + 3] + b2[t * 4 + 3], 0.f));
    *reinterpret_cast<ushort4*>(o + t * 4) = w;
  }
  if (t < 12) o[500 + t] = 0;
}

// -------- fused ln3+att+esum: one block per (b,i) pair, 15 rows --------------
__global__ __launch_bounds__(256) void chunk_post(
    const u16* __restrict__ V,
    const float* __restrict__ g3, const float* __restrict__ b3,
    const float* __restrict__ g4, const float* __restrict__ b4,
    const float* __restrict__ w5, const float* __restrict__ b5,
    float* __restrict__ esum, int c0)
{
  int pp = blockIdx.x, t = threadIdx.x;
  int gp = c0 + pp;
  __shared__ float xs[512], accs[512];
  if (t < 128) *reinterpret_cast<float4*>(&accs[t * 4]) = make_float4(0.f, 0.f, 0.f, 0.f);
  __syncthreads();
  for (int j = 0; j < 15; ++j) {
    const u16* vr = V + (size_t)(pp * 15 + j) * 640;
    float s = 0.f, s2 = 0.f;
    for (int k = t; k < 500; k += 256) {
      float v = bf2f(vr[k]); xs[k] = v; s += v; s2 += v * v;
    }
    float S = block_sum256(s), S2 = block_sum256(s2);
    float mu = S / 500.f;
    float rstd = rsqrtf(S2 / 500.f - mu * mu + EPSF);
    // attention scalar from cols 512..612 (fc4 part)
    float y = (t < 100) ? bf2f(vr[512 + t]) : 0.f;
    float SA = block_sum256(y), SA2 = block_sum256(y * y);
    float mu4 = SA / 100.f;
    float rstd4 = rsqrtf(SA2 / 100.f - mu4 * mu4 + EPSF);
    float dv = (t < 100) ? tanhf((y - mu4) * rstd4 * g4[t] + b4[t]) * w5[t] : 0.f;
    float D = block_sum256(dv);
    float att = 1.f / (1.f + expf(-(D + b5[0])));
    for (int k = t; k < 500; k += 256)
      accs[k] += fmaxf((xs[k] - mu) * rstd * g3[k] + b3[k], 0.f) * att;
  }
  __syncthreads();
  if (t < 125) {
    float4 v = *reinterpret_cast<const float4*>(&accs[t * 4]);
    *reinterpret_cast<float4*>(esum + (size_t)gp * 500 + t * 4) = v;
  }
}

// -------- transpose+pack: dst[(n+nOff)*ldDst + kOff + k] = bf16(src[k*srcLd+n])
__global__ void transpose_pack(
    const float* __restrict__ src, int K, int N, int srcLd,
    u16* __restrict__ dst, int ldDst, int nOff, int kOff)
{
  __shared__ float tl[32][33];
  int tx = threadIdx.x, ty = threadIdx.y;   // 32 x 8
  int k0 = blockIdx.y * 32, n0 = blockIdx.x * 32;
#pragma unroll
  for (int r = 0; r < 4; ++r) {
    int row = k0 + ty + r * 8;
    if (row < K && n0 + tx < N) tl[ty + r * 8][tx] = src[(size_t)row * srcLd + n0 + tx];
  }
  __syncthreads();
#pragma unroll
  for (int r = 0; r < 4; ++r) {
    int n = n0 + ty + r * 8, k = k0 + tx;
    if (n < N && k < K)
      dst[(size_t)(n + nOff) * ldDst + kOff + k] = f2bf(tl[tx][ty + r * 8]);
  }
}

// -------- pack padded biases --------------------------------------------------
__global__ void pack_biases(
    const float* ac2, const float* lnf2, const float* f1, const float* f2,
    const float* f3, const float* f4, const float* f6,
    float* b_ac2p, float* b_lnf2p, float* b_f1p, float* b2p, float* b34p, float* b_f6p)
{
  int t = threadIdx.x;  // 1024
  switch (blockIdx.x) {
    case 0: if (t < 512) b_ac2p[t]  = (t < 500) ? ac2[t]  : 0.f; break;
    case 1: if (t < 512) b_lnf2p[t] = (t < 500) ? lnf2[t] : 0.f; break;
    case 2: if (t < 512) b_f1p[t]   = (t < 500) ? f1[t]   : 0.f; break;
    case 3: b2p[t] = (t < 500) ? f2[t] : 0.f; break;
    case 4: if (t < 640) b34p[t] = (t < 500) ? f3[t] : ((t >= 512 && t < 612) ? f4[t - 512] : 0.f); break;
    case 5: if (t < 512) b_f6p[t]   = (t < 500) ? f6[t]   : 0.f; break;
  }
}

extern "C" void kernel_launch(void* const* d_in, const int* in_sizes, int n_in,
                              void* d_out, int out_size, void* d_ws, size_t ws_size,
                              hipStream_t stream)
{
  const float* state    = (const float*)d_in[0];
  const float* actions  = (const float*)d_in[1];
  const float* ac_fc1_w = (const float*)d_in[2];
  const float* ac_fc1_b = (const float*)d_in[3];
  const float* ac_ln1_g = (const float*)d_in[4];
  const float* ac_ln1_b = (const float*)d_in[5];
  const float* ac_fc2_w = (const float*)d_in[6];
  const float* ac_fc2_b = (const float*)d_in[7];
  const float* ac_lnf2_w= (const float*)d_in[8];
  const float* ac_lnf2_b= (const float*)d_in[9];
  const float* ac_fc3_w = (const float*)d_in[10];
  const float* ac_fc3_b = (const float*)d_in[11];
  const float* fc1_w = (const float*)d_in[12];
  const float* fc1_b = (const float*)d_in[13];
  const float* ln1_g = (const float*)d_in[14];
  const float* ln1_b = (const float*)d_in[15];
  const float* fc2_w = (const float*)d_in[16];
  const float* fc2_b = (const float*)d_in[17];
  const float* ln2_g = (const float*)d_in[18];
  const float* ln2_b = (const float*)d_in[19];
  const float* fc3_w = (const float*)d_in[20];
  const float* fc3_b = (const float*)d_in[21];
  const float* ln3_g = (const float*)d_in[22];
  const float* ln3_b = (const float*)d_in[23];
  const float* fc4_w = (const float*)d_in[24];
  const float* fc4_b = (const float*)d_in[25];
  const float* ln4_g = (const float*)d_in[26];
  const float* ln4_b = (const float*)d_in[27];
  const float* fc5_w = (const float*)d_in[28];
  const float* fc5_b = (const float*)d_in[29];
  const float* fc6_w = (const float*)d_in[30];
  const float* fc6_b = (const float*)d_in[31];
  const float* ln6_g = (const float*)d_in[32];
  const float* ln6_b = (const float*)d_in[33];
  float* out = (float*)d_out;

  // ---- ws carve (bytes, 256-aligned) ----
  char* p = (char*)d_ws;
  auto carve = [&](size_t bytes) { char* r = p; p += (bytes + 255) & ~(size_t)255; return r; };
  u16*   cat    = (u16*)  carve(8192ull * 1024 * 2);   // also 'total'
  u16*   t1     = (u16*)  carve(8192ull * 512 * 2);
  u16*   s2     = (u16*)  carve(8192ull * 512 * 2);
  u16*   s1     = (u16*)  carve(8192ull * 512 * 2);
  u16*   core   = (u16*)  carve(15360ull * 512 * 2);
  u16*   v      = (u16*)  carve(15360ull * 640 * 2);
  float* pre    = (float*)carve(8192ull * 512 * 4);
  float* PQ     = (float*)carve(8192ull * 1024 * 4);
  float* esum   = (float*)carve(8192ull * 500 * 4);
  u16*   a_buf  = (u16*)  carve(512ull * 512 * 2);
  float* tmp_a  = (float*)carve(512ull * 500 * 4);
  float* att_a  = (float*)carve(8192ull * 4);
  char*  wT0    =         carve(0);
  u16*   ac_fc2T  = (u16*)carve(512ull * 1024 * 2);
  u16*   ac_lnf2T = (u16*)carve(512ull * 512 * 2);
  u16*   fc1T     = (u16*)carve(512ull * 512 * 2);
  u16*   B2T      = (u16*)carve(1024ull * 512 * 2);
  u16*   B34T     = (u16*)carve(640ull * 512 * 2);
  u16*   fc6T     = (u16*)carve(512ull * 1024 * 2);
  size_t wTbytes  = (size_t)((char*)carve(0) - wT0);
  float* b_ac2p  = (float*)carve(512 * 4);
  float* b_lnf2p = (float*)carve(512 * 4);
  float* b_f1p   = (float*)carve(512 * 4);
  float* b2p     = (float*)carve(1024 * 4);
  float* b34p    = (float*)carve(640 * 4);
  float* b_f6p   = (float*)carve(512 * 4);

  dim3 blk(256);
  dim3 tblk(32, 8);

  // ---- weight packing (every call; deterministic) ----
  hipMemsetAsync(wT0, 0, wTbytes, stream);
  transpose_pack<<<dim3(16, 32), tblk, 0, stream>>>(ac_fc2_w, 1000, 500, 500, ac_fc2T, 1024, 0, 0);
  transpose_pack<<<dim3(16, 16), tblk, 0, stream>>>(ac_lnf2_w, 500, 500, 500, ac_lnf2T, 512, 0, 0);
  transpose_pack<<<dim3(16, 16), tblk, 0, stream>>>(fc1_w, 500, 500, 500, fc1T, 512, 0, 0);
  transpose_pack<<<dim3(16, 16), tblk, 0, stream>>>(fc2_w, 500, 500, 500, B2T, 512, 0, 0);
  transpose_pack<<<dim3(16, 16), tblk, 0, stream>>>(fc2_w + 250000, 500, 500, 500, B2T, 512, 512, 0);
  transpose_pack<<<dim3(16, 16), tblk, 0, stream>>>(fc3_w, 500, 500, 500, B34T, 512, 0, 0);
  transpose_pack<<<dim3(4, 16),  tblk, 0, stream>>>(fc4_w, 500, 100, 100, B34T, 512, 512, 0);
  transpose_pack<<<dim3(16, 16), tblk, 0, stream>>>(fc6_w, 500, 500, 500, fc6T, 1024, 0, 0);
  transpose_pack<<<dim3(16, 16), tblk, 0, stream>>>(fc6_w + 250000, 500, 500, 500, fc6T, 1024, 0, 512);
  pack_biases<<<6, 1024, 0, stream>>>(ac_fc2_b, ac_lnf2_b, fc1_b, fc2_b, fc3_b, fc4_b, fc6_b,
                                      b_ac2p, b_lnf2p, b_f1p, b2p, b34p, b_f6p);

  // ---- a = LN(actions @ ac_fc1_w + b) ----
  gemm128<<<dim3(4, 4), blk, 0, stream>>>(actions, ac_fc1_w, ac_fc1_b, nullptr, tmp_a, 512, 500, 64);
  ln_rows<0, u16><<<512, blk, 0, stream>>>(tmp_a, a_buf, ac_ln1_g, ac_ln1_b, 500, 500, 512, 512);
  build_concat<<<8192, blk, 0, stream>>>(state, a_buf, cat);

  // ---- t1 = cat @ ac_fc2_w + b (bf16 out); att_a ----
  gemm_mfma<u16><<<dim3(4, 64), blk, 0, stream>>>(cat, ac_fc2T, b_ac2p, nullptr, t1, 8192, 512, 1024);
  dot_sig<<<8192, blk, 0, stream>>>(cat, ac_fc3_w, ac_fc3_b, att_a);
  // ---- s2 = (t1 @ ac_lnf2_w + b) * att_a (bf16) ----
  gemm_mfma<u16><<<dim3(4, 64), blk, 0, stream>>>(t1, ac_lnf2T, b_lnf2p, att_a, s2, 8192, 512, 512);
  // ---- s1 = relu(LN(s2 @ fc1_w + b, ln1)) ----
  gemm_mfma<float><<<dim3(4, 64), blk, 0, stream>>>(s2, fc1T, b_f1p, nullptr, pre, 8192, 512, 512);
  ln_rows<1, u16><<<8192, blk, 0, stream>>>(pre, s1, ln1_g, ln1_b, 500, 512, 512, 512);
  // ---- PQ = s1 @ [fc2_w[:500] | fc2_w[500:]] (f32; bias only on P half) ----
  gemm_mfma<float><<<dim3(8, 64), blk, 0, stream>>>(s1, B2T, b2p, nullptr, PQ, 8192, 1024, 512);

  for (int c = 0; c < 8; ++c) {
    int c0 = c * 1024;
    core_build<<<15360, blk, 0, stream>>>(PQ, core, ln2_g, ln2_b, c0);
    gemm_mfma<u16><<<dim3(5, 120), blk, 0, stream>>>(core, B34T, b34p, nullptr, v, 15360, 640, 512);
    chunk_post<<<1024, blk, 0, stream>>>(v, ln3_g, ln3_b, ln4_g, ln4_b, fc5_w, fc5_b, esum, c0);
  }

  build_total<<<8192, blk, 0, stream>>>(s1, esum, cat);
  gemm_mfma<float><<<dim3(4, 64), blk, 0, stream>>>(cat, fc6T, b_f6p, nullptr, pre, 8192, 512, 1024);
  ln_rows<0, float><<<8192, blk, 0, stream>>>(pre, out, ln6_g, ln6_b, 500, 512, 500, 500);
}

// Round 3
// 801.249 us; speedup vs baseline: 3.2098x; 1.1668x over previous
//
#include <hip/hip_runtime.h>
#include <math.h>

// TheRecurrentNet: B=512, K=16, H=500, A=64, nc=15.
// Round 3: wave-per-row reductions (no barrier chains), fused single-barrier
// chunk tail, bf16 PQ. GEMMs unchanged (m97-structure bf16 MFMA).

#define EPSF 1e-5f
typedef unsigned short u16;
typedef unsigned int u32;

typedef __bf16 bf16x8 __attribute__((ext_vector_type(8)));
typedef float f32x4 __attribute__((ext_vector_type(4)));
typedef u16 u16x8 __attribute__((ext_vector_type(8)));

__device__ __forceinline__ float bf2f(u16 u) {
  return __builtin_bit_cast(float, (u32)u << 16);
}
__device__ __forceinline__ u16 f2bf(float f) {
  u32 u = __builtin_bit_cast(u32, f);
  return (u16)((u + 0x7FFFu + ((u >> 16) & 1u)) >> 16);   // RNE
}

#define GLOAD16(g, l) __builtin_amdgcn_global_load_lds( \
    (__attribute__((address_space(1))) u32*)(g), \
    (__attribute__((address_space(3))) u32*)(l), 16, 0, 0)

// ---- wave-wide (64-lane) sums via shfl_xor, no LDS/barriers ----
__device__ __forceinline__ void wred2(float& a, float& b) {
#pragma unroll
  for (int m = 32; m; m >>= 1) { a += __shfl_xor(a, m); b += __shfl_xor(b, m); }
}
__device__ __forceinline__ float wred1(float a) {
#pragma unroll
  for (int m = 32; m; m >>= 1) a += __shfl_xor(a, m);
  return a;
}

// ---------------- block-wide sum over 256 threads (dot_sig only) -------------
__device__ __forceinline__ float block_sum256(float v) {
  __shared__ float red[4];
  int lane = threadIdx.x & 63;
  int wid  = threadIdx.x >> 6;
#pragma unroll
  for (int off = 32; off > 0; off >>= 1) v += __shfl_down(v, off);
  __syncthreads();
  if (lane == 0) red[wid] = v;
  __syncthreads();
  return red[0] + red[1] + red[2] + red[3];
}

// ======================= bf16 MFMA GEMM =======================
// C[M,Npad] = A[M,K](bf16) @ Bt[Npad,K]^T(bf16) + bias, optional *rowscale.
// M%128==0, Npad%128==0, K%32==0. 128x128 tile, BK=32, 4 waves x 4x4 frags.
template <typename TOUT>
__global__ __launch_bounds__(256) void gemm_mfma(
    const u16* __restrict__ A, const u16* __restrict__ Bt,
    const float* __restrict__ bias, const float* __restrict__ rowscale,
    TOUT* __restrict__ C, int M, int Npad, int K)
{
  __shared__ __align__(16) u16 As[128 * 32];   // [row][k]
  __shared__ __align__(16) u16 Bs[128 * 32];   // [col][k]
  const int tid = threadIdx.x;
  const int lane = tid & 63, wid = tid >> 6;
  const int wr = wid >> 1, wc = wid & 1;
  const size_t row0 = (size_t)blockIdx.y * 128, col0 = (size_t)blockIdx.x * 128;

  f32x4 acc[4][4] = {};

  const int s_row = tid >> 2, s_ch = tid & 3;
  const u16* gA0 = A + (row0 + s_row) * (size_t)K + s_ch * 8;
  const u16* gA1 = gA0 + (size_t)64 * K;
  const u16* gB0 = Bt + (col0 + s_row) * (size_t)K + s_ch * 8;
  const u16* gB1 = gB0 + (size_t)64 * K;
  u16* lA0 = As + tid * 8;
  u16* lA1 = As + 2048 + tid * 8;
  u16* lB0 = Bs + tid * 8;
  u16* lB1 = Bs + 2048 + tid * 8;

  const int fr = lane & 15, fq = lane >> 4;
  const u16* pAf = As + (wr * 64 + fr) * 32 + fq * 8;
  const u16* pBf = Bs + (wc * 64 + fr) * 32 + fq * 8;

  for (int k0 = 0; k0 < K; k0 += 32) {
    GLOAD16(gA0 + k0, lA0);
    GLOAD16(gA1 + k0, lA1);
    GLOAD16(gB0 + k0, lB0);
    GLOAD16(gB1 + k0, lB1);
    __syncthreads();
    bf16x8 af[4], bfv[4];
#pragma unroll
    for (int m = 0; m < 4; ++m) af[m] = *reinterpret_cast<const bf16x8*>(pAf + m * 16 * 32);
#pragma unroll
    for (int n = 0; n < 4; ++n) bfv[n] = *reinterpret_cast<const bf16x8*>(pBf + n * 16 * 32);
#pragma unroll
    for (int m = 0; m < 4; ++m)
#pragma unroll
      for (int n = 0; n < 4; ++n)
        acc[m][n] = __builtin_amdgcn_mfma_f32_16x16x32_bf16(af[m], bfv[n], acc[m][n], 0, 0, 0);
    __syncthreads();
  }

  const int cl = lane & 15, rg = lane >> 4;
#pragma unroll
  for (int m = 0; m < 4; ++m) {
#pragma unroll
    for (int n = 0; n < 4; ++n) {
      size_t col = col0 + wc * 64 + n * 16 + cl;
      float bv = bias[col];
#pragma unroll
      for (int r = 0; r < 4; ++r) {
        size_t row = row0 + wr * 64 + m * 16 + rg * 4 + r;
        float v = acc[m][n][r] + bv;
        if (rowscale) v *= rowscale[row];
        if constexpr (sizeof(TOUT) == 2) C[row * Npad + col] = f2bf(v);
        else                             C[row * Npad + col] = v;
      }
    }
  }
}

// ---------------- small f32 GEMM (actions @ ac_fc1_w) ------------------------
__global__ __launch_bounds__(256) void gemm128(
    const float* __restrict__ A, const float* __restrict__ B,
    const float* __restrict__ bias, const float* __restrict__ rowscale,
    float* __restrict__ C, int M, int N, int K)
{
  __shared__ float As[16][132];
  __shared__ float Bs[16][128];
  const int tid = threadIdx.x;
  const int tx = tid & 15, ty = tid >> 4;
  const int row0 = blockIdx.y * 128, col0 = blockIdx.x * 128;
  float acc[8][8];
#pragma unroll
  for (int i = 0; i < 8; ++i)
#pragma unroll
    for (int j = 0; j < 8; ++j) acc[i][j] = 0.f;

  const int nkt = (K + 15) >> 4;
  for (int kt = 0; kt < nkt; ++kt) {
    const int k0 = kt << 4;
#pragma unroll
    for (int h = 0; h < 2; ++h) {
      int i = tid + h * 256;
      int m = i >> 2, kk = (i & 3) << 2;
      int gm = row0 + m, gk = k0 + kk;
      float4 v = make_float4(0.f, 0.f, 0.f, 0.f);
      if (gm < M && gk < K) v = *reinterpret_cast<const float4*>(A + (size_t)gm * K + gk);
      As[kk + 0][m] = v.x; As[kk + 1][m] = v.y; As[kk + 2][m] = v.z; As[kk + 3][m] = v.w;
    }
#pragma unroll
    for (int h = 0; h < 2; ++h) {
      int i = tid + h * 256;
      int kk = i >> 5, n = (i & 31) << 2;
      int gk = k0 + kk, gn = col0 + n;
      float4 v = make_float4(0.f, 0.f, 0.f, 0.f);
      if (gk < K && gn < N) v = *reinterpret_cast<const float4*>(B + (size_t)gk * N + gn);
      *reinterpret_cast<float4*>(&Bs[kk][n]) = v;
    }
    __syncthreads();
#pragma unroll
    for (int kk = 0; kk < 16; ++kk) {
      float4 a0 = *reinterpret_cast<const float4*>(&As[kk][ty * 4]);
      float4 a1 = *reinterpret_cast<const float4*>(&As[kk][ty * 4 + 64]);
      float4 b0 = *reinterpret_cast<const float4*>(&Bs[kk][tx * 4]);
      float4 b1 = *reinterpret_cast<const float4*>(&Bs[kk][tx * 4 + 64]);
      float av[8] = {a0.x, a0.y, a0.z, a0.w, a1.x, a1.y, a1.z, a1.w};
      float bv[8] = {b0.x, b0.y, b0.z, b0.w, b1.x, b1.y, b1.z, b1.w};
#pragma unroll
      for (int i = 0; i < 8; ++i)
#pragma unroll
        for (int j = 0; j < 8; ++j) acc[i][j] += av[i] * bv[j];
    }
    __syncthreads();
  }
#pragma unroll
  for (int i = 0; i < 8; ++i) {
    int gm = row0 + ty * 4 + ((i >> 2) << 6) + (i & 3);
    if (gm >= M) continue;
    float rs = rowscale ? rowscale[gm] : 1.f;
#pragma unroll
    for (int j = 0; j < 8; ++j) {
      int gn = col0 + tx * 4 + ((j >> 2) << 6) + (j & 3);
      if (gn < N) {
        float v = acc[i][j];
        if (bias) v += bias[gn];
        C[(size_t)gm * N + gn] = v * rs;
      }
    }
  }
}

// ---------------- wave-per-row LayerNorm (cols=500), f32 in ------------------
// 4 rows per block. TOUT=u16 -> ldy must be 512 (pads zeroed).
template <int ACT, typename TOUT>
__global__ __launch_bounds__(256) void ln_wave(
    const float* __restrict__ X, TOUT* __restrict__ Y,
    const float* __restrict__ g, const float* __restrict__ b,
    int ldx, int ldy)
{
  int row = blockIdx.x * 4 + (threadIdx.x >> 6);
  int lane = threadIdx.x & 63;
  const float* x = X + (size_t)row * ldx;
  int k0 = lane * 8;
  float xv[8];
  if (k0 + 8 <= 500) {
    float4 a = *reinterpret_cast<const float4*>(x + k0);
    float4 c = *reinterpret_cast<const float4*>(x + k0 + 4);
    xv[0] = a.x; xv[1] = a.y; xv[2] = a.z; xv[3] = a.w;
    xv[4] = c.x; xv[5] = c.y; xv[6] = c.z; xv[7] = c.w;
  } else {
#pragma unroll
    for (int e = 0; e < 8; ++e) xv[e] = (k0 + e < 500) ? x[k0 + e] : 0.f;
  }
  float s = 0.f, s2 = 0.f;
#pragma unroll
  for (int e = 0; e < 8; ++e) { s += xv[e]; s2 += xv[e] * xv[e]; }
  wred2(s, s2);
  float mu = s / 500.f;
  float rstd = rsqrtf(s2 / 500.f - mu * mu + EPSF);
  float ov[8];
#pragma unroll
  for (int e = 0; e < 8; ++e) {
    int k = k0 + e;
    float v = 0.f;
    if (k < 500) {
      v = (xv[e] - mu) * rstd * g[k] + b[k];
      if (ACT == 1) v = fmaxf(v, 0.f);
    }
    ov[e] = v;
  }
  if constexpr (sizeof(TOUT) == 2) {
    u16x8 o;
#pragma unroll
    for (int e = 0; e < 8; ++e) o[e] = f2bf(ov[e]);
    *reinterpret_cast<u16x8*>((u16*)Y + (size_t)row * ldy + k0) = o;
  } else {
    float* y = (float*)Y + (size_t)row * ldy;
    if (k0 + 4 <= 500)
      *reinterpret_cast<float4*>(y + k0) = make_float4(ov[0], ov[1], ov[2], ov[3]);
    if (k0 + 8 <= 500)
      *reinterpret_cast<float4*>(y + k0 + 4) = make_float4(ov[4], ov[5], ov[6], ov[7]);
  }
}

// ---------------- cat[r] = [bf16(state[r]) | a[r>>4] | 0pad] -----------------
__global__ __launch_bounds__(256) void build_concat(
    const float* __restrict__ state, const u16* __restrict__ a, u16* __restrict__ cat)
{
  int r = blockIdx.x, t = threadIdx.x;
  int b = r >> 4;
  u16* c = cat + (size_t)r * 1024;
  if (t < 125) {
    float4 v = *reinterpret_cast<const float4*>(state + (size_t)r * 500 + t * 4);
    ushort4 o; o.x = f2bf(v.x); o.y = f2bf(v.y); o.z = f2bf(v.z); o.w = f2bf(v.w);
    *reinterpret_cast<ushort4*>(c + t * 4) = o;
    *reinterpret_cast<ushort4*>(c + 500 + t * 4) =
        *reinterpret_cast<const ushort4*>(a + (size_t)b * 512 + t * 4);
  }
  if (t < 24) c[1000 + t] = 0;
}

// ---------------- total[r] = [s1[r] | 0 | bf16(esum[r]) | 0] -----------------
__global__ __launch_bounds__(256) void build_total(
    const u16* __restrict__ s1, const float* __restrict__ esum, u16* __restrict__ tot)
{
  int r = blockIdx.x, t = threadIdx.x;
  u16* c = tot + (size_t)r * 1024;
  if (t < 125) {
    *reinterpret_cast<ushort4*>(c + t * 4) =
        *reinterpret_cast<const ushort4*>(s1 + (size_t)r * 512 + t * 4);
    float4 v = *reinterpret_cast<const float4*>(esum + (size_t)r * 500 + t * 4);
    ushort4 o; o.x = f2bf(v.x); o.y = f2bf(v.y); o.z = f2bf(v.z); o.w = f2bf(v.w);
    *reinterpret_cast<ushort4*>(c + 512 + t * 4) = o;
  }
  if (t < 12) { c[500 + t] = 0; c[1012 + t] = 0; }
}

// ---------------- att_a[r] = sigmoid(dot(cat[r,0:1000], w3) + b3) ------------
__global__ __launch_bounds__(256) void dot_sig(
    const u16* __restrict__ cat, const float* __restrict__ w3,
    const float* __restrict__ b3, float* __restrict__ atta)
{
  int r = blockIdx.x, t = threadIdx.x;
  const u16* x = cat + (size_t)r * 1024;
  float s = 0.f;
  if (t < 125) {
    ushort4 u0 = *reinterpret_cast<const ushort4*>(x + t * 8);
    ushort4 u1 = *reinterpret_cast<const ushort4*>(x + t * 8 + 4);
    float4 w0 = *reinterpret_cast<const float4*>(w3 + t * 8);
    float4 w1 = *reinterpret_cast<const float4*>(w3 + t * 8 + 4);
    s = bf2f(u0.x) * w0.x + bf2f(u0.y) * w0.y + bf2f(u0.z) * w0.z + bf2f(u0.w) * w0.w
      + bf2f(u1.x) * w1.x + bf2f(u1.y) * w1.y + bf2f(u1.z) * w1.z + bf2f(u1.w) * w1.w;
  }
  s = block_sum256(s);
  if (t == 0) atta[r] = 1.f / (1.f + expf(-(s + b3[0])));
}

// -------- core row = relu(LN(P[r1]+Q[r2], ln2)) — wave-per-row, bf16 ---------
__global__ __launch_bounds__(256) void core_build2(
    const u16* __restrict__ PQ, u16* __restrict__ core,
    const float* __restrict__ g2, const float* __restrict__ b2, int c0)
{
  int id = blockIdx.x * 4 + (threadIdx.x >> 6);   // chunk row 0..15359
  int lane = threadIdx.x & 63;
  int pp = id / 15, j = id - pp * 15;
  int gp = c0 + pp;
  int i = gp & 15;
  int col = j + (j >= i);
  int r2 = (gp & ~15) | col;
  const u16* p = PQ + (size_t)gp * 1024;
  const u16* q = PQ + (size_t)r2 * 1024 + 512;
  int k0 = lane * 8;
  u16x8 up = *reinterpret_cast<const u16x8*>(p + k0);
  u16x8 uq = *reinterpret_cast<const u16x8*>(q + k0);
  float xv[8], s = 0.f, s2 = 0.f;
#pragma unroll
  for (int e = 0; e < 8; ++e) {
    xv[e] = bf2f(up[e]) + bf2f(uq[e]);   // pads are exact zeros
    s += xv[e]; s2 += xv[e] * xv[e];
  }
  wred2(s, s2);
  float mu = s / 500.f;
  float rstd = rsqrtf(s2 / 500.f - mu * mu + EPSF);
  u16x8 o;
#pragma unroll
  for (int e = 0; e < 8; ++e) {
    int k = k0 + e;
    o[e] = (k < 500) ? f2bf(fmaxf((xv[e] - mu) * rstd * g2[k] + b2[k], 0.f)) : (u16)0;
  }
  *reinterpret_cast<u16x8*>(core + (size_t)id * 512 + k0) = o;
}

// -------- fused chunk tail: stats wave-per-row, one barrier, then esum -------
// v row layout: [0:500)=fc3 out (pads 500:512 zero), [512:612)=fc4 out
// (pads 612:640 zero) — unmasked vector sums are exact.
__global__ __launch_bounds__(256) void chunk_post2(
    const u16* __restrict__ V,
    const float* __restrict__ g3, const float* __restrict__ b3,
    const float* __restrict__ g4, const float* __restrict__ b4,
    const float* __restrict__ w5, const float* __restrict__ b5,
    float* __restrict__ esum, int c0)
{
  __shared__ u16 rows[15][512];
  __shared__ float st[15][4];   // mu, rstd, att
  int pp = blockIdx.x, t = threadIdx.x;
  int lane = t & 63, w = t >> 6;

  for (int j = w; j < 15; j += 4) {
    const u16* vr = V + (size_t)(pp * 15 + j) * 640;
    int k0 = lane * 8;
    u16x8 u = *reinterpret_cast<const u16x8*>(vr + k0);
    *reinterpret_cast<u16x8*>(&rows[j][k0]) = u;
    float s = 0.f, s2 = 0.f;
#pragma unroll
    for (int e = 0; e < 8; ++e) { float v = bf2f(u[e]); s += v; s2 += v * v; }
    // fc4 part: 128 cols starting at 512 (zeros beyond 100)
    ushort2 ua = *reinterpret_cast<const ushort2*>(vr + 512 + lane * 2);
    float y0 = bf2f(ua.x), y1 = bf2f(ua.y);
    float sa = y0 + y1, sa2 = y0 * y0 + y1 * y1;
    wred2(s, s2);
    wred2(sa, sa2);
    float mu = s / 500.f;
    float rstd = rsqrtf(s2 / 500.f - mu * mu + EPSF);
    float mu4 = sa / 100.f;
    float rstd4 = rsqrtf(sa2 / 100.f - mu4 * mu4 + EPSF);
    float dv = 0.f;
    int k = lane * 2;
    if (k < 100)     dv += tanhf((y0 - mu4) * rstd4 * g4[k] + b4[k]) * w5[k];
    if (k + 1 < 100) dv += tanhf((y1 - mu4) * rstd4 * g4[k + 1] + b4[k + 1]) * w5[k + 1];
    float D = wred1(dv);
    if (lane == 0) {
      st[j][0] = mu; st[j][1] = rstd;
      st[j][2] = 1.f / (1.f + expf(-(D + b5[0])));
    }
  }
  __syncthreads();

  for (int n = t; n < 500; n += 256) {
    float gg = g3[n], bb = b3[n], acc = 0.f;
#pragma unroll
    for (int j = 0; j < 15; ++j) {
      float v = bf2f(rows[j][n]);
      acc += fmaxf((v - st[j][0]) * st[j][1] * gg + bb, 0.f) * st[j][2];
    }
    esum[(size_t)(c0 + pp) * 500 + n] = acc;
  }
}

// -------- transpose+pack: dst[(n+nOff)*ldDst + kOff + k] = bf16(src[k*srcLd+n])
__global__ void transpose_pack(
    const float* __restrict__ src, int K, int N, int srcLd,
    u16* __restrict__ dst, int ldDst, int nOff, int kOff)
{
  __shared__ float tl[32][33];
  int tx = threadIdx.x, ty = threadIdx.y;   // 32 x 8
  int k0 = blockIdx.y * 32, n0 = blockIdx.x * 32;
#pragma unroll
  for (int r = 0; r < 4; ++r) {
    int row = k0 + ty + r * 8;
    if (row < K && n0 + tx < N) tl[ty + r * 8][tx] = src[(size_t)row * srcLd + n0 + tx];
  }
  __syncthreads();
#pragma unroll
  for (int r = 0; r < 4; ++r) {
    int n = n0 + ty + r * 8, k = k0 + tx;
    if (n < N && k < K)
      dst[(size_t)(n + nOff) * ldDst + kOff + k] = f2bf(tl[tx][ty + r * 8]);
  }
}

// -------- pack padded biases --------------------------------------------------
__global__ void pack_biases(
    const float* ac2, const float* lnf2, const float* f1, const float* f2,
    const float* f3, const float* f4, const float* f6,
    float* b_ac2p, float* b_lnf2p, float* b_f1p, float* b2p, float* b34p, float* b_f6p)
{
  int t = threadIdx.x;  // 1024
  switch (blockIdx.x) {
    case 0: if (t < 512) b_ac2p[t]  = (t < 500) ? ac2[t]  : 0.f; break;
    case 1: if (t < 512) b_lnf2p[t] = (t < 500) ? lnf2[t] : 0.f; break;
    case 2: if (t < 512) b_f1p[t]   = (t < 500) ? f1[t]   : 0.f; break;
    case 3: b2p[t] = (t < 500) ? f2[t] : 0.f; break;
    case 4: if (t < 640) b34p[t] = (t < 500) ? f3[t] : ((t >= 512 && t < 612) ? f4[t - 512] : 0.f); break;
    case 5: if (t < 512) b_f6p[t]   = (t < 500) ? f6[t]   : 0.f; break;
  }
}

extern "C" void kernel_launch(void* const* d_in, const int* in_sizes, int n_in,
                              void* d_out, int out_size, void* d_ws, size_t ws_size,
                              hipStream_t stream)
{
  const float* state    = (const float*)d_in[0];
  const float* actions  = (const float*)d_in[1];
  const float* ac_fc1_w = (const float*)d_in[2];
  const float* ac_fc1_b = (const float*)d_in[3];
  const float* ac_ln1_g = (const float*)d_in[4];
  const float* ac_ln1_b = (const float*)d_in[5];
  const float* ac_fc2_w = (const float*)d_in[6];
  const float* ac_fc2_b = (const float*)d_in[7];
  const float* ac_lnf2_w= (const float*)d_in[8];
  const float* ac_lnf2_b= (const float*)d_in[9];
  const float* ac_fc3_w = (const float*)d_in[10];
  const float* ac_fc3_b = (const float*)d_in[11];
  const float* fc1_w = (const float*)d_in[12];
  const float* fc1_b = (const float*)d_in[13];
  const float* ln1_g = (const float*)d_in[14];
  const float* ln1_b = (const float*)d_in[15];
  const float* fc2_w = (const float*)d_in[16];
  const float* fc2_b = (const float*)d_in[17];
  const float* ln2_g = (const float*)d_in[18];
  const float* ln2_b = (const float*)d_in[19];
  const float* fc3_w = (const float*)d_in[20];
  const float* fc3_b = (const float*)d_in[21];
  const float* ln3_g = (const float*)d_in[22];
  const float* ln3_b = (const float*)d_in[23];
  const float* fc4_w = (const float*)d_in[24];
  const float* fc4_b = (const float*)d_in[25];
  const float* ln4_g = (const float*)d_in[26];
  const float* ln4_b = (const float*)d_in[27];
  const float* fc5_w = (const float*)d_in[28];
  const float* fc5_b = (const float*)d_in[29];
  const float* fc6_w = (const float*)d_in[30];
  const float* fc6_b = (const float*)d_in[31];
  const float* ln6_g = (const float*)d_in[32];
  const float* ln6_b = (const float*)d_in[33];
  float* out = (float*)d_out;

  // ---- ws carve (bytes, 256-aligned) ----
  char* p = (char*)d_ws;
  auto carve = [&](size_t bytes) { char* r = p; p += (bytes + 255) & ~(size_t)255; return r; };
  u16*   cat    = (u16*)  carve(8192ull * 1024 * 2);   // also 'total'
  u16*   t1     = (u16*)  carve(8192ull * 512 * 2);
  u16*   s2     = (u16*)  carve(8192ull * 512 * 2);
  u16*   s1     = (u16*)  carve(8192ull * 512 * 2);
  u16*   core   = (u16*)  carve(15360ull * 512 * 2);
  u16*   v      = (u16*)  carve(15360ull * 640 * 2);
  float* pre    = (float*)carve(8192ull * 512 * 4);
  u16*   PQ     = (u16*)  carve(8192ull * 1024 * 2);
  float* esum   = (float*)carve(8192ull * 500 * 4);
  u16*   a_buf  = (u16*)  carve(512ull * 512 * 2);
  float* tmp_a  = (float*)carve(512ull * 500 * 4);
  float* att_a  = (float*)carve(8192ull * 4);
  char*  wT0    =         carve(0);
  u16*   ac_fc2T  = (u16*)carve(512ull * 1024 * 2);
  u16*   ac_lnf2T = (u16*)carve(512ull * 512 * 2);
  u16*   fc1T     = (u16*)carve(512ull * 512 * 2);
  u16*   B2T      = (u16*)carve(1024ull * 512 * 2);
  u16*   B34T     = (u16*)carve(640ull * 512 * 2);
  u16*   fc6T     = (u16*)carve(512ull * 1024 * 2);
  size_t wTbytes  = (size_t)((char*)carve(0) - wT0);
  float* b_ac2p  = (float*)carve(512 * 4);
  float* b_lnf2p = (float*)carve(512 * 4);
  float* b_f1p   = (float*)carve(512 * 4);
  float* b2p     = (float*)carve(1024 * 4);
  float* b34p    = (float*)carve(640 * 4);
  float* b_f6p   = (float*)carve(512 * 4);

  dim3 blk(256);
  dim3 tblk(32, 8);

  // ---- weight packing (every call; deterministic) ----
  hipMemsetAsync(wT0, 0, wTbytes, stream);
  transpose_pack<<<dim3(16, 32), tblk, 0, stream>>>(ac_fc2_w, 1000, 500, 500, ac_fc2T, 1024, 0, 0);
  transpose_pack<<<dim3(16, 16), tblk, 0, stream>>>(ac_lnf2_w, 500, 500, 500, ac_lnf2T, 512, 0, 0);
  transpose_pack<<<dim3(16, 16), tblk, 0, stream>>>(fc1_w, 500, 500, 500, fc1T, 512, 0, 0);
  transpose_pack<<<dim3(16, 16), tblk, 0, stream>>>(fc2_w, 500, 500, 500, B2T, 512, 0, 0);
  transpose_pack<<<dim3(16, 16), tblk, 0, stream>>>(fc2_w + 250000, 500, 500, 500, B2T, 512, 512, 0);
  transpose_pack<<<dim3(16, 16), tblk, 0, stream>>>(fc3_w, 500, 500, 500, B34T, 512, 0, 0);
  transpose_pack<<<dim3(4, 16),  tblk, 0, stream>>>(fc4_w, 500, 100, 100, B34T, 512, 512, 0);
  transpose_pack<<<dim3(16, 16), tblk, 0, stream>>>(fc6_w, 500, 500, 500, fc6T, 1024, 0, 0);
  transpose_pack<<<dim3(16, 16), tblk, 0, stream>>>(fc6_w + 250000, 500, 500, 500, fc6T, 1024, 0, 512);
  pack_biases<<<6, 1024, 0, stream>>>(ac_fc2_b, ac_lnf2_b, fc1_b, fc2_b, fc3_b, fc4_b, fc6_b,
                                      b_ac2p, b_lnf2p, b_f1p, b2p, b34p, b_f6p);

  // ---- a = LN(actions @ ac_fc1_w + b) ----
  gemm128<<<dim3(4, 4), blk, 0, stream>>>(actions, ac_fc1_w, ac_fc1_b, nullptr, tmp_a, 512, 500, 64);
  ln_wave<0, u16><<<128, blk, 0, stream>>>(tmp_a, a_buf, ac_ln1_g, ac_ln1_b, 500, 512);
  build_concat<<<8192, blk, 0, stream>>>(state, a_buf, cat);

  // ---- t1 = cat @ ac_fc2_w + b (bf16); att_a ----
  gemm_mfma<u16><<<dim3(4, 64), blk, 0, stream>>>(cat, ac_fc2T, b_ac2p, nullptr, t1, 8192, 512, 1024);
  dot_sig<<<8192, blk, 0, stream>>>(cat, ac_fc3_w, ac_fc3_b, att_a);
  // ---- s2 = (t1 @ ac_lnf2_w + b) * att_a (bf16) ----
  gemm_mfma<u16><<<dim3(4, 64), blk, 0, stream>>>(t1, ac_lnf2T, b_lnf2p, att_a, s2, 8192, 512, 512);
  // ---- s1 = relu(LN(s2 @ fc1_w + b, ln1)) ----
  gemm_mfma<float><<<dim3(4, 64), blk, 0, stream>>>(s2, fc1T, b_f1p, nullptr, pre, 8192, 512, 512);
  ln_wave<1, u16><<<2048, blk, 0, stream>>>(pre, s1, ln1_g, ln1_b, 512, 512);
  // ---- PQ = s1 @ [fc2_w[:500] | fc2_w[500:]] (bf16) ----
  gemm_mfma<u16><<<dim3(8, 64), blk, 0, stream>>>(s1, B2T, b2p, nullptr, PQ, 8192, 1024, 512);

  for (int c = 0; c < 8; ++c) {
    int c0 = c * 1024;
    core_build2<<<3840, blk, 0, stream>>>(PQ, core, ln2_g, ln2_b, c0);
    gemm_mfma<u16><<<dim3(5, 120), blk, 0, stream>>>(core, B34T, b34p, nullptr, v, 15360, 640, 512);
    chunk_post2<<<1024, blk, 0, stream>>>(v, ln3_g, ln3_b, ln4_g, ln4_b, fc5_w, fc5_b, esum, c0);
  }

  build_total<<<8192, blk, 0, stream>>>(s1, esum, cat);
  gemm_mfma<float><<<dim3(4, 64), blk, 0, stream>>>(cat, fc6T, b_f6p, nullptr, pre, 8192, 512, 1024);
  ln_wave<0, float><<<2048, blk, 0, stream>>>(pre, out, ln6_g, ln6_b, 512, 500);
}

// Round 4
// 723.579 us; speedup vs baseline: 3.5543x; 1.1073x over previous
//
#include <hip/hip_runtime.h>
#include <math.h>

// TheRecurrentNet: B=512, K=16, H=500, A=64, nc=15.
// Round 4: 128x64 GEMM tiles (2-9 blocks/CU for barrier overlap), chunk=2048
// (4 iters), merged weight-pack dispatch, wave-per-row dot_sig.

#define EPSF 1e-5f
typedef unsigned short u16;
typedef unsigned int u32;

typedef __bf16 bf16x8 __attribute__((ext_vector_type(8)));
typedef float f32x4 __attribute__((ext_vector_type(4)));
typedef u16 u16x8 __attribute__((ext_vector_type(8)));

__device__ __forceinline__ float bf2f(u16 u) {
  return __builtin_bit_cast(float, (u32)u << 16);
}
__device__ __forceinline__ u16 f2bf(float f) {
  u32 u = __builtin_bit_cast(u32, f);
  return (u16)((u + 0x7FFFu + ((u >> 16) & 1u)) >> 16);   // RNE
}

#define GLOAD16(g, l) __builtin_amdgcn_global_load_lds( \
    (__attribute__((address_space(1))) u32*)(g), \
    (__attribute__((address_space(3))) u32*)(l), 16, 0, 0)

// ---- wave-wide (64-lane) sums via shfl_xor ----
__device__ __forceinline__ void wred2(float& a, float& b) {
#pragma unroll
  for (int m = 32; m; m >>= 1) { a += __shfl_xor(a, m); b += __shfl_xor(b, m); }
}
__device__ __forceinline__ float wred1(float a) {
#pragma unroll
  for (int m = 32; m; m >>= 1) a += __shfl_xor(a, m);
  return a;
}

// ======================= bf16 MFMA GEMM, 128x64 tile =======================
// C[M,Npad] = A[M,K](bf16) @ Bt[Npad,K]^T(bf16) + bias, optional *rowscale.
// M%128==0, Npad%64==0, K%32==0. BK=32, 4 waves; wave w owns rows
// [w*32,w*32+32) x 64 cols as 2x4 16x16x32 fragments (acc = 32 VGPR).
template <typename TOUT>
__global__ __launch_bounds__(256) void gemm_mfma(
    const u16* __restrict__ A, const u16* __restrict__ Bt,
    const float* __restrict__ bias, const float* __restrict__ rowscale,
    TOUT* __restrict__ C, int M, int Npad, int K)
{
  __shared__ __align__(16) u16 As[128 * 32];   // [row][k]
  __shared__ __align__(16) u16 Bs[64 * 32];    // [col][k]
  const int tid = threadIdx.x;
  const int lane = tid & 63, wid = tid >> 6;
  const size_t row0 = (size_t)blockIdx.y * 128, col0 = (size_t)blockIdx.x * 64;

  f32x4 acc[2][4] = {};

  // staging: thread covers 16B at (row = tid>>2, k-chunk = (tid&3)*8)
  const int s_row = tid >> 2, s_ch = tid & 3;
  const u16* gA0 = A + (row0 + s_row) * (size_t)K + s_ch * 8;
  const u16* gA1 = gA0 + (size_t)64 * K;
  const u16* gB0 = Bt + (col0 + s_row) * (size_t)K + s_ch * 8;
  u16* lA0 = As + tid * 8;
  u16* lA1 = As + 2048 + tid * 8;
  u16* lB0 = Bs + tid * 8;

  const int fr = lane & 15, fq = lane >> 4;
  const u16* pAf = As + (wid * 32 + fr) * 32 + fq * 8;
  const u16* pBf = Bs + fr * 32 + fq * 8;

  for (int k0 = 0; k0 < K; k0 += 32) {
    GLOAD16(gA0 + k0, lA0);
    GLOAD16(gA1 + k0, lA1);
    GLOAD16(gB0 + k0, lB0);
    __syncthreads();
    bf16x8 af[2], bfv[4];
#pragma unroll
    for (int m = 0; m < 2; ++m) af[m] = *reinterpret_cast<const bf16x8*>(pAf + m * 16 * 32);
#pragma unroll
    for (int n = 0; n < 4; ++n) bfv[n] = *reinterpret_cast<const bf16x8*>(pBf + n * 16 * 32);
#pragma unroll
    for (int m = 0; m < 2; ++m)
#pragma unroll
      for (int n = 0; n < 4; ++n)
        acc[m][n] = __builtin_amdgcn_mfma_f32_16x16x32_bf16(af[m], bfv[n], acc[m][n], 0, 0, 0);
    __syncthreads();
  }

  // epilogue: C/D layout col=lane&15, row=(lane>>4)*4+reg
  const int cl = lane & 15, rg = lane >> 4;
#pragma unroll
  for (int m = 0; m < 2; ++m) {
#pragma unroll
    for (int n = 0; n < 4; ++n) {
      size_t col = col0 + n * 16 + cl;
      float bv = bias[col];
#pragma unroll
      for (int r = 0; r < 4; ++r) {
        size_t row = row0 + wid * 32 + m * 16 + rg * 4 + r;
        float v = acc[m][n][r] + bv;
        if (rowscale) v *= rowscale[row];
        if constexpr (sizeof(TOUT) == 2) C[row * Npad + col] = f2bf(v);
        else                             C[row * Npad + col] = v;
      }
    }
  }
}

// ---------------- small f32 GEMM (actions @ ac_fc1_w) ------------------------
__global__ __launch_bounds__(256) void gemm128(
    const float* __restrict__ A, const float* __restrict__ B,
    const float* __restrict__ bias, float* __restrict__ C, int M, int N, int K)
{
  __shared__ float As[16][132];
  __shared__ float Bs[16][128];
  const int tid = threadIdx.x;
  const int tx = tid & 15, ty = tid >> 4;
  const int row0 = blockIdx.y * 128, col0 = blockIdx.x * 128;
  float acc[8][8];
#pragma unroll
  for (int i = 0; i < 8; ++i)
#pragma unroll
    for (int j = 0; j < 8; ++j) acc[i][j] = 0.f;

  const int nkt = (K + 15) >> 4;
  for (int kt = 0; kt < nkt; ++kt) {
    const int k0 = kt << 4;
#pragma unroll
    for (int h = 0; h < 2; ++h) {
      int i = tid + h * 256;
      int m = i >> 2, kk = (i & 3) << 2;
      int gm = row0 + m, gk = k0 + kk;
      float4 v = make_float4(0.f, 0.f, 0.f, 0.f);
      if (gm < M && gk < K) v = *reinterpret_cast<const float4*>(A + (size_t)gm * K + gk);
      As[kk + 0][m] = v.x; As[kk + 1][m] = v.y; As[kk + 2][m] = v.z; As[kk + 3][m] = v.w;
    }
#pragma unroll
    for (int h = 0; h < 2; ++h) {
      int i = tid + h * 256;
      int kk = i >> 5, n = (i & 31) << 2;
      int gk = k0 + kk, gn = col0 + n;
      float4 v = make_float4(0.f, 0.f, 0.f, 0.f);
      if (gk < K && gn < N) v = *reinterpret_cast<const float4*>(B + (size_t)gk * N + gn);
      *reinterpret_cast<float4*>(&Bs[kk][n]) = v;
    }
    __syncthreads();
#pragma unroll
    for (int kk = 0; kk < 16; ++kk) {
      float4 a0 = *reinterpret_cast<const float4*>(&As[kk][ty * 4]);
      float4 a1 = *reinterpret_cast<const float4*>(&As[kk][ty * 4 + 64]);
      float4 b0 = *reinterpret_cast<const float4*>(&Bs[kk][tx * 4]);
      float4 b1 = *reinterpret_cast<const float4*>(&Bs[kk][tx * 4 + 64]);
      float av[8] = {a0.x, a0.y, a0.z, a0.w, a1.x, a1.y, a1.z, a1.w};
      float bv[8] = {b0.x, b0.y, b0.z, b0.w, b1.x, b1.y, b1.z, b1.w};
#pragma unroll
      for (int i = 0; i < 8; ++i)
#pragma unroll
        for (int j = 0; j < 8; ++j) acc[i][j] += av[i] * bv[j];
    }
    __syncthreads();
  }
#pragma unroll
  for (int i = 0; i < 8; ++i) {
    int gm = row0 + ty * 4 + ((i >> 2) << 6) + (i & 3);
    if (gm >= M) continue;
#pragma unroll
    for (int j = 0; j < 8; ++j) {
      int gn = col0 + tx * 4 + ((j >> 2) << 6) + (j & 3);
      if (gn < N) C[(size_t)gm * N + gn] = acc[i][j] + bias[gn];
    }
  }
}

// ---------------- wave-per-row LayerNorm (cols=500), f32 in ------------------
template <int ACT, typename TOUT>
__global__ __launch_bounds__(256) void ln_wave(
    const float* __restrict__ X, TOUT* __restrict__ Y,
    const float* __restrict__ g, const float* __restrict__ b,
    int ldx, int ldy)
{
  int row = blockIdx.x * 4 + (threadIdx.x >> 6);
  int lane = threadIdx.x & 63;
  const float* x = X + (size_t)row * ldx;
  int k0 = lane * 8;
  float xv[8];
  if (k0 + 8 <= 500) {
    float4 a = *reinterpret_cast<const float4*>(x + k0);
    float4 c = *reinterpret_cast<const float4*>(x + k0 + 4);
    xv[0] = a.x; xv[1] = a.y; xv[2] = a.z; xv[3] = a.w;
    xv[4] = c.x; xv[5] = c.y; xv[6] = c.z; xv[7] = c.w;
  } else {
#pragma unroll
    for (int e = 0; e < 8; ++e) xv[e] = (k0 + e < 500) ? x[k0 + e] : 0.f;
  }
  float s = 0.f, s2 = 0.f;
#pragma unroll
  for (int e = 0; e < 8; ++e) { s += xv[e]; s2 += xv[e] * xv[e]; }
  wred2(s, s2);
  float mu = s / 500.f;
  float rstd = rsqrtf(s2 / 500.f - mu * mu + EPSF);
  float ov[8];
#pragma unroll
  for (int e = 0; e < 8; ++e) {
    int k = k0 + e;
    float v = 0.f;
    if (k < 500) {
      v = (xv[e] - mu) * rstd * g[k] + b[k];
      if (ACT == 1) v = fmaxf(v, 0.f);
    }
    ov[e] = v;
  }
  if constexpr (sizeof(TOUT) == 2) {
    u16x8 o;
#pragma unroll
    for (int e = 0; e < 8; ++e) o[e] = f2bf(ov[e]);
    *reinterpret_cast<u16x8*>((u16*)Y + (size_t)row * ldy + k0) = o;
  } else {
    float* y = (float*)Y + (size_t)row * ldy;
    if (k0 + 4 <= 500)
      *reinterpret_cast<float4*>(y + k0) = make_float4(ov[0], ov[1], ov[2], ov[3]);
    if (k0 + 8 <= 500)
      *reinterpret_cast<float4*>(y + k0 + 4) = make_float4(ov[4], ov[5], ov[6], ov[7]);
  }
}

// ---------------- cat[r] = [bf16(state[r]) | a[r>>4] | 0pad] -----------------
__global__ __launch_bounds__(256) void build_concat(
    const float* __restrict__ state, const u16* __restrict__ a, u16* __restrict__ cat)
{
  int r = blockIdx.x, t = threadIdx.x;
  int b = r >> 4;
  u16* c = cat + (size_t)r * 1024;
  if (t < 125) {
    float4 v = *reinterpret_cast<const float4*>(state + (size_t)r * 500 + t * 4);
    ushort4 o; o.x = f2bf(v.x); o.y = f2bf(v.y); o.z = f2bf(v.z); o.w = f2bf(v.w);
    *reinterpret_cast<ushort4*>(c + t * 4) = o;
    *reinterpret_cast<ushort4*>(c + 500 + t * 4) =
        *reinterpret_cast<const ushort4*>(a + (size_t)b * 512 + t * 4);
  }
  if (t < 24) c[1000 + t] = 0;
}

// ---------------- total[r] = [s1[r] | 0 | bf16(esum[r]) | 0] -----------------
__global__ __launch_bounds__(256) void build_total(
    const u16* __restrict__ s1, const float* __restrict__ esum, u16* __restrict__ tot)
{
  int r = blockIdx.x, t = threadIdx.x;
  u16* c = tot + (size_t)r * 1024;
  if (t < 125) {
    *reinterpret_cast<ushort4*>(c + t * 4) =
        *reinterpret_cast<const ushort4*>(s1 + (size_t)r * 512 + t * 4);
    float4 v = *reinterpret_cast<const float4*>(esum + (size_t)r * 500 + t * 4);
    ushort4 o; o.x = f2bf(v.x); o.y = f2bf(v.y); o.z = f2bf(v.z); o.w = f2bf(v.w);
    *reinterpret_cast<ushort4*>(c + 512 + t * 4) = o;
  }
  if (t < 12) { c[500 + t] = 0; c[1012 + t] = 0; }
}

// -------- att_a: wave-per-row, 4 rows/block, no barriers ---------------------
__global__ __launch_bounds__(256) void dot_sig(
    const u16* __restrict__ cat, const float* __restrict__ w3,
    const float* __restrict__ b3, float* __restrict__ atta)
{
  int r = blockIdx.x * 4 + (threadIdx.x >> 6);
  int lane = threadIdx.x & 63;
  const u16* x = cat + (size_t)r * 1024;
  int k0 = lane * 16;
  float s = 0.f;
  if (k0 + 8 <= 1000) {
    u16x8 u = *reinterpret_cast<const u16x8*>(x + k0);
#pragma unroll
    for (int e = 0; e < 8; ++e) s += bf2f(u[e]) * w3[k0 + e];
  }
  if (k0 + 16 <= 1000) {
    u16x8 u = *reinterpret_cast<const u16x8*>(x + k0 + 8);
#pragma unroll
    for (int e = 0; e < 8; ++e) s += bf2f(u[e]) * w3[k0 + 8 + e];
  }
  s = wred1(s);
  if (lane == 0) atta[r] = 1.f / (1.f + expf(-(s + b3[0])));
}

// -------- core row = relu(LN(P[r1]+Q[r2], ln2)) — wave-per-row, bf16 ---------
__global__ __launch_bounds__(256) void core_build2(
    const u16* __restrict__ PQ, u16* __restrict__ core,
    const float* __restrict__ g2, const float* __restrict__ b2, int c0)
{
  int id = blockIdx.x * 4 + (threadIdx.x >> 6);
  int lane = threadIdx.x & 63;
  int pp = id / 15, j = id - pp * 15;
  int gp = c0 + pp;
  int i = gp & 15;
  int col = j + (j >= i);
  int r2 = (gp & ~15) | col;
  const u16* p = PQ + (size_t)gp * 1024;
  const u16* q = PQ + (size_t)r2 * 1024 + 512;
  int k0 = lane * 8;
  u16x8 up = *reinterpret_cast<const u16x8*>(p + k0);
  u16x8 uq = *reinterpret_cast<const u16x8*>(q + k0);
  float xv[8], s = 0.f, s2 = 0.f;
#pragma unroll
  for (int e = 0; e < 8; ++e) {
    xv[e] = bf2f(up[e]) + bf2f(uq[e]);   // pads are exact zeros
    s += xv[e]; s2 += xv[e] * xv[e];
  }
  wred2(s, s2);
  float mu = s / 500.f;
  float rstd = rsqrtf(s2 / 500.f - mu * mu + EPSF);
  u16x8 o;
#pragma unroll
  for (int e = 0; e < 8; ++e) {
    int k = k0 + e;
    o[e] = (k < 500) ? f2bf(fmaxf((xv[e] - mu) * rstd * g2[k] + b2[k], 0.f)) : (u16)0;
  }
  *reinterpret_cast<u16x8*>(core + (size_t)id * 512 + k0) = o;
}

// -------- fused chunk tail: stats wave-per-row, one barrier, then esum -------
__global__ __launch_bounds__(256) void chunk_post2(
    const u16* __restrict__ V,
    const float* __restrict__ g3, const float* __restrict__ b3,
    const float* __restrict__ g4, const float* __restrict__ b4,
    const float* __restrict__ w5, const float* __restrict__ b5,
    float* __restrict__ esum, int c0)
{
  __shared__ u16 rows[15][512];
  __shared__ float st[15][4];   // mu, rstd, att
  int pp = blockIdx.x, t = threadIdx.x;
  int lane = t & 63, w = t >> 6;

  for (int j = w; j < 15; j += 4) {
    const u16* vr = V + (size_t)(pp * 15 + j) * 640;
    int k0 = lane * 8;
    u16x8 u = *reinterpret_cast<const u16x8*>(vr + k0);
    *reinterpret_cast<u16x8*>(&rows[j][k0]) = u;
    float s = 0.f, s2 = 0.f;
#pragma unroll
    for (int e = 0; e < 8; ++e) { float v = bf2f(u[e]); s += v; s2 += v * v; }
    ushort2 ua = *reinterpret_cast<const ushort2*>(vr + 512 + lane * 2);
    float y0 = bf2f(ua.x), y1 = bf2f(ua.y);
    float sa = y0 + y1, sa2 = y0 * y0 + y1 * y1;
    wred2(s, s2);
    wred2(sa, sa2);
    float mu = s / 500.f;
    float rstd = rsqrtf(s2 / 500.f - mu * mu + EPSF);
    float mu4 = sa / 100.f;
    float rstd4 = rsqrtf(sa2 / 100.f - mu4 * mu4 + EPSF);
    float dv = 0.f;
    int k = lane * 2;
    if (k < 100)     dv += tanhf((y0 - mu4) * rstd4 * g4[k] + b4[k]) * w5[k];
    if (k + 1 < 100) dv += tanhf((y1 - mu4) * rstd4 * g4[k + 1] + b4[k + 1]) * w5[k + 1];
    float D = wred1(dv);
    if (lane == 0) {
      st[j][0] = mu; st[j][1] = rstd;
      st[j][2] = 1.f / (1.f + expf(-(D + b5[0])));
    }
  }
  __syncthreads();

  for (int n = t; n < 500; n += 256) {
    float gg = g3[n], bb = b3[n], acc = 0.f;
#pragma unroll
    for (int j = 0; j < 15; ++j) {
      float v = bf2f(rows[j][n]);
      acc += fmaxf((v - st[j][0]) * st[j][1] * gg + bb, 0.f) * st[j][2];
    }
    esum[(size_t)(c0 + pp) * 500 + n] = acc;
  }
}

// -------- merged transpose+pack: all 9 weight jobs in one dispatch -----------
struct TJob {
  const float* src; u16* dst;
  int K, N, srcLd, ldDst, nOff, kOff, tileBase, tilesX;
};
struct TJobs { TJob j[9]; int total; };

__global__ void pack_weights(TJobs jobs)
{
  __shared__ float tl[32][33];
  int bid = blockIdx.x;
  int ji = 0;
#pragma unroll
  for (int q = 1; q < 9; ++q) if (bid >= jobs.j[q].tileBase) ji = q;
  const TJob& J = jobs.j[ji];
  int t = bid - J.tileBase;
  int bx = t % J.tilesX, by = t / J.tilesX;
  int tx = threadIdx.x, ty = threadIdx.y;   // 32 x 8
  int k0 = by * 32, n0 = bx * 32;
#pragma unroll
  for (int r = 0; r < 4; ++r) {
    int row = k0 + ty + r * 8;
    if (row < J.K && n0 + tx < J.N) tl[ty + r * 8][tx] = J.src[(size_t)row * J.srcLd + n0 + tx];
  }
  __syncthreads();
#pragma unroll
  for (int r = 0; r < 4; ++r) {
    int n = n0 + ty + r * 8, k = k0 + tx;
    if (n < J.N && k < J.K)
      J.dst[(size_t)(n + J.nOff) * J.ldDst + J.kOff + k] = f2bf(tl[tx][ty + r * 8]);
  }
}

// -------- pack padded biases --------------------------------------------------
__global__ void pack_biases(
    const float* ac2, const float* lnf2, const float* f1, const float* f2,
    const float* f3, const float* f4, const float* f6,
    float* b_ac2p, float* b_lnf2p, float* b_f1p, float* b2p, float* b34p, float* b_f6p)
{
  int t = threadIdx.x;  // 1024
  switch (blockIdx.x) {
    case 0: if (t < 512) b_ac2p[t]  = (t < 500) ? ac2[t]  : 0.f; break;
    case 1: if (t < 512) b_lnf2p[t] = (t < 500) ? lnf2[t] : 0.f; break;
    case 2: if (t < 512) b_f1p[t]   = (t < 500) ? f1[t]   : 0.f; break;
    case 3: b2p[t] = (t < 500) ? f2[t] : 0.f; break;
    case 4: if (t < 640) b34p[t] = (t < 500) ? f3[t] : ((t >= 512 && t < 612) ? f4[t - 512] : 0.f); break;
    case 5: if (t < 512) b_f6p[t]   = (t < 500) ? f6[t]   : 0.f; break;
  }
}

extern "C" void kernel_launch(void* const* d_in, const int* in_sizes, int n_in,
                              void* d_out, int out_size, void* d_ws, size_t ws_size,
                              hipStream_t stream)
{
  const float* state    = (const float*)d_in[0];
  const float* actions  = (const float*)d_in[1];
  const float* ac_fc1_w = (const float*)d_in[2];
  const float* ac_fc1_b = (const float*)d_in[3];
  const float* ac_ln1_g = (const float*)d_in[4];
  const float* ac_ln1_b = (const float*)d_in[5];
  const float* ac_fc2_w = (const float*)d_in[6];
  const float* ac_fc2_b = (const float*)d_in[7];
  const float* ac_lnf2_w= (const float*)d_in[8];
  const float* ac_lnf2_b= (const float*)d_in[9];
  const float* ac_fc3_w = (const float*)d_in[10];
  const float* ac_fc3_b = (const float*)d_in[11];
  const float* fc1_w = (const float*)d_in[12];
  const float* fc1_b = (const float*)d_in[13];
  const float* ln1_g = (const float*)d_in[14];
  const float* ln1_b = (const float*)d_in[15];
  const float* fc2_w = (const float*)d_in[16];
  const float* fc2_b = (const float*)d_in[17];
  const float* ln2_g = (const float*)d_in[18];
  const float* ln2_b = (const float*)d_in[19];
  const float* fc3_w = (const float*)d_in[20];
  const float* fc3_b = (const float*)d_in[21];
  const float* ln3_g = (const float*)d_in[22];
  const float* ln3_b = (const float*)d_in[23];
  const float* fc4_w = (const float*)d_in[24];
  const float* fc4_b = (const float*)d_in[25];
  const float* ln4_g = (const float*)d_in[26];
  const float* ln4_b = (const float*)d_in[27];
  const float* fc5_w = (const float*)d_in[28];
  const float* fc5_b = (const float*)d_in[29];
  const float* fc6_w = (const float*)d_in[30];
  const float* fc6_b = (const float*)d_in[31];
  const float* ln6_g = (const float*)d_in[32];
  const float* ln6_b = (const float*)d_in[33];
  float* out = (float*)d_out;

  // ---- ws carve (bytes, 256-aligned); total ~171 MB (< 256 MiB) ----
  char* p = (char*)d_ws;
  auto carve = [&](size_t bytes) { char* r = p; p += (bytes + 255) & ~(size_t)255; return r; };
  u16*   cat    = (u16*)  carve(8192ull * 1024 * 2);   // also 'total'
  u16*   t1     = (u16*)  carve(8192ull * 512 * 2);
  u16*   s2     = (u16*)  carve(8192ull * 512 * 2);
  u16*   s1     = (u16*)  carve(8192ull * 512 * 2);
  u16*   core   = (u16*)  carve(30720ull * 512 * 2);
  u16*   v      = (u16*)  carve(30720ull * 640 * 2);
  float* pre    = (float*)carve(8192ull * 512 * 4);
  u16*   PQ     = (u16*)  carve(8192ull * 1024 * 2);
  float* esum   = (float*)carve(8192ull * 500 * 4);
  u16*   a_buf  = (u16*)  carve(512ull * 512 * 2);
  float* tmp_a  = (float*)carve(512ull * 500 * 4);
  float* att_a  = (float*)carve(8192ull * 4);
  char*  wT0    =         carve(0);
  u16*   ac_fc2T  = (u16*)carve(512ull * 1024 * 2);
  u16*   ac_lnf2T = (u16*)carve(512ull * 512 * 2);
  u16*   fc1T     = (u16*)carve(512ull * 512 * 2);
  u16*   B2T      = (u16*)carve(1024ull * 512 * 2);
  u16*   B34T     = (u16*)carve(640ull * 512 * 2);
  u16*   fc6T     = (u16*)carve(512ull * 1024 * 2);
  size_t wTbytes  = (size_t)((char*)carve(0) - wT0);
  float* b_ac2p  = (float*)carve(512 * 4);
  float* b_lnf2p = (float*)carve(512 * 4);
  float* b_f1p   = (float*)carve(512 * 4);
  float* b2p     = (float*)carve(1024 * 4);
  float* b34p    = (float*)carve(640 * 4);
  float* b_f6p   = (float*)carve(512 * 4);

  dim3 blk(256);
  dim3 tblk(32, 8);

  // ---- weight packing: one memset + one merged transpose dispatch ----
  hipMemsetAsync(wT0, 0, wTbytes, stream);
  TJobs jobs;
  int base = 0;
  auto addjob = [&](int idx, const float* src, u16* dst, int K, int N, int srcLd,
                    int ldDst, int nOff, int kOff) {
    int tx = (N + 31) / 32, ty = (K + 31) / 32;
    jobs.j[idx] = {src, dst, K, N, srcLd, ldDst, nOff, kOff, base, tx};
    base += tx * ty;
  };
  addjob(0, ac_fc2_w,         ac_fc2T,  1000, 500, 500, 1024, 0, 0);
  addjob(1, ac_lnf2_w,        ac_lnf2T,  500, 500, 500,  512, 0, 0);
  addjob(2, fc1_w,            fc1T,      500, 500, 500,  512, 0, 0);
  addjob(3, fc2_w,            B2T,       500, 500, 500,  512, 0, 0);
  addjob(4, fc2_w + 250000,   B2T,       500, 500, 500,  512, 512, 0);
  addjob(5, fc3_w,            B34T,      500, 500, 500,  512, 0, 0);
  addjob(6, fc4_w,            B34T,      500, 100, 100,  512, 512, 0);
  addjob(7, fc6_w,            fc6T,      500, 500, 500, 1024, 0, 0);
  addjob(8, fc6_w + 250000,   fc6T,      500, 500, 500, 1024, 0, 512);
  jobs.total = base;
  pack_weights<<<base, tblk, 0, stream>>>(jobs);
  pack_biases<<<6, 1024, 0, stream>>>(ac_fc2_b, ac_lnf2_b, fc1_b, fc2_b, fc3_b, fc4_b, fc6_b,
                                      b_ac2p, b_lnf2p, b_f1p, b2p, b34p, b_f6p);

  // ---- a = LN(actions @ ac_fc1_w + b) ----
  gemm128<<<dim3(4, 4), blk, 0, stream>>>(actions, ac_fc1_w, ac_fc1_b, tmp_a, 512, 500, 64);
  ln_wave<0, u16><<<128, blk, 0, stream>>>(tmp_a, a_buf, ac_ln1_g, ac_ln1_b, 500, 512);
  build_concat<<<8192, blk, 0, stream>>>(state, a_buf, cat);

  // ---- t1 = cat @ ac_fc2_w + b (bf16); att_a ----
  gemm_mfma<u16><<<dim3(8, 64), blk, 0, stream>>>(cat, ac_fc2T, b_ac2p, nullptr, t1, 8192, 512, 1024);
  dot_sig<<<2048, blk, 0, stream>>>(cat, ac_fc3_w, ac_fc3_b, att_a);
  // ---- s2 = (t1 @ ac_lnf2_w + b) * att_a (bf16) ----
  gemm_mfma<u16><<<dim3(8, 64), blk, 0, stream>>>(t1, ac_lnf2T, b_lnf2p, att_a, s2, 8192, 512, 512);
  // ---- s1 = relu(LN(s2 @ fc1_w + b, ln1)) ----
  gemm_mfma<float><<<dim3(8, 64), blk, 0, stream>>>(s2, fc1T, b_f1p, nullptr, pre, 8192, 512, 512);
  ln_wave<1, u16><<<2048, blk, 0, stream>>>(pre, s1, ln1_g, ln1_b, 512, 512);
  // ---- PQ = s1 @ [fc2_w[:500] | fc2_w[500:]] (bf16) ----
  gemm_mfma<u16><<<dim3(16, 64), blk, 0, stream>>>(s1, B2T, b2p, nullptr, PQ, 8192, 1024, 512);

  for (int c = 0; c < 4; ++c) {
    int c0 = c * 2048;
    core_build2<<<7680, blk, 0, stream>>>(PQ, core, ln2_g, ln2_b, c0);
    gemm_mfma<u16><<<dim3(10, 240), blk, 0, stream>>>(core, B34T, b34p, nullptr, v, 30720, 640, 512);
    chunk_post2<<<2048, blk, 0, stream>>>(v, ln3_g, ln3_b, ln4_g, ln4_b, fc5_w, fc5_b, esum, c0);
  }

  build_total<<<8192, blk, 0, stream>>>(s1, esum, cat);
  gemm_mfma<float><<<dim3(8, 64), blk, 0, stream>>>(cat, fc6T, b_f6p, nullptr, pre, 8192, 512, 1024);
  ln_wave<0, float><<<2048, blk, 0, stream>>>(pre, out, ln6_g, ln6_b, 512, 500);
}

// Round 5
// 574.840 us; speedup vs baseline: 4.4740x; 1.2587x over previous
//
#include <hip/hip_runtime.h>
#include <math.h>

// TheRecurrentNet: B=512, K=16, H=500, A=64, nc=15.
// Round 5: 4-rows-per-wave ILP batching for all wave-per-row kernels
// (core_build, chunk_post stats, ln, dot_sig) to break the serial
// shfl-chain latency wall. GEMMs unchanged from round 4.

#define EPSF 1e-5f
typedef unsigned short u16;
typedef unsigned int u32;

typedef __bf16 bf16x8 __attribute__((ext_vector_type(8)));
typedef float f32x4 __attribute__((ext_vector_type(4)));
typedef u16 u16x8 __attribute__((ext_vector_type(8)));

__device__ __forceinline__ float bf2f(u16 u) {
  return __builtin_bit_cast(float, (u32)u << 16);
}
__device__ __forceinline__ u16 f2bf(float f) {
  u32 u = __builtin_bit_cast(u32, f);
  return (u16)((u + 0x7FFFu + ((u >> 16) & 1u)) >> 16);   // RNE
}

#define GLOAD16(g, l) __builtin_amdgcn_global_load_lds( \
    (__attribute__((address_space(1))) u32*)(g), \
    (__attribute__((address_space(3))) u32*)(l), 16, 0, 0)

// ======================= bf16 MFMA GEMM, 128x64 tile =======================
template <typename TOUT>
__global__ __launch_bounds__(256) void gemm_mfma(
    const u16* __restrict__ A, const u16* __restrict__ Bt,
    const float* __restrict__ bias, const float* __restrict__ rowscale,
    TOUT* __restrict__ C, int M, int Npad, int K)
{
  __shared__ __align__(16) u16 As[128 * 32];   // [row][k]
  __shared__ __align__(16) u16 Bs[64 * 32];    // [col][k]
  const int tid = threadIdx.x;
  const int lane = tid & 63, wid = tid >> 6;
  const size_t row0 = (size_t)blockIdx.y * 128, col0 = (size_t)blockIdx.x * 64;

  f32x4 acc[2][4] = {};

  const int s_row = tid >> 2, s_ch = tid & 3;
  const u16* gA0 = A + (row0 + s_row) * (size_t)K + s_ch * 8;
  const u16* gA1 = gA0 + (size_t)64 * K;
  const u16* gB0 = Bt + (col0 + s_row) * (size_t)K + s_ch * 8;
  u16* lA0 = As + tid * 8;
  u16* lA1 = As + 2048 + tid * 8;
  u16* lB0 = Bs + tid * 8;

  const int fr = lane & 15, fq = lane >> 4;
  const u16* pAf = As + (wid * 32 + fr) * 32 + fq * 8;
  const u16* pBf = Bs + fr * 32 + fq * 8;

  for (int k0 = 0; k0 < K; k0 += 32) {
    GLOAD16(gA0 + k0, lA0);
    GLOAD16(gA1 + k0, lA1);
    GLOAD16(gB0 + k0, lB0);
    __syncthreads();
    bf16x8 af[2], bfv[4];
#pragma unroll
    for (int m = 0; m < 2; ++m) af[m] = *reinterpret_cast<const bf16x8*>(pAf + m * 16 * 32);
#pragma unroll
    for (int n = 0; n < 4; ++n) bfv[n] = *reinterpret_cast<const bf16x8*>(pBf + n * 16 * 32);
#pragma unroll
    for (int m = 0; m < 2; ++m)
#pragma unroll
      for (int n = 0; n < 4; ++n)
        acc[m][n] = __builtin_amdgcn_mfma_f32_16x16x32_bf16(af[m], bfv[n], acc[m][n], 0, 0, 0);
    __syncthreads();
  }

  const int cl = lane & 15, rg = lane >> 4;
#pragma unroll
  for (int m = 0; m < 2; ++m) {
#pragma unroll
    for (int n = 0; n < 4; ++n) {
      size_t col = col0 + n * 16 + cl;
      float bv = bias[col];
#pragma unroll
      for (int r = 0; r < 4; ++r) {
        size_t row = row0 + wid * 32 + m * 16 + rg * 4 + r;
        float v = acc[m][n][r] + bv;
        if (rowscale) v *= rowscale[row];
        if constexpr (sizeof(TOUT) == 2) C[row * Npad + col] = f2bf(v);
        else                             C[row * Npad + col] = v;
      }
    }
  }
}

// ---------------- small f32 GEMM (actions @ ac_fc1_w) ------------------------
__global__ __launch_bounds__(256) void gemm128(
    const float* __restrict__ A, const float* __restrict__ B,
    const float* __restrict__ bias, float* __restrict__ C, int M, int N, int K)
{
  __shared__ float As[16][132];
  __shared__ float Bs[16][128];
  const int tid = threadIdx.x;
  const int tx = tid & 15, ty = tid >> 4;
  const int row0 = blockIdx.y * 128, col0 = blockIdx.x * 128;
  float acc[8][8];
#pragma unroll
  for (int i = 0; i < 8; ++i)
#pragma unroll
    for (int j = 0; j < 8; ++j) acc[i][j] = 0.f;

  const int nkt = (K + 15) >> 4;
  for (int kt = 0; kt < nkt; ++kt) {
    const int k0 = kt << 4;
#pragma unroll
    for (int h = 0; h < 2; ++h) {
      int i = tid + h * 256;
      int m = i >> 2, kk = (i & 3) << 2;
      int gm = row0 + m, gk = k0 + kk;
      float4 v = make_float4(0.f, 0.f, 0.f, 0.f);
      if (gm < M && gk < K) v = *reinterpret_cast<const float4*>(A + (size_t)gm * K + gk);
      As[kk + 0][m] = v.x; As[kk + 1][m] = v.y; As[kk + 2][m] = v.z; As[kk + 3][m] = v.w;
    }
#pragma unroll
    for (int h = 0; h < 2; ++h) {
      int i = tid + h * 256;
      int kk = i >> 5, n = (i & 31) << 2;
      int gk = k0 + kk, gn = col0 + n;
      float4 v = make_float4(0.f, 0.f, 0.f, 0.f);
      if (gk < K && gn < N) v = *reinterpret_cast<const float4*>(B + (size_t)gk * N + gn);
      *reinterpret_cast<float4*>(&Bs[kk][n]) = v;
    }
    __syncthreads();
#pragma unroll
    for (int kk = 0; kk < 16; ++kk) {
      float4 a0 = *reinterpret_cast<const float4*>(&As[kk][ty * 4]);
      float4 a1 = *reinterpret_cast<const float4*>(&As[kk][ty * 4 + 64]);
      float4 b0 = *reinterpret_cast<const float4*>(&Bs[kk][tx * 4]);
      float4 b1 = *reinterpret_cast<const float4*>(&Bs[kk][tx * 4 + 64]);
      float av[8] = {a0.x, a0.y, a0.z, a0.w, a1.x, a1.y, a1.z, a1.w};
      float bv[8] = {b0.x, b0.y, b0.z, b0.w, b1.x, b1.y, b1.z, b1.w};
#pragma unroll
      for (int i = 0; i < 8; ++i)
#pragma unroll
        for (int j = 0; j < 8; ++j) acc[i][j] += av[i] * bv[j];
    }
    __syncthreads();
  }
#pragma unroll
  for (int i = 0; i < 8; ++i) {
    int gm = row0 + ty * 4 + ((i >> 2) << 6) + (i & 3);
    if (gm >= M) continue;
#pragma unroll
    for (int j = 0; j < 8; ++j) {
      int gn = col0 + tx * 4 + ((j >> 2) << 6) + (j & 3);
      if (gn < N) C[(size_t)gm * N + gn] = acc[i][j] + bias[gn];
    }
  }
}

// ------------- wave-per-4-rows LayerNorm (cols=500), f32 in ------------------
// 16 rows/block. TOUT=u16 -> ldy=512 (pads zeroed).
template <int ACT, typename TOUT>
__global__ __launch_bounds__(256) void ln_wave4(
    const float* __restrict__ X, TOUT* __restrict__ Y,
    const float* __restrict__ g, const float* __restrict__ b,
    int ldx, int ldy)
{
  int w = threadIdx.x >> 6, lane = threadIdx.x & 63;
  int id0 = (blockIdx.x * 4 + w) * 4;
  int k0 = lane * 8;
  float xv[4][8], s[4], s2[4];
#pragma unroll
  for (int r = 0; r < 4; ++r) {
    const float* x = X + (size_t)(id0 + r) * ldx;
    if (k0 + 8 <= 500) {
      float4 a = *reinterpret_cast<const float4*>(x + k0);
      float4 c = *reinterpret_cast<const float4*>(x + k0 + 4);
      xv[r][0] = a.x; xv[r][1] = a.y; xv[r][2] = a.z; xv[r][3] = a.w;
      xv[r][4] = c.x; xv[r][5] = c.y; xv[r][6] = c.z; xv[r][7] = c.w;
    } else {
#pragma unroll
      for (int e = 0; e < 8; ++e) xv[r][e] = (k0 + e < 500) ? x[k0 + e] : 0.f;
    }
    s[r] = 0.f; s2[r] = 0.f;
#pragma unroll
    for (int e = 0; e < 8; ++e) { s[r] += xv[r][e]; s2[r] += xv[r][e] * xv[r][e]; }
  }
#pragma unroll
  for (int m = 32; m; m >>= 1)
#pragma unroll
    for (int r = 0; r < 4; ++r) {
      s[r] += __shfl_xor(s[r], m);
      s2[r] += __shfl_xor(s2[r], m);
    }
  float gv[8], bv[8];
#pragma unroll
  for (int e = 0; e < 8; ++e) {
    int k = k0 + e;
    gv[e] = (k < 500) ? g[k] : 0.f;
    bv[e] = (k < 500) ? b[k] : 0.f;
  }
#pragma unroll
  for (int r = 0; r < 4; ++r) {
    float mu = s[r] / 500.f;
    float rstd = rsqrtf(s2[r] / 500.f - mu * mu + EPSF);
    float ov[8];
#pragma unroll
    for (int e = 0; e < 8; ++e) {
      float v = (k0 + e < 500) ? ((xv[r][e] - mu) * rstd * gv[e] + bv[e]) : 0.f;
      if (ACT == 1) v = fmaxf(v, 0.f);
      ov[e] = v;
    }
    if constexpr (sizeof(TOUT) == 2) {
      u16x8 o;
#pragma unroll
      for (int e = 0; e < 8; ++e) o[e] = f2bf(ov[e]);
      *reinterpret_cast<u16x8*>((u16*)Y + (size_t)(id0 + r) * ldy + k0) = o;
    } else {
      float* y = (float*)Y + (size_t)(id0 + r) * ldy;
      if (k0 + 4 <= 500)
        *reinterpret_cast<float4*>(y + k0) = make_float4(ov[0], ov[1], ov[2], ov[3]);
      if (k0 + 8 <= 500)
        *reinterpret_cast<float4*>(y + k0 + 4) = make_float4(ov[4], ov[5], ov[6], ov[7]);
    }
  }
}

// ---------------- cat[r] = [bf16(state[r]) | a[r>>4] | 0pad] -----------------
__global__ __launch_bounds__(256) void build_concat(
    const float* __restrict__ state, const u16* __restrict__ a, u16* __restrict__ cat)
{
  int r = blockIdx.x, t = threadIdx.x;
  int b = r >> 4;
  u16* c = cat + (size_t)r * 1024;
  if (t < 125) {
    float4 v = *reinterpret_cast<const float4*>(state + (size_t)r * 500 + t * 4);
    ushort4 o; o.x = f2bf(v.x); o.y = f2bf(v.y); o.z = f2bf(v.z); o.w = f2bf(v.w);
    *reinterpret_cast<ushort4*>(c + t * 4) = o;
    *reinterpret_cast<ushort4*>(c + 500 + t * 4) =
        *reinterpret_cast<const ushort4*>(a + (size_t)b * 512 + t * 4);
  }
  if (t < 24) c[1000 + t] = 0;
}

// ---------------- total[r] = [s1[r] | 0 | bf16(esum[r]) | 0] -----------------
__global__ __launch_bounds__(256) void build_total(
    const u16* __restrict__ s1, const float* __restrict__ esum, u16* __restrict__ tot)
{
  int r = blockIdx.x, t = threadIdx.x;
  u16* c = tot + (size_t)r * 1024;
  if (t < 125) {
    *reinterpret_cast<ushort4*>(c + t * 4) =
        *reinterpret_cast<const ushort4*>(s1 + (size_t)r * 512 + t * 4);
    float4 v = *reinterpret_cast<const float4*>(esum + (size_t)r * 500 + t * 4);
    ushort4 o; o.x = f2bf(v.x); o.y = f2bf(v.y); o.z = f2bf(v.z); o.w = f2bf(v.w);
    *reinterpret_cast<ushort4*>(c + 512 + t * 4) = o;
  }
  if (t < 12) { c[500 + t] = 0; c[1012 + t] = 0; }
}

// -------- att_a: 4 rows per wave ---------------------------------------------
__global__ __launch_bounds__(256) void dot_sig4(
    const u16* __restrict__ cat, const float* __restrict__ w3,
    const float* __restrict__ b3, float* __restrict__ atta)
{
  int w = threadIdx.x >> 6, lane = threadIdx.x & 63;
  int r0 = (blockIdx.x * 4 + w) * 4;
  int k0 = lane * 16;
  float wv[16];
#pragma unroll
  for (int e = 0; e < 16; ++e) wv[e] = (k0 + e < 1000) ? w3[k0 + e] : 0.f;
  float s[4];
#pragma unroll
  for (int r = 0; r < 4; ++r) {
    const u16* x = cat + (size_t)(r0 + r) * 1024 + k0;
    u16x8 u0 = *reinterpret_cast<const u16x8*>(x);
    u16x8 u1 = *reinterpret_cast<const u16x8*>(x + 8);
    float acc = 0.f;
#pragma unroll
    for (int e = 0; e < 8; ++e) acc += bf2f(u0[e]) * wv[e];
#pragma unroll
    for (int e = 0; e < 8; ++e) acc += bf2f(u1[e]) * wv[8 + e];
    s[r] = acc;   // cat pads (1000:1024) are zero; wv guarded anyway
  }
#pragma unroll
  for (int m = 32; m; m >>= 1)
#pragma unroll
    for (int r = 0; r < 4; ++r) s[r] += __shfl_xor(s[r], m);
  if (lane == 0) {
#pragma unroll
    for (int r = 0; r < 4; ++r)
      atta[r0 + r] = 1.f / (1.f + expf(-(s[r] + b3[0])));
  }
}

// -------- core rows = relu(LN(P[r1]+Q[r2], ln2)) — 4 rows/wave, bf16 ---------
__global__ __launch_bounds__(256) void core_build3(
    const u16* __restrict__ PQ, u16* __restrict__ core,
    const float* __restrict__ g2, const float* __restrict__ b2, int c0)
{
  int w = threadIdx.x >> 6, lane = threadIdx.x & 63;
  int id0 = (blockIdx.x * 4 + w) * 4;    // 4 rows per wave, 16 per block
  int k0 = lane * 8;
  u16x8 up[4], uq[4];
#pragma unroll
  for (int r = 0; r < 4; ++r) {
    int id = id0 + r;
    int pp = id / 15, j = id - pp * 15;
    int gp = c0 + pp, i = gp & 15;
    int col = j + (j >= i);
    int r2 = (gp & ~15) | col;
    up[r] = *reinterpret_cast<const u16x8*>(PQ + (size_t)gp * 1024 + k0);
    uq[r] = *reinterpret_cast<const u16x8*>(PQ + (size_t)r2 * 1024 + 512 + k0);
  }
  float xv[4][8], s[4], s2[4];
#pragma unroll
  for (int r = 0; r < 4; ++r) {
    s[r] = 0.f; s2[r] = 0.f;
#pragma unroll
    for (int e = 0; e < 8; ++e) {
      float v = bf2f(up[r][e]) + bf2f(uq[r][e]);   // pads are exact zeros
      xv[r][e] = v; s[r] += v; s2[r] += v * v;
    }
  }
#pragma unroll
  for (int m = 32; m; m >>= 1)
#pragma unroll
    for (int r = 0; r < 4; ++r) {
      s[r] += __shfl_xor(s[r], m);
      s2[r] += __shfl_xor(s2[r], m);
    }
  float gv[8], bv[8];
#pragma unroll
  for (int e = 0; e < 8; ++e) {
    int k = k0 + e;
    gv[e] = (k < 500) ? g2[k] : 0.f;
    bv[e] = (k < 500) ? b2[k] : 0.f;
  }
#pragma unroll
  for (int r = 0; r < 4; ++r) {
    float mu = s[r] / 500.f;
    float rstd = rsqrtf(s2[r] / 500.f - mu * mu + EPSF);
    u16x8 o;
#pragma unroll
    for (int e = 0; e < 8; ++e)
      o[e] = (k0 + e < 500) ? f2bf(fmaxf((xv[r][e] - mu) * rstd * gv[e] + bv[e], 0.f)) : (u16)0;
    *reinterpret_cast<u16x8*>(core + (size_t)(id0 + r) * 512 + k0) = o;
  }
}

// -------- fused chunk tail: interleaved 4-rows/wave stats, 1 barrier ---------
__global__ __launch_bounds__(256) void chunk_post3(
    const u16* __restrict__ V,
    const float* __restrict__ g3, const float* __restrict__ b3,
    const float* __restrict__ g4, const float* __restrict__ b4,
    const float* __restrict__ w5, const float* __restrict__ b5,
    float* __restrict__ esum, int c0)
{
  __shared__ u16 rows[15][512];
  __shared__ float st[15][4];   // mu, rstd, att
  int pp = blockIdx.x, t = threadIdx.x;
  int lane = t & 63, w = t >> 6;
  int k0 = lane * 8;
  int kk = lane * 2;

  u16x8 u[4]; ushort2 ua[4];
#pragma unroll
  for (int r = 0; r < 4; ++r) {
    int j = w * 4 + r;
    if (j < 15) {
      const u16* vr = V + (size_t)(pp * 15 + j) * 640;
      u[r] = *reinterpret_cast<const u16x8*>(vr + k0);
      ua[r] = *reinterpret_cast<const ushort2*>(vr + 512 + kk);
    }
  }
  float s[4], s2[4], sa[4], sa2[4], y0[4], y1[4];
#pragma unroll
  for (int r = 0; r < 4; ++r) {
    s[r] = s2[r] = sa[r] = sa2[r] = 0.f; y0[r] = y1[r] = 0.f;
    int j = w * 4 + r;
    if (j < 15) {
#pragma unroll
      for (int e = 0; e < 8; ++e) { float v = bf2f(u[r][e]); s[r] += v; s2[r] += v * v; }
      y0[r] = bf2f(ua[r].x); y1[r] = bf2f(ua[r].y);
      sa[r] = y0[r] + y1[r]; sa2[r] = y0[r] * y0[r] + y1[r] * y1[r];
      *reinterpret_cast<u16x8*>(&rows[j][k0]) = u[r];
    }
  }
#pragma unroll
  for (int m = 32; m; m >>= 1)
#pragma unroll
    for (int r = 0; r < 4; ++r) {
      s[r]   += __shfl_xor(s[r], m);
      s2[r]  += __shfl_xor(s2[r], m);
      sa[r]  += __shfl_xor(sa[r], m);
      sa2[r] += __shfl_xor(sa2[r], m);
    }
  float dv[4];
#pragma unroll
  for (int r = 0; r < 4; ++r) {
    float mu4 = sa[r] / 100.f;
    float rstd4 = rsqrtf(sa2[r] / 100.f - mu4 * mu4 + EPSF);
    float d = 0.f;
    if (kk < 100)     d += tanhf((y0[r] - mu4) * rstd4 * g4[kk] + b4[kk]) * w5[kk];
    if (kk + 1 < 100) d += tanhf((y1[r] - mu4) * rstd4 * g4[kk + 1] + b4[kk + 1]) * w5[kk + 1];
    dv[r] = d;
  }
#pragma unroll
  for (int m = 32; m; m >>= 1)
#pragma unroll
    for (int r = 0; r < 4; ++r) dv[r] += __shfl_xor(dv[r], m);
  if (lane == 0) {
#pragma unroll
    for (int r = 0; r < 4; ++r) {
      int j = w * 4 + r;
      if (j < 15) {
        float mu = s[r] / 500.f;
        st[j][0] = mu;
        st[j][1] = rsqrtf(s2[r] / 500.f - mu * mu + EPSF);
        st[j][2] = 1.f / (1.f + expf(-(dv[r] + b5[0])));
      }
    }
  }
  __syncthreads();

  for (int n = t; n < 500; n += 256) {
    float gg = g3[n], bb = b3[n], acc = 0.f;
#pragma unroll
    for (int j = 0; j < 15; ++j) {
      float v = bf2f(rows[j][n]);
      acc += fmaxf((v - st[j][0]) * st[j][1] * gg + bb, 0.f) * st[j][2];
    }
    esum[(size_t)(c0 + pp) * 500 + n] = acc;
  }
}

// -------- merged transpose+pack: all 9 weight jobs in one dispatch -----------
struct TJob {
  const float* src; u16* dst;
  int K, N, srcLd, ldDst, nOff, kOff, tileBase, tilesX;
};
struct TJobs { TJob j[9]; int total; };

__global__ void pack_weights(TJobs jobs)
{
  __shared__ float tl[32][33];
  int bid = blockIdx.x;
  int ji = 0;
#pragma unroll
  for (int q = 1; q < 9; ++q) if (bid >= jobs.j[q].tileBase) ji = q;
  const TJob& J = jobs.j[ji];
  int t = bid - J.tileBase;
  int bx = t % J.tilesX, by = t / J.tilesX;
  int tx = threadIdx.x, ty = threadIdx.y;   // 32 x 8
  int k0 = by * 32, n0 = bx * 32;
#pragma unroll
  for (int r = 0; r < 4; ++r) {
    int row = k0 + ty + r * 8;
    if (row < J.K && n0 + tx < J.N) tl[ty + r * 8][tx] = J.src[(size_t)row * J.srcLd + n0 + tx];
  }
  __syncthreads();
#pragma unroll
  for (int r = 0; r < 4; ++r) {
    int n = n0 + ty + r * 8, k = k0 + tx;
    if (n < J.N && k < J.K)
      J.dst[(size_t)(n + J.nOff) * J.ldDst + J.kOff + k] = f2bf(tl[tx][ty + r * 8]);
  }
}

// -------- pack padded biases --------------------------------------------------
__global__ void pack_biases(
    const float* ac2, const float* lnf2, const float* f1, const float* f2,
    const float* f3, const float* f4, const float* f6,
    float* b_ac2p, float* b_lnf2p, float* b_f1p, float* b2p, float* b34p, float* b_f6p)
{
  int t = threadIdx.x;  // 1024
  switch (blockIdx.x) {
    case 0: if (t < 512) b_ac2p[t]  = (t < 500) ? ac2[t]  : 0.f; break;
    case 1: if (t < 512) b_lnf2p[t] = (t < 500) ? lnf2[t] : 0.f; break;
    case 2: if (t < 512) b_f1p[t]   = (t < 500) ? f1[t]   : 0.f; break;
    case 3: b2p[t] = (t < 500) ? f2[t] : 0.f; break;
    case 4: if (t < 640) b34p[t] = (t < 500) ? f3[t] : ((t >= 512 && t < 612) ? f4[t - 512] : 0.f); break;
    case 5: if (t < 512) b_f6p[t]   = (t < 500) ? f6[t]   : 0.f; break;
  }
}

extern "C" void kernel_launch(void* const* d_in, const int* in_sizes, int n_in,
                              void* d_out, int out_size, void* d_ws, size_t ws_size,
                              hipStream_t stream)
{
  const float* state    = (const float*)d_in[0];
  const float* actions  = (const float*)d_in[1];
  const float* ac_fc1_w = (const float*)d_in[2];
  const float* ac_fc1_b = (const float*)d_in[3];
  const float* ac_ln1_g = (const float*)d_in[4];
  const float* ac_ln1_b = (const float*)d_in[5];
  const float* ac_fc2_w = (const float*)d_in[6];
  const float* ac_fc2_b = (const float*)d_in[7];
  const float* ac_lnf2_w= (const float*)d_in[8];
  const float* ac_lnf2_b= (const float*)d_in[9];
  const float* ac_fc3_w = (const float*)d_in[10];
  const float* ac_fc3_b = (const float*)d_in[11];
  const float* fc1_w = (const float*)d_in[12];
  const float* fc1_b = (const float*)d_in[13];
  const float* ln1_g = (const float*)d_in[14];
  const float* ln1_b = (const float*)d_in[15];
  const float* fc2_w = (const float*)d_in[16];
  const float* fc2_b = (const float*)d_in[17];
  const float* ln2_g = (const float*)d_in[18];
  const float* ln2_b = (const float*)d_in[19];
  const float* fc3_w = (const float*)d_in[20];
  const float* fc3_b = (const float*)d_in[21];
  const float* ln3_g = (const float*)d_in[22];
  const float* ln3_b = (const float*)d_in[23];
  const float* fc4_w = (const float*)d_in[24];
  const float* fc4_b = (const float*)d_in[25];
  const float* ln4_g = (const float*)d_in[26];
  const float* ln4_b = (const float*)d_in[27];
  const float* fc5_w = (const float*)d_in[28];
  const float* fc5_b = (const float*)d_in[29];
  const float* fc6_w = (const float*)d_in[30];
  const float* fc6_b = (const float*)d_in[31];
  const float* ln6_g = (const float*)d_in[32];
  const float* ln6_b = (const float*)d_in[33];
  float* out = (float*)d_out;

  // ---- ws carve (bytes, 256-aligned); total ~171 MB ----
  char* p = (char*)d_ws;
  auto carve = [&](size_t bytes) { char* r = p; p += (bytes + 255) & ~(size_t)255; return r; };
  u16*   cat    = (u16*)  carve(8192ull * 1024 * 2);   // also 'total'
  u16*   t1     = (u16*)  carve(8192ull * 512 * 2);
  u16*   s2     = (u16*)  carve(8192ull * 512 * 2);
  u16*   s1     = (u16*)  carve(8192ull * 512 * 2);
  u16*   core   = (u16*)  carve(30720ull * 512 * 2);
  u16*   v      = (u16*)  carve(30720ull * 640 * 2);
  float* pre    = (float*)carve(8192ull * 512 * 4);
  u16*   PQ     = (u16*)  carve(8192ull * 1024 * 2);
  float* esum   = (float*)carve(8192ull * 500 * 4);
  u16*   a_buf  = (u16*)  carve(512ull * 512 * 2);
  float* tmp_a  = (float*)carve(512ull * 500 * 4);
  float* att_a  = (float*)carve(8192ull * 4);
  char*  wT0    =         carve(0);
  u16*   ac_fc2T  = (u16*)carve(512ull * 1024 * 2);
  u16*   ac_lnf2T = (u16*)carve(512ull * 512 * 2);
  u16*   fc1T     = (u16*)carve(512ull * 512 * 2);
  u16*   B2T      = (u16*)carve(1024ull * 512 * 2);
  u16*   B34T     = (u16*)carve(640ull * 512 * 2);
  u16*   fc6T     = (u16*)carve(512ull * 1024 * 2);
  size_t wTbytes  = (size_t)((char*)carve(0) - wT0);
  float* b_ac2p  = (float*)carve(512 * 4);
  float* b_lnf2p = (float*)carve(512 * 4);
  float* b_f1p   = (float*)carve(512 * 4);
  float* b2p     = (float*)carve(1024 * 4);
  float* b34p    = (float*)carve(640 * 4);
  float* b_f6p   = (float*)carve(512 * 4);

  dim3 blk(256);
  dim3 tblk(32, 8);

  // ---- weight packing: one memset + one merged transpose dispatch ----
  hipMemsetAsync(wT0, 0, wTbytes, stream);
  TJobs jobs;
  int base = 0;
  auto addjob = [&](int idx, const float* src, u16* dst, int K, int N, int srcLd,
                    int ldDst, int nOff, int kOff) {
    int tx = (N + 31) / 32, ty = (K + 31) / 32;
    jobs.j[idx] = {src, dst, K, N, srcLd, ldDst, nOff, kOff, base, tx};
    base += tx * ty;
  };
  addjob(0, ac_fc2_w,         ac_fc2T,  1000, 500, 500, 1024, 0, 0);
  addjob(1, ac_lnf2_w,        ac_lnf2T,  500, 500, 500,  512, 0, 0);
  addjob(2, fc1_w,            fc1T,      500, 500, 500,  512, 0, 0);
  addjob(3, fc2_w,            B2T,       500, 500, 500,  512, 0, 0);
  addjob(4, fc2_w + 250000,   B2T,       500, 500, 500,  512, 512, 0);
  addjob(5, fc3_w,            B34T,      500, 500, 500,  512, 0, 0);
  addjob(6, fc4_w,            B34T,      500, 100, 100,  512, 512, 0);
  addjob(7, fc6_w,            fc6T,      500, 500, 500, 1024, 0, 0);
  addjob(8, fc6_w + 250000,   fc6T,      500, 500, 500, 1024, 0, 512);
  jobs.total = base;
  pack_weights<<<base, tblk, 0, stream>>>(jobs);
  pack_biases<<<6, 1024, 0, stream>>>(ac_fc2_b, ac_lnf2_b, fc1_b, fc2_b, fc3_b, fc4_b, fc6_b,
                                      b_ac2p, b_lnf2p, b_f1p, b2p, b34p, b_f6p);

  // ---- a = LN(actions @ ac_fc1_w + b) ----
  gemm128<<<dim3(4, 4), blk, 0, stream>>>(actions, ac_fc1_w, ac_fc1_b, tmp_a, 512, 500, 64);
  ln_wave4<0, u16><<<32, blk, 0, stream>>>(tmp_a, a_buf, ac_ln1_g, ac_ln1_b, 500, 512);
  build_concat<<<8192, blk, 0, stream>>>(state, a_buf, cat);

  // ---- t1 = cat @ ac_fc2_w + b (bf16); att_a ----
  gemm_mfma<u16><<<dim3(8, 64), blk, 0, stream>>>(cat, ac_fc2T, b_ac2p, nullptr, t1, 8192, 512, 1024);
  dot_sig4<<<512, blk, 0, stream>>>(cat, ac_fc3_w, ac_fc3_b, att_a);
  // ---- s2 = (t1 @ ac_lnf2_w + b) * att_a (bf16) ----
  gemm_mfma<u16><<<dim3(8, 64), blk, 0, stream>>>(t1, ac_lnf2T, b_lnf2p, att_a, s2, 8192, 512, 512);
  // ---- s1 = relu(LN(s2 @ fc1_w + b, ln1)) ----
  gemm_mfma<float><<<dim3(8, 64), blk, 0, stream>>>(s2, fc1T, b_f1p, nullptr, pre, 8192, 512, 512);
  ln_wave4<1, u16><<<512, blk, 0, stream>>>(pre, s1, ln1_g, ln1_b, 512, 512);
  // ---- PQ = s1 @ [fc2_w[:500] | fc2_w[500:]] (bf16) ----
  gemm_mfma<u16><<<dim3(16, 64), blk, 0, stream>>>(s1, B2T, b2p, nullptr, PQ, 8192, 1024, 512);

  for (int c = 0; c < 4; ++c) {
    int c0 = c * 2048;
    core_build3<<<1920, blk, 0, stream>>>(PQ, core, ln2_g, ln2_b, c0);
    gemm_mfma<u16><<<dim3(10, 240), blk, 0, stream>>>(core, B34T, b34p, nullptr, v, 30720, 640, 512);
    chunk_post3<<<2048, blk, 0, stream>>>(v, ln3_g, ln3_b, ln4_g, ln4_b, fc5_w, fc5_b, esum, c0);
  }

  build_total<<<8192, blk, 0, stream>>>(s1, esum, cat);
  gemm_mfma<float><<<dim3(8, 64), blk, 0, stream>>>(cat, fc6T, b_f6p, nullptr, pre, 8192, 512, 1024);
  ln_wave4<0, float><<<512, blk, 0, stream>>>(pre, out, ln6_g, ln6_b, 512, 500);
}

// Round 6
// 490.442 us; speedup vs baseline: 5.2439x; 1.1721x over previous
//
#include <hip/hip_runtime.h>
#include <math.h>

// TheRecurrentNet: B=512, K=16, H=500, A=64, nc=15.
// Round 6: GEMM rewrite — BK=64 double-buffered single-barrier K-loop,
// LDS XOR-swizzle (conflict-free ds_read_b128), XCD-aware block swizzle
// (A-panel L2 locality). Everything else unchanged from round 5.

#define EPSF 1e-5f
typedef unsigned short u16;
typedef unsigned int u32;

typedef __bf16 bf16x8 __attribute__((ext_vector_type(8)));
typedef float f32x4 __attribute__((ext_vector_type(4)));
typedef u16 u16x8 __attribute__((ext_vector_type(8)));

__device__ __forceinline__ float bf2f(u16 u) {
  return __builtin_bit_cast(float, (u32)u << 16);
}
__device__ __forceinline__ u16 f2bf(float f) {
  u32 u = __builtin_bit_cast(u32, f);
  return (u16)((u + 0x7FFFu + ((u >> 16) & 1u)) >> 16);   // RNE
}

#define GLOAD16(g, l) __builtin_amdgcn_global_load_lds( \
    (__attribute__((address_space(1))) u32*)(g), \
    (__attribute__((address_space(3))) u32*)(l), 16, 0, 0)

// ======================= bf16 MFMA GEMM, 128x64 tile, BK=64 ==================
// C[M,Npad] = A[M,K](bf16) @ Bt[Npad,K]^T(bf16) + bias, optional *rowscale.
// M%128==0, Npad%64==0, K%64==0, grid (Npad/64, M/128), nwg%8==0.
// Double-buffered LDS, one barrier per K-step. LDS swizzle: 16B-chunk c of
// row r lives at slot c^(r&7) -> ds_read_b128 is 2-way (free).
// XCD swizzle: col-fast chunks per XCD -> each A panel fetched by one XCD.
template <typename TOUT>
__global__ __launch_bounds__(256) void gemm_mfma(
    const u16* __restrict__ A, const u16* __restrict__ Bt,
    const float* __restrict__ bias, const float* __restrict__ rowscale,
    TOUT* __restrict__ C, int M, int Npad, int K)
{
  __shared__ __align__(16) u16 As[2][128 * 64];   // slot = row*8 + chunk (16B chunks)
  __shared__ __align__(16) u16 Bs[2][64 * 64];
  const int tid = threadIdx.x;
  const int lane = tid & 63, wid = tid >> 6;

  // ---- XCD-aware block swizzle (requires nwg % 8 == 0; true for all call sites)
  const int ncols = gridDim.x;
  const int nwg = ncols * gridDim.y;
  const int bid = blockIdx.y * ncols + blockIdx.x;
  const int swz = (bid & 7) * (nwg >> 3) + (bid >> 3);
  const size_t row0 = (size_t)(swz / ncols) * 128;
  const size_t col0 = (size_t)(swz % ncols) * 64;

  f32x4 acc[2][4] = {};

  // ---- staging precompute: instruction h covers slot s = h*256+tid
  // row = h*32 + (tid>>3); LDS gets chunk (tid&7), whose DATA chunk is
  // (tid&7)^(row&7) = (tid&7)^((tid>>3)&7)  (h*32 doesn't affect row&7)
  const int s_sub = tid >> 3;                       // row within 32-row group
  const int s_chunk = (tid & 7) ^ (s_sub & 7);      // pre-swizzled source chunk
  const u16* gA = A + (row0 + s_sub) * (size_t)K + s_chunk * 8;
  const u16* gB = Bt + (col0 + s_sub) * (size_t)K + s_chunk * 8;

  // ---- fragment read precompute
  const int fr = lane & 15, fq = lane >> 4;
  const int cx0 = fq ^ (fr & 7);          // swizzled chunk for ks=0
  const int cx1 = (4 + fq) ^ (fr & 7);    // swizzled chunk for ks=1

  const int nkt = K >> 6;
  int cur = 0;

  // prologue: stage K-tile 0 into buffer 0
  {
    const u16* a = gA; const u16* b = gB;
#pragma unroll
    for (int h = 0; h < 4; ++h)
      GLOAD16(a + (size_t)h * 32 * K, &As[0][(h * 256 + tid) * 8]);
#pragma unroll
    for (int h = 0; h < 2; ++h)
      GLOAD16(b + (size_t)h * 32 * K, &Bs[0][(h * 256 + tid) * 8]);
  }
  __syncthreads();

  for (int kt = 0; kt < nkt; ++kt) {
    // stage next K-tile into the other buffer (overlaps with compute below)
    if (kt + 1 < nkt) {
      const u16* a = gA + (size_t)(kt + 1) * 64;
      const u16* b = gB + (size_t)(kt + 1) * 64;
#pragma unroll
      for (int h = 0; h < 4; ++h)
        GLOAD16(a + (size_t)h * 32 * K, &As[cur ^ 1][(h * 256 + tid) * 8]);
#pragma unroll
      for (int h = 0; h < 2; ++h)
        GLOAD16(b + (size_t)h * 32 * K, &Bs[cur ^ 1][(h * 256 + tid) * 8]);
    }
    // compute on current buffer: 2 k-sub-steps of 32
    const u16* as = As[cur];
    const u16* bs = Bs[cur];
#pragma unroll
    for (int ks = 0; ks < 2; ++ks) {
      const int cx = ks ? cx1 : cx0;
      bf16x8 af[2], bf[4];
#pragma unroll
      for (int m = 0; m < 2; ++m) {
        int row = wid * 32 + m * 16 + fr;
        af[m] = *reinterpret_cast<const bf16x8*>(as + (row * 8 + cx) * 8);
      }
#pragma unroll
      for (int n = 0; n < 4; ++n) {
        int row = n * 16 + fr;
        bf[n] = *reinterpret_cast<const bf16x8*>(bs + (row * 8 + cx) * 8);
      }
#pragma unroll
      for (int m = 0; m < 2; ++m)
#pragma unroll
        for (int n = 0; n < 4; ++n)
          acc[m][n] = __builtin_amdgcn_mfma_f32_16x16x32_bf16(af[m], bf[n], acc[m][n], 0, 0, 0);
    }
    __syncthreads();   // drains vmcnt (stage done) + lgkmcnt; buffers flip
    cur ^= 1;
  }

  // epilogue: C/D layout col=lane&15, row=(lane>>4)*4+reg
  const int cl = lane & 15, rg = lane >> 4;
#pragma unroll
  for (int m = 0; m < 2; ++m) {
#pragma unroll
    for (int n = 0; n < 4; ++n) {
      size_t col = col0 + n * 16 + cl;
      float bv = bias[col];
#pragma unroll
      for (int r = 0; r < 4; ++r) {
        size_t row = row0 + wid * 32 + m * 16 + rg * 4 + r;
        float v = acc[m][n][r] + bv;
        if (rowscale) v *= rowscale[row];
        if constexpr (sizeof(TOUT) == 2) C[row * Npad + col] = f2bf(v);
        else                             C[row * Npad + col] = v;
      }
    }
  }
}

// ---------------- small f32 GEMM (actions @ ac_fc1_w) ------------------------
__global__ __launch_bounds__(256) void gemm128(
    const float* __restrict__ A, const float* __restrict__ B,
    const float* __restrict__ bias, float* __restrict__ C, int M, int N, int K)
{
  __shared__ float As[16][132];
  __shared__ float Bs[16][128];
  const int tid = threadIdx.x;
  const int tx = tid & 15, ty = tid >> 4;
  const int row0 = blockIdx.y * 128, col0 = blockIdx.x * 128;
  float acc[8][8];
#pragma unroll
  for (int i = 0; i < 8; ++i)
#pragma unroll
    for (int j = 0; j < 8; ++j) acc[i][j] = 0.f;

  const int nkt = (K + 15) >> 4;
  for (int kt = 0; kt < nkt; ++kt) {
    const int k0 = kt << 4;
#pragma unroll
    for (int h = 0; h < 2; ++h) {
      int i = tid + h * 256;
      int m = i >> 2, kk = (i & 3) << 2;
      int gm = row0 + m, gk = k0 + kk;
      float4 v = make_float4(0.f, 0.f, 0.f, 0.f);
      if (gm < M && gk < K) v = *reinterpret_cast<const float4*>(A + (size_t)gm * K + gk);
      As[kk + 0][m] = v.x; As[kk + 1][m] = v.y; As[kk + 2][m] = v.z; As[kk + 3][m] = v.w;
    }
#pragma unroll
    for (int h = 0; h < 2; ++h) {
      int i = tid + h * 256;
      int kk = i >> 5, n = (i & 31) << 2;
      int gk = k0 + kk, gn = col0 + n;
      float4 v = make_float4(0.f, 0.f, 0.f, 0.f);
      if (gk < K && gn < N) v = *reinterpret_cast<const float4*>(B + (size_t)gk * N + gn);
      *reinterpret_cast<float4*>(&Bs[kk][n]) = v;
    }
    __syncthreads();
#pragma unroll
    for (int kk = 0; kk < 16; ++kk) {
      float4 a0 = *reinterpret_cast<const float4*>(&As[kk][ty * 4]);
      float4 a1 = *reinterpret_cast<const float4*>(&As[kk][ty * 4 + 64]);
      float4 b0 = *reinterpret_cast<const float4*>(&Bs[kk][tx * 4]);
      float4 b1 = *reinterpret_cast<const float4*>(&Bs[kk][tx * 4 + 64]);
      float av[8] = {a0.x, a0.y, a0.z, a0.w, a1.x, a1.y, a1.z, a1.w};
      float bv[8] = {b0.x, b0.y, b0.z, b0.w, b1.x, b1.y, b1.z, b1.w};
#pragma unroll
      for (int i = 0; i < 8; ++i)
#pragma unroll
        for (int j = 0; j < 8; ++j) acc[i][j] += av[i] * bv[j];
    }
    __syncthreads();
  }
#pragma unroll
  for (int i = 0; i < 8; ++i) {
    int gm = row0 + ty * 4 + ((i >> 2) << 6) + (i & 3);
    if (gm >= M) continue;
#pragma unroll
    for (int j = 0; j < 8; ++j) {
      int gn = col0 + tx * 4 + ((j >> 2) << 6) + (j & 3);
      if (gn < N) C[(size_t)gm * N + gn] = acc[i][j] + bias[gn];
    }
  }
}

// ------------- wave-per-4-rows LayerNorm (cols=500), f32 in ------------------
template <int ACT, typename TOUT>
__global__ __launch_bounds__(256) void ln_wave4(
    const float* __restrict__ X, TOUT* __restrict__ Y,
    const float* __restrict__ g, const float* __restrict__ b,
    int ldx, int ldy)
{
  int w = threadIdx.x >> 6, lane = threadIdx.x & 63;
  int id0 = (blockIdx.x * 4 + w) * 4;
  int k0 = lane * 8;
  float xv[4][8], s[4], s2[4];
#pragma unroll
  for (int r = 0; r < 4; ++r) {
    const float* x = X + (size_t)(id0 + r) * ldx;
    if (k0 + 8 <= 500) {
      float4 a = *reinterpret_cast<const float4*>(x + k0);
      float4 c = *reinterpret_cast<const float4*>(x + k0 + 4);
      xv[r][0] = a.x; xv[r][1] = a.y; xv[r][2] = a.z; xv[r][3] = a.w;
      xv[r][4] = c.x; xv[r][5] = c.y; xv[r][6] = c.z; xv[r][7] = c.w;
    } else {
#pragma unroll
      for (int e = 0; e < 8; ++e) xv[r][e] = (k0 + e < 500) ? x[k0 + e] : 0.f;
    }
    s[r] = 0.f; s2[r] = 0.f;
#pragma unroll
    for (int e = 0; e < 8; ++e) { s[r] += xv[r][e]; s2[r] += xv[r][e] * xv[r][e]; }
  }
#pragma unroll
  for (int m = 32; m; m >>= 1)
#pragma unroll
    for (int r = 0; r < 4; ++r) {
      s[r] += __shfl_xor(s[r], m);
      s2[r] += __shfl_xor(s2[r], m);
    }
  float gv[8], bv[8];
#pragma unroll
  for (int e = 0; e < 8; ++e) {
    int k = k0 + e;
    gv[e] = (k < 500) ? g[k] : 0.f;
    bv[e] = (k < 500) ? b[k] : 0.f;
  }
#pragma unroll
  for (int r = 0; r < 4; ++r) {
    float mu = s[r] / 500.f;
    float rstd = rsqrtf(s2[r] / 500.f - mu * mu + EPSF);
    float ov[8];
#pragma unroll
    for (int e = 0; e < 8; ++e) {
      float v = (k0 + e < 500) ? ((xv[r][e] - mu) * rstd * gv[e] + bv[e]) : 0.f;
      if (ACT == 1) v = fmaxf(v, 0.f);
      ov[e] = v;
    }
    if constexpr (sizeof(TOUT) == 2) {
      u16x8 o;
#pragma unroll
      for (int e = 0; e < 8; ++e) o[e] = f2bf(ov[e]);
      *reinterpret_cast<u16x8*>((u16*)Y + (size_t)(id0 + r) * ldy + k0) = o;
    } else {
      float* y = (float*)Y + (size_t)(id0 + r) * ldy;
      if (k0 + 4 <= 500)
        *reinterpret_cast<float4*>(y + k0) = make_float4(ov[0], ov[1], ov[2], ov[3]);
      if (k0 + 8 <= 500)
        *reinterpret_cast<float4*>(y + k0 + 4) = make_float4(ov[4], ov[5], ov[6], ov[7]);
    }
  }
}

// ---------------- cat[r] = [bf16(state[r]) | a[r>>4] | 0pad] -----------------
__global__ __launch_bounds__(256) void build_concat(
    const float* __restrict__ state, const u16* __restrict__ a, u16* __restrict__ cat)
{
  int r = blockIdx.x, t = threadIdx.x;
  int b = r >> 4;
  u16* c = cat + (size_t)r * 1024;
  if (t < 125) {
    float4 v = *reinterpret_cast<const float4*>(state + (size_t)r * 500 + t * 4);
    ushort4 o; o.x = f2bf(v.x); o.y = f2bf(v.y); o.z = f2bf(v.z); o.w = f2bf(v.w);
    *reinterpret_cast<ushort4*>(c + t * 4) = o;
    *reinterpret_cast<ushort4*>(c + 500 + t * 4) =
        *reinterpret_cast<const ushort4*>(a + (size_t)b * 512 + t * 4);
  }
  if (t < 24) c[1000 + t] = 0;
}

// ---------------- total[r] = [s1[r] | 0 | bf16(esum[r]) | 0] -----------------
__global__ __launch_bounds__(256) void build_total(
    const u16* __restrict__ s1, const float* __restrict__ esum, u16* __restrict__ tot)
{
  int r = blockIdx.x, t = threadIdx.x;
  u16* c = tot + (size_t)r * 1024;
  if (t < 125) {
    *reinterpret_cast<ushort4*>(c + t * 4) =
        *reinterpret_cast<const ushort4*>(s1 + (size_t)r * 512 + t * 4);
    float4 v = *reinterpret_cast<const float4*>(esum + (size_t)r * 500 + t * 4);
    ushort4 o; o.x = f2bf(v.x); o.y = f2bf(v.y); o.z = f2bf(v.z); o.w = f2bf(v.w);
    *reinterpret_cast<ushort4*>(c + 512 + t * 4) = o;
  }
  if (t < 12) { c[500 + t] = 0; c[1012 + t] = 0; }
}

// -------- att_a: 4 rows per wave ---------------------------------------------
__global__ __launch_bounds__(256) void dot_sig4(
    const u16* __restrict__ cat, const float* __restrict__ w3,
    const float* __restrict__ b3, float* __restrict__ atta)
{
  int w = threadIdx.x >> 6, lane = threadIdx.x & 63;
  int r0 = (blockIdx.x * 4 + w) * 4;
  int k0 = lane * 16;
  float wv[16];
#pragma unroll
  for (int e = 0; e < 16; ++e) wv[e] = (k0 + e < 1000) ? w3[k0 + e] : 0.f;
  float s[4];
#pragma unroll
  for (int r = 0; r < 4; ++r) {
    const u16* x = cat + (size_t)(r0 + r) * 1024 + k0;
    u16x8 u0 = *reinterpret_cast<const u16x8*>(x);
    u16x8 u1 = *reinterpret_cast<const u16x8*>(x + 8);
    float acc = 0.f;
#pragma unroll
    for (int e = 0; e < 8; ++e) acc += bf2f(u0[e]) * wv[e];
#pragma unroll
    for (int e = 0; e < 8; ++e) acc += bf2f(u1[e]) * wv[8 + e];
    s[r] = acc;
  }
#pragma unroll
  for (int m = 32; m; m >>= 1)
#pragma unroll
    for (int r = 0; r < 4; ++r) s[r] += __shfl_xor(s[r], m);
  if (lane == 0) {
#pragma unroll
    for (int r = 0; r < 4; ++r)
      atta[r0 + r] = 1.f / (1.f + expf(-(s[r] + b3[0])));
  }
}

// -------- core rows = relu(LN(P[r1]+Q[r2], ln2)) — 4 rows/wave, bf16 ---------
__global__ __launch_bounds__(256) void core_build3(
    const u16* __restrict__ PQ, u16* __restrict__ core,
    const float* __restrict__ g2, const float* __restrict__ b2, int c0)
{
  int w = threadIdx.x >> 6, lane = threadIdx.x & 63;
  int id0 = (blockIdx.x * 4 + w) * 4;
  int k0 = lane * 8;
  u16x8 up[4], uq[4];
#pragma unroll
  for (int r = 0; r < 4; ++r) {
    int id = id0 + r;
    int pp = id / 15, j = id - pp * 15;
    int gp = c0 + pp, i = gp & 15;
    int col = j + (j >= i);
    int r2 = (gp & ~15) | col;
    up[r] = *reinterpret_cast<const u16x8*>(PQ + (size_t)gp * 1024 + k0);
    uq[r] = *reinterpret_cast<const u16x8*>(PQ + (size_t)r2 * 1024 + 512 + k0);
  }
  float xv[4][8], s[4], s2[4];
#pragma unroll
  for (int r = 0; r < 4; ++r) {
    s[r] = 0.f; s2[r] = 0.f;
#pragma unroll
    for (int e = 0; e < 8; ++e) {
      float v = bf2f(up[r][e]) + bf2f(uq[r][e]);   // pads are exact zeros
      xv[r][e] = v; s[r] += v; s2[r] += v * v;
    }
  }
#pragma unroll
  for (int m = 32; m; m >>= 1)
#pragma unroll
    for (int r = 0; r < 4; ++r) {
      s[r] += __shfl_xor(s[r], m);
      s2[r] += __shfl_xor(s2[r], m);
    }
  float gv[8], bv[8];
#pragma unroll
  for (int e = 0; e < 8; ++e) {
    int k = k0 + e;
    gv[e] = (k < 500) ? g2[k] : 0.f;
    bv[e] = (k < 500) ? b2[k] : 0.f;
  }
#pragma unroll
  for (int r = 0; r < 4; ++r) {
    float mu = s[r] / 500.f;
    float rstd = rsqrtf(s2[r] / 500.f - mu * mu + EPSF);
    u16x8 o;
#pragma unroll
    for (int e = 0; e < 8; ++e)
      o[e] = (k0 + e < 500) ? f2bf(fmaxf((xv[r][e] - mu) * rstd * gv[e] + bv[e], 0.f)) : (u16)0;
    *reinterpret_cast<u16x8*>(core + (size_t)(id0 + r) * 512 + k0) = o;
  }
}

// -------- fused chunk tail: interleaved 4-rows/wave stats, 1 barrier ---------
__global__ __launch_bounds__(256) void chunk_post3(
    const u16* __restrict__ V,
    const float* __restrict__ g3, const float* __restrict__ b3,
    const float* __restrict__ g4, const float* __restrict__ b4,
    const float* __restrict__ w5, const float* __restrict__ b5,
    float* __restrict__ esum, int c0)
{
  __shared__ u16 rows[15][512];
  __shared__ float st[15][4];   // mu, rstd, att
  int pp = blockIdx.x, t = threadIdx.x;
  int lane = t & 63, w = t >> 6;
  int k0 = lane * 8;
  int kk = lane * 2;

  u16x8 u[4]; ushort2 ua[4];
#pragma unroll
  for (int r = 0; r < 4; ++r) {
    int j = w * 4 + r;
    if (j < 15) {
      const u16* vr = V + (size_t)(pp * 15 + j) * 640;
      u[r] = *reinterpret_cast<const u16x8*>(vr + k0);
      ua[r] = *reinterpret_cast<const ushort2*>(vr + 512 + kk);
    }
  }
  float s[4], s2[4], sa[4], sa2[4], y0[4], y1[4];
#pragma unroll
  for (int r = 0; r < 4; ++r) {
    s[r] = s2[r] = sa[r] = sa2[r] = 0.f; y0[r] = y1[r] = 0.f;
    int j = w * 4 + r;
    if (j < 15) {
#pragma unroll
      for (int e = 0; e < 8; ++e) { float v = bf2f(u[r][e]); s[r] += v; s2[r] += v * v; }
      y0[r] = bf2f(ua[r].x); y1[r] = bf2f(ua[r].y);
      sa[r] = y0[r] + y1[r]; sa2[r] = y0[r] * y0[r] + y1[r] * y1[r];
      *reinterpret_cast<u16x8*>(&rows[j][k0]) = u[r];
    }
  }
#pragma unroll
  for (int m = 32; m; m >>= 1)
#pragma unroll
    for (int r = 0; r < 4; ++r) {
      s[r]   += __shfl_xor(s[r], m);
      s2[r]  += __shfl_xor(s2[r], m);
      sa[r]  += __shfl_xor(sa[r], m);
      sa2[r] += __shfl_xor(sa2[r], m);
    }
  float dv[4];
#pragma unroll
  for (int r = 0; r < 4; ++r) {
    float mu4 = sa[r] / 100.f;
    float rstd4 = rsqrtf(sa2[r] / 100.f - mu4 * mu4 + EPSF);
    float d = 0.f;
    if (kk < 100)     d += tanhf((y0[r] - mu4) * rstd4 * g4[kk] + b4[kk]) * w5[kk];
    if (kk + 1 < 100) d += tanhf((y1[r] - mu4) * rstd4 * g4[kk + 1] + b4[kk + 1]) * w5[kk + 1];
    dv[r] = d;
  }
#pragma unroll
  for (int m = 32; m; m >>= 1)
#pragma unroll
    for (int r = 0; r < 4; ++r) dv[r] += __shfl_xor(dv[r], m);
  if (lane == 0) {
#pragma unroll
    for (int r = 0; r < 4; ++r) {
      int j = w * 4 + r;
      if (j < 15) {
        float mu = s[r] / 500.f;
        st[j][0] = mu;
        st[j][1] = rsqrtf(s2[r] / 500.f - mu * mu + EPSF);
        st[j][2] = 1.f / (1.f + expf(-(dv[r] + b5[0])));
      }
    }
  }
  __syncthreads();

  for (int n = t; n < 500; n += 256) {
    float gg = g3[n], bb = b3[n], acc = 0.f;
#pragma unroll
    for (int j = 0; j < 15; ++j) {
      float v = bf2f(rows[j][n]);
      acc += fmaxf((v - st[j][0]) * st[j][1] * gg + bb, 0.f) * st[j][2];
    }
    esum[(size_t)(c0 + pp) * 500 + n] = acc;
  }
}

// -------- merged transpose+pack: all 9 weight jobs in one dispatch -----------
struct TJob {
  const float* src; u16* dst;
  int K, N, srcLd, ldDst, nOff, kOff, tileBase, tilesX;
};
struct TJobs { TJob j[9]; int total; };

__global__ void pack_weights(TJobs jobs)
{
  __shared__ float tl[32][33];
  int bid = blockIdx.x;
  int ji = 0;
#pragma unroll
  for (int q = 1; q < 9; ++q) if (bid >= jobs.j[q].tileBase) ji = q;
  const TJob& J = jobs.j[ji];
  int t = bid - J.tileBase;
  int bx = t % J.tilesX, by = t / J.tilesX;
  int tx = threadIdx.x, ty = threadIdx.y;   // 32 x 8
  int k0 = by * 32, n0 = bx * 32;
#pragma unroll
  for (int r = 0; r < 4; ++r) {
    int row = k0 + ty + r * 8;
    if (row < J.K && n0 + tx < J.N) tl[ty + r * 8][tx] = J.src[(size_t)row * J.srcLd + n0 + tx];
  }
  __syncthreads();
#pragma unroll
  for (int r = 0; r < 4; ++r) {
    int n = n0 + ty + r * 8, k = k0 + tx;
    if (n < J.N && k < J.K)
      J.dst[(size_t)(n + J.nOff) * J.ldDst + J.kOff + k] = f2bf(tl[tx][ty + r * 8]);
  }
}

// -------- pack padded biases --------------------------------------------------
__global__ void pack_biases(
    const float* ac2, const float* lnf2, const float* f1, const float* f2,
    const float* f3, const float* f4, const float* f6,
    float* b_ac2p, float* b_lnf2p, float* b_f1p, float* b2p, float* b34p, float* b_f6p)
{
  int t = threadIdx.x;  // 1024
  switch (blockIdx.x) {
    case 0: if (t < 512) b_ac2p[t]  = (t < 500) ? ac2[t]  : 0.f; break;
    case 1: if (t < 512) b_lnf2p[t] = (t < 500) ? lnf2[t] : 0.f; break;
    case 2: if (t < 512) b_f1p[t]   = (t < 500) ? f1[t]   : 0.f; break;
    case 3: b2p[t] = (t < 500) ? f2[t] : 0.f; break;
    case 4: if (t < 640) b34p[t] = (t < 500) ? f3[t] : ((t >= 512 && t < 612) ? f4[t - 512] : 0.f); break;
    case 5: if (t < 512) b_f6p[t]   = (t < 500) ? f6[t]   : 0.f; break;
  }
}

extern "C" void kernel_launch(void* const* d_in, const int* in_sizes, int n_in,
                              void* d_out, int out_size, void* d_ws, size_t ws_size,
                              hipStream_t stream)
{
  const float* state    = (const float*)d_in[0];
  const float* actions  = (const float*)d_in[1];
  const float* ac_fc1_w = (const float*)d_in[2];
  const float* ac_fc1_b = (const float*)d_in[3];
  const float* ac_ln1_g = (const float*)d_in[4];
  const float* ac_ln1_b = (const float*)d_in[5];
  const float* ac_fc2_w = (const float*)d_in[6];
  const float* ac_fc2_b = (const float*)d_in[7];
  const float* ac_lnf2_w= (const float*)d_in[8];
  const float* ac_lnf2_b= (const float*)d_in[9];
  const float* ac_fc3_w = (const float*)d_in[10];
  const float* ac_fc3_b = (const float*)d_in[11];
  const float* fc1_w = (const float*)d_in[12];
  const float* fc1_b = (const float*)d_in[13];
  const float* ln1_g = (const float*)d_in[14];
  const float* ln1_b = (const float*)d_in[15];
  const float* fc2_w = (const float*)d_in[16];
  const float* fc2_b = (const float*)d_in[17];
  const float* ln2_g = (const float*)d_in[18];
  const float* ln2_b = (const float*)d_in[19];
  const float* fc3_w = (const float*)d_in[20];
  const float* fc3_b = (const float*)d_in[21];
  const float* ln3_g = (const float*)d_in[22];
  const float* ln3_b = (const float*)d_in[23];
  const float* fc4_w = (const float*)d_in[24];
  const float* fc4_b = (const float*)d_in[25];
  const float* ln4_g = (const float*)d_in[26];
  const float* ln4_b = (const float*)d_in[27];
  const float* fc5_w = (const float*)d_in[28];
  const float* fc5_b = (const float*)d_in[29];
  const float* fc6_w = (const float*)d_in[30];
  const float* fc6_b = (const float*)d_in[31];
  const float* ln6_g = (const float*)d_in[32];
  const float* ln6_b = (const float*)d_in[33];
  float* out = (float*)d_out;

  // ---- ws carve (bytes, 256-aligned); total ~171 MB ----
  char* p = (char*)d_ws;
  auto carve = [&](size_t bytes) { char* r = p; p += (bytes + 255) & ~(size_t)255; return r; };
  u16*   cat    = (u16*)  carve(8192ull * 1024 * 2);   // also 'total'
  u16*   t1     = (u16*)  carve(8192ull * 512 * 2);
  u16*   s2     = (u16*)  carve(8192ull * 512 * 2);
  u16*   s1     = (u16*)  carve(8192ull * 512 * 2);
  u16*   core   = (u16*)  carve(30720ull * 512 * 2);
  u16*   v      = (u16*)  carve(30720ull * 640 * 2);
  float* pre    = (float*)carve(8192ull * 512 * 4);
  u16*   PQ     = (u16*)  carve(8192ull * 1024 * 2);
  float* esum   = (float*)carve(8192ull * 500 * 4);
  u16*   a_buf  = (u16*)  carve(512ull * 512 * 2);
  float* tmp_a  = (float*)carve(512ull * 500 * 4);
  float* att_a  = (float*)carve(8192ull * 4);
  char*  wT0    =         carve(0);
  u16*   ac_fc2T  = (u16*)carve(512ull * 1024 * 2);
  u16*   ac_lnf2T = (u16*)carve(512ull * 512 * 2);
  u16*   fc1T     = (u16*)carve(512ull * 512 * 2);
  u16*   B2T      = (u16*)carve(1024ull * 512 * 2);
  u16*   B34T     = (u16*)carve(640ull * 512 * 2);
  u16*   fc6T     = (u16*)carve(512ull * 1024 * 2);
  size_t wTbytes  = (size_t)((char*)carve(0) - wT0);
  float* b_ac2p  = (float*)carve(512 * 4);
  float* b_lnf2p = (float*)carve(512 * 4);
  float* b_f1p   = (float*)carve(512 * 4);
  float* b2p     = (float*)carve(1024 * 4);
  float* b34p    = (float*)carve(640 * 4);
  float* b_f6p   = (float*)carve(512 * 4);

  dim3 blk(256);
  dim3 tblk(32, 8);

  // ---- weight packing: one memset + one merged transpose dispatch ----
  hipMemsetAsync(wT0, 0, wTbytes, stream);
  TJobs jobs;
  int base = 0;
  auto addjob = [&](int idx, const float* src, u16* dst, int K, int N, int srcLd,
                    int ldDst, int nOff, int kOff) {
    int tx = (N + 31) / 32, ty = (K + 31) / 32;
    jobs.j[idx] = {src, dst, K, N, srcLd, ldDst, nOff, kOff, base, tx};
    base += tx * ty;
  };
  addjob(0, ac_fc2_w,         ac_fc2T,  1000, 500, 500, 1024, 0, 0);
  addjob(1, ac_lnf2_w,        ac_lnf2T,  500, 500, 500,  512, 0, 0);
  addjob(2, fc1_w,            fc1T,      500, 500, 500,  512, 0, 0);
  addjob(3, fc2_w,            B2T,       500, 500, 500,  512, 0, 0);
  addjob(4, fc2_w + 250000,   B2T,       500, 500, 500,  512, 512, 0);
  addjob(5, fc3_w,            B34T,      500, 500, 500,  512, 0, 0);
  addjob(6, fc4_w,            B34T,      500, 100, 100,  512, 512, 0);
  addjob(7, fc6_w,            fc6T,      500, 500, 500, 1024, 0, 0);
  addjob(8, fc6_w + 250000,   fc6T,      500, 500, 500, 1024, 0, 512);
  jobs.total = base;
  pack_weights<<<base, tblk, 0, stream>>>(jobs);
  pack_biases<<<6, 1024, 0, stream>>>(ac_fc2_b, ac_lnf2_b, fc1_b, fc2_b, fc3_b, fc4_b, fc6_b,
                                      b_ac2p, b_lnf2p, b_f1p, b2p, b34p, b_f6p);

  // ---- a = LN(actions @ ac_fc1_w + b) ----
  gemm128<<<dim3(4, 4), blk, 0, stream>>>(actions, ac_fc1_w, ac_fc1_b, tmp_a, 512, 500, 64);
  ln_wave4<0, u16><<<32, blk, 0, stream>>>(tmp_a, a_buf, ac_ln1_g, ac_ln1_b, 500, 512);
  build_concat<<<8192, blk, 0, stream>>>(state, a_buf, cat);

  // ---- t1 = cat @ ac_fc2_w + b (bf16); att_a ----
  gemm_mfma<u16><<<dim3(8, 64), blk, 0, stream>>>(cat, ac_fc2T, b_ac2p, nullptr, t1, 8192, 512, 1024);
  dot_sig4<<<512, blk, 0, stream>>>(cat, ac_fc3_w, ac_fc3_b, att_a);
  // ---- s2 = (t1 @ ac_lnf2_w + b) * att_a (bf16) ----
  gemm_mfma<u16><<<dim3(8, 64), blk, 0, stream>>>(t1, ac_lnf2T, b_lnf2p, att_a, s2, 8192, 512, 512);
  // ---- s1 = relu(LN(s2 @ fc1_w + b, ln1)) ----
  gemm_mfma<float><<<dim3(8, 64), blk, 0, stream>>>(s2, fc1T, b_f1p, nullptr, pre, 8192, 512, 512);
  ln_wave4<1, u16><<<512, blk, 0, stream>>>(pre, s1, ln1_g, ln1_b, 512, 512);
  // ---- PQ = s1 @ [fc2_w[:500] | fc2_w[500:]] (bf16) ----
  gemm_mfma<u16><<<dim3(16, 64), blk, 0, stream>>>(s1, B2T, b2p, nullptr, PQ, 8192, 1024, 512);

  for (int c = 0; c < 4; ++c) {
    int c0 = c * 2048;
    core_build3<<<1920, blk, 0, stream>>>(PQ, core, ln2_g, ln2_b, c0);
    gemm_mfma<u16><<<dim3(10, 240), blk, 0, stream>>>(core, B34T, b34p, nullptr, v, 30720, 640, 512);
    chunk_post3<<<2048, blk, 0, stream>>>(v, ln3_g, ln3_b, ln4_g, ln4_b, fc5_w, fc5_b, esum, c0);
  }

  build_total<<<8192, blk, 0, stream>>>(s1, esum, cat);
  gemm_mfma<float><<<dim3(8, 64), blk, 0, stream>>>(cat, fc6T, b_f6p, nullptr, pre, 8192, 512, 1024);
  ln_wave4<0, float><<<512, blk, 0, stream>>>(pre, out, ln6_g, ln6_b, 512, 500);
}

// Round 7
// 428.155 us; speedup vs baseline: 6.0068x; 1.1455x over previous
//
#include <hip/hip_runtime.h>
#include <math.h>

// TheRecurrentNet: B=512, K=16, H=500, A=64, nc=15.
// Round 7: counted-vmcnt GEMM K-loop (loads stay in flight across barriers),
// chunk=4096 (2 iters), esum->bf16 + split-A fc6 (build_total gone),
// bf16 pre-LN buffers. XCD swizzle + LDS XOR-swizzle kept from round 6.

#define EPSF 1e-5f
typedef unsigned short u16;
typedef unsigned int u32;

typedef __bf16 bf16x8 __attribute__((ext_vector_type(8)));
typedef float f32x4 __attribute__((ext_vector_type(4)));
typedef u16 u16x8 __attribute__((ext_vector_type(8)));

__device__ __forceinline__ float bf2f(u16 u) {
  return __builtin_bit_cast(float, (u32)u << 16);
}
__device__ __forceinline__ u16 f2bf(float f) {
  u32 u = __builtin_bit_cast(u32, f);
  return (u16)((u + 0x7FFFu + ((u >> 16) & 1u)) >> 16);   // RNE
}

#define GLOAD16(g, l) __builtin_amdgcn_global_load_lds( \
    (__attribute__((address_space(1))) u32*)(g), \
    (__attribute__((address_space(3))) u32*)(l), 16, 0, 0)

// ======================= bf16 MFMA GEMM, 128x64 tile, BK=64 ==================
// C[M,Npad] = A[M,K] @ Bt[Npad,K]^T + bias, optional *rowscale.
// A rows have leading dim lda. If A2 != nullptr, K-range [khalf,K) reads from
// A2 (same lda) — used to fuse the [s1|esum] concat into the fc6 GEMM.
// Double-buffered LDS, counted vmcnt: next-tile loads stay in flight across
// the barrier (only the current tile's 6 loads are waited). LDS XOR-swizzle:
// 16B-chunk c of row r at slot c^(r&7). XCD-aware col-fast block swizzle.
template <typename TOUT>
__global__ __launch_bounds__(256) void gemm_mfma(
    const u16* __restrict__ A, const u16* __restrict__ A2,
    const u16* __restrict__ Bt,
    const float* __restrict__ bias, const float* __restrict__ rowscale,
    TOUT* __restrict__ C, int M, int Npad, int K, int lda, int khalf)
{
  __shared__ __align__(16) u16 As[2][128 * 64];   // slot = row*8 + chunk (16B chunks)
  __shared__ __align__(16) u16 Bs[2][64 * 64];
  const int tid = threadIdx.x;
  const int lane = tid & 63, wid = tid >> 6;

  // XCD-aware block swizzle (nwg % 8 == 0 at every call site)
  const int ncols = gridDim.x;
  const int nwg = ncols * gridDim.y;
  const int bid = blockIdx.y * ncols + blockIdx.x;
  const int swz = (bid & 7) * (nwg >> 3) + (bid >> 3);
  const size_t row0 = (size_t)(swz / ncols) * 128;
  const size_t col0 = (size_t)(swz % ncols) * 64;

  f32x4 acc[2][4] = {};

  // staging: instr h covers slot s=h*256+tid; row = h*32+(tid>>3);
  // LDS chunk (tid&7) holds data chunk (tid&7)^(row&7)
  const int s_sub = tid >> 3;
  const int s_chunk = (tid & 7) ^ (s_sub & 7);
  const size_t aoff = (row0 + s_sub) * (size_t)lda + s_chunk * 8;
  const u16* gA = A + aoff;
  const u16* gA2 = A2 ? (A2 + aoff - khalf) : nullptr;   // +kk gives A2[(kk-khalf)]
  const u16* gB = Bt + (col0 + s_sub) * (size_t)K + s_chunk * 8;

  // fragment read: row fr, k-chunk fq (ks=0) / 4+fq (ks=1), swizzled by fr&7
  const int fr = lane & 15, fq = lane >> 4;
  const int cx0 = fq ^ (fr & 7);
  const int cx1 = (4 + fq) ^ (fr & 7);

  const int nkt = K >> 6;
  int cur = 0;

  // prologue: stage K-tile 0 into buffer 0
  {
#pragma unroll
    for (int h = 0; h < 4; ++h)
      GLOAD16(gA + (size_t)h * 32 * lda, &As[0][(h * 256 + tid) * 8]);
#pragma unroll
    for (int h = 0; h < 2; ++h)
      GLOAD16(gB + (size_t)h * 32 * K, &Bs[0][(h * 256 + tid) * 8]);
  }

  for (int kt = 0; kt < nkt; ++kt) {
    // issue next tile's 6 loads (they stay in flight across the barrier)
    if (kt + 1 < nkt) {
      const int kk = (kt + 1) * 64;
      const u16* a = (A2 && kk >= khalf) ? (gA2 + kk) : (gA + kk);
      const u16* b = gB + kk;
#pragma unroll
      for (int h = 0; h < 4; ++h)
        GLOAD16(a + (size_t)h * 32 * lda, &As[cur ^ 1][(h * 256 + tid) * 8]);
#pragma unroll
      for (int h = 0; h < 2; ++h)
        GLOAD16(b + (size_t)h * 32 * K, &Bs[cur ^ 1][(h * 256 + tid) * 8]);
      asm volatile("s_waitcnt vmcnt(6)" ::: "memory");   // wait tile kt only
    } else {
      asm volatile("s_waitcnt vmcnt(0)" ::: "memory");   // last tile: drain
    }
    __builtin_amdgcn_sched_barrier(0);
    __builtin_amdgcn_s_barrier();                        // all waves: tile kt ready
    __builtin_amdgcn_sched_barrier(0);

    const u16* as = As[cur];
    const u16* bs = Bs[cur];
#pragma unroll
    for (int ks = 0; ks < 2; ++ks) {
      const int cx = ks ? cx1 : cx0;
      bf16x8 af[2], bf[4];
#pragma unroll
      for (int m = 0; m < 2; ++m) {
        int row = wid * 32 + m * 16 + fr;
        af[m] = *reinterpret_cast<const bf16x8*>(as + (row * 8 + cx) * 8);
      }
#pragma unroll
      for (int n = 0; n < 4; ++n) {
        int row = n * 16 + fr;
        bf[n] = *reinterpret_cast<const bf16x8*>(bs + (row * 8 + cx) * 8);
      }
#pragma unroll
      for (int m = 0; m < 2; ++m)
#pragma unroll
        for (int n = 0; n < 4; ++n)
          acc[m][n] = __builtin_amdgcn_mfma_f32_16x16x32_bf16(af[m], bf[n], acc[m][n], 0, 0, 0);
    }
    asm volatile("s_waitcnt lgkmcnt(0)" ::: "memory");   // ds_reads delivered
    __builtin_amdgcn_sched_barrier(0);
    __builtin_amdgcn_s_barrier();                        // safe to overwrite buf
    __builtin_amdgcn_sched_barrier(0);
    cur ^= 1;
  }

  // epilogue: C/D layout col=lane&15, row=(lane>>4)*4+reg
  const int cl = lane & 15, rg = lane >> 4;
#pragma unroll
  for (int m = 0; m < 2; ++m) {
#pragma unroll
    for (int n = 0; n < 4; ++n) {
      size_t col = col0 + n * 16 + cl;
      float bv = bias[col];
#pragma unroll
      for (int r = 0; r < 4; ++r) {
        size_t row = row0 + wid * 32 + m * 16 + rg * 4 + r;
        float v = acc[m][n][r] + bv;
        if (rowscale) v *= rowscale[row];
        if constexpr (sizeof(TOUT) == 2) C[row * Npad + col] = f2bf(v);
        else                             C[row * Npad + col] = v;
      }
    }
  }
}

// ---------------- small f32 GEMM (actions @ ac_fc1_w) ------------------------
__global__ __launch_bounds__(256) void gemm128(
    const float* __restrict__ A, const float* __restrict__ B,
    const float* __restrict__ bias, float* __restrict__ C, int M, int N, int K)
{
  __shared__ float As[16][132];
  __shared__ float Bs[16][128];
  const int tid = threadIdx.x;
  const int tx = tid & 15, ty = tid >> 4;
  const int row0 = blockIdx.y * 128, col0 = blockIdx.x * 128;
  float acc[8][8];
#pragma unroll
  for (int i = 0; i < 8; ++i)
#pragma unroll
    for (int j = 0; j < 8; ++j) acc[i][j] = 0.f;

  const int nkt = (K + 15) >> 4;
  for (int kt = 0; kt < nkt; ++kt) {
    const int k0 = kt << 4;
#pragma unroll
    for (int h = 0; h < 2; ++h) {
      int i = tid + h * 256;
      int m = i >> 2, kk = (i & 3) << 2;
      int gm = row0 + m, gk = k0 + kk;
      float4 v = make_float4(0.f, 0.f, 0.f, 0.f);
      if (gm < M && gk < K) v = *reinterpret_cast<const float4*>(A + (size_t)gm * K + gk);
      As[kk + 0][m] = v.x; As[kk + 1][m] = v.y; As[kk + 2][m] = v.z; As[kk + 3][m] = v.w;
    }
#pragma unroll
    for (int h = 0; h < 2; ++h) {
      int i = tid + h * 256;
      int kk = i >> 5, n = (i & 31) << 2;
      int gk = k0 + kk, gn = col0 + n;
      float4 v = make_float4(0.f, 0.f, 0.f, 0.f);
      if (gk < K && gn < N) v = *reinterpret_cast<const float4*>(B + (size_t)gk * N + gn);
      *reinterpret_cast<float4*>(&Bs[kk][n]) = v;
    }
    __syncthreads();
#pragma unroll
    for (int kk = 0; kk < 16; ++kk) {
      float4 a0 = *reinterpret_cast<const float4*>(&As[kk][ty * 4]);
      float4 a1 = *reinterpret_cast<const float4*>(&As[kk][ty * 4 + 64]);
      float4 b0 = *reinterpret_cast<const float4*>(&Bs[kk][tx * 4]);
      float4 b1 = *reinterpret_cast<const float4*>(&Bs[kk][tx * 4 + 64]);
      float av[8] = {a0.x, a0.y, a0.z, a0.w, a1.x, a1.y, a1.z, a1.w};
      float bv[8] = {b0.x, b0.y, b0.z, b0.w, b1.x, b1.y, b1.z, b1.w};
#pragma unroll
      for (int i = 0; i < 8; ++i)
#pragma unroll
        for (int j = 0; j < 8; ++j) acc[i][j] += av[i] * bv[j];
    }
    __syncthreads();
  }
#pragma unroll
  for (int i = 0; i < 8; ++i) {
    int gm = row0 + ty * 4 + ((i >> 2) << 6) + (i & 3);
    if (gm >= M) continue;
#pragma unroll
    for (int j = 0; j < 8; ++j) {
      int gn = col0 + tx * 4 + ((j >> 2) << 6) + (j & 3);
      if (gn < N) C[(size_t)gm * N + gn] = acc[i][j] + bias[gn];
    }
  }
}

// ------------- wave-per-4-rows LayerNorm (cols=500) --------------------------
// TIN=u16: ldx must be 512 with zero pads (sums include pads harmlessly).
template <int ACT, typename TIN, typename TOUT>
__global__ __launch_bounds__(256) void ln_wave4(
    const TIN* __restrict__ X, TOUT* __restrict__ Y,
    const float* __restrict__ g, const float* __restrict__ b,
    int ldx, int ldy)
{
  int w = threadIdx.x >> 6, lane = threadIdx.x & 63;
  int id0 = (blockIdx.x * 4 + w) * 4;
  int k0 = lane * 8;
  float xv[4][8], s[4], s2[4];
#pragma unroll
  for (int r = 0; r < 4; ++r) {
    s[r] = 0.f; s2[r] = 0.f;
    if constexpr (sizeof(TIN) == 2) {
      u16x8 u = *reinterpret_cast<const u16x8*>((const u16*)X + (size_t)(id0 + r) * ldx + k0);
#pragma unroll
      for (int e = 0; e < 8; ++e) xv[r][e] = bf2f(u[e]);
    } else {
      const float* x = (const float*)X + (size_t)(id0 + r) * ldx;
      if (k0 + 8 <= 500) {
        float4 a = *reinterpret_cast<const float4*>(x + k0);
        float4 c = *reinterpret_cast<const float4*>(x + k0 + 4);
        xv[r][0] = a.x; xv[r][1] = a.y; xv[r][2] = a.z; xv[r][3] = a.w;
        xv[r][4] = c.x; xv[r][5] = c.y; xv[r][6] = c.z; xv[r][7] = c.w;
      } else {
#pragma unroll
        for (int e = 0; e < 8; ++e) xv[r][e] = (k0 + e < 500) ? x[k0 + e] : 0.f;
      }
    }
#pragma unroll
    for (int e = 0; e < 8; ++e) { s[r] += xv[r][e]; s2[r] += xv[r][e] * xv[r][e]; }
  }
#pragma unroll
  for (int m = 32; m; m >>= 1)
#pragma unroll
    for (int r = 0; r < 4; ++r) {
      s[r] += __shfl_xor(s[r], m);
      s2[r] += __shfl_xor(s2[r], m);
    }
  float gv[8], bv[8];
#pragma unroll
  for (int e = 0; e < 8; ++e) {
    int k = k0 + e;
    gv[e] = (k < 500) ? g[k] : 0.f;
    bv[e] = (k < 500) ? b[k] : 0.f;
  }
#pragma unroll
  for (int r = 0; r < 4; ++r) {
    float mu = s[r] / 500.f;
    float rstd = rsqrtf(s2[r] / 500.f - mu * mu + EPSF);
    float ov[8];
#pragma unroll
    for (int e = 0; e < 8; ++e) {
      float v = (k0 + e < 500) ? ((xv[r][e] - mu) * rstd * gv[e] + bv[e]) : 0.f;
      if (ACT == 1) v = fmaxf(v, 0.f);
      ov[e] = v;
    }
    if constexpr (sizeof(TOUT) == 2) {
      u16x8 o;
#pragma unroll
      for (int e = 0; e < 8; ++e) o[e] = f2bf(ov[e]);
      *reinterpret_cast<u16x8*>((u16*)Y + (size_t)(id0 + r) * ldy + k0) = o;
    } else {
      float* y = (float*)Y + (size_t)(id0 + r) * ldy;
      if (k0 + 4 <= 500)
        *reinterpret_cast<float4*>(y + k0) = make_float4(ov[0], ov[1], ov[2], ov[3]);
      if (k0 + 8 <= 500)
        *reinterpret_cast<float4*>(y + k0 + 4) = make_float4(ov[4], ov[5], ov[6], ov[7]);
    }
  }
}

// ---------------- cat[r] = [bf16(state[r]) | a[r>>4] | 0pad] -----------------
__global__ __launch_bounds__(256) void build_concat(
    const float* __restrict__ state, const u16* __restrict__ a, u16* __restrict__ cat)
{
  int r = blockIdx.x, t = threadIdx.x;
  int b = r >> 4;
  u16* c = cat + (size_t)r * 1024;
  if (t < 125) {
    float4 v = *reinterpret_cast<const float4*>(state + (size_t)r * 500 + t * 4);
    ushort4 o; o.x = f2bf(v.x); o.y = f2bf(v.y); o.z = f2bf(v.z); o.w = f2bf(v.w);
    *reinterpret_cast<ushort4*>(c + t * 4) = o;
    *reinterpret_cast<ushort4*>(c + 500 + t * 4) =
        *reinterpret_cast<const ushort4*>(a + (size_t)b * 512 + t * 4);
  }
  if (t < 24) c[1000 + t] = 0;
}

// -------- att_a: 4 rows per wave ---------------------------------------------
__global__ __launch_bounds__(256) void dot_sig4(
    const u16* __restrict__ cat, const float* __restrict__ w3,
    const float* __restrict__ b3, float* __restrict__ atta)
{
  int w = threadIdx.x >> 6, lane = threadIdx.x & 63;
  int r0 = (blockIdx.x * 4 + w) * 4;
  int k0 = lane * 16;
  float wv[16];
#pragma unroll
  for (int e = 0; e < 16; ++e) wv[e] = (k0 + e < 1000) ? w3[k0 + e] : 0.f;
  float s[4];
#pragma unroll
  for (int r = 0; r < 4; ++r) {
    const u16* x = cat + (size_t)(r0 + r) * 1024 + k0;
    u16x8 u0 = *reinterpret_cast<const u16x8*>(x);
    u16x8 u1 = *reinterpret_cast<const u16x8*>(x + 8);
    float acc = 0.f;
#pragma unroll
    for (int e = 0; e < 8; ++e) acc += bf2f(u0[e]) * wv[e];
#pragma unroll
    for (int e = 0; e < 8; ++e) acc += bf2f(u1[e]) * wv[8 + e];
    s[r] = acc;
  }
#pragma unroll
  for (int m = 32; m; m >>= 1)
#pragma unroll
    for (int r = 0; r < 4; ++r) s[r] += __shfl_xor(s[r], m);
  if (lane == 0) {
#pragma unroll
    for (int r = 0; r < 4; ++r)
      atta[r0 + r] = 1.f / (1.f + expf(-(s[r] + b3[0])));
  }
}

// -------- core rows = relu(LN(P[r1]+Q[r2], ln2)) — 4 rows/wave, bf16 ---------
__global__ __launch_bounds__(256) void core_build3(
    const u16* __restrict__ PQ, u16* __restrict__ core,
    const float* __restrict__ g2, const float* __restrict__ b2, int c0)
{
  int w = threadIdx.x >> 6, lane = threadIdx.x & 63;
  int id0 = (blockIdx.x * 4 + w) * 4;
  int k0 = lane * 8;
  u16x8 up[4], uq[4];
#pragma unroll
  for (int r = 0; r < 4; ++r) {
    int id = id0 + r;
    int pp = id / 15, j = id - pp * 15;
    int gp = c0 + pp, i = gp & 15;
    int col = j + (j >= i);
    int r2 = (gp & ~15) | col;
    up[r] = *reinterpret_cast<const u16x8*>(PQ + (size_t)gp * 1024 + k0);
    uq[r] = *reinterpret_cast<const u16x8*>(PQ + (size_t)r2 * 1024 + 512 + k0);
  }
  float xv[4][8], s[4], s2[4];
#pragma unroll
  for (int r = 0; r < 4; ++r) {
    s[r] = 0.f; s2[r] = 0.f;
#pragma unroll
    for (int e = 0; e < 8; ++e) {
      float v = bf2f(up[r][e]) + bf2f(uq[r][e]);   // pads are exact zeros
      xv[r][e] = v; s[r] += v; s2[r] += v * v;
    }
  }
#pragma unroll
  for (int m = 32; m; m >>= 1)
#pragma unroll
    for (int r = 0; r < 4; ++r) {
      s[r] += __shfl_xor(s[r], m);
      s2[r] += __shfl_xor(s2[r], m);
    }
  float gv[8], bv[8];
#pragma unroll
  for (int e = 0; e < 8; ++e) {
    int k = k0 + e;
    gv[e] = (k < 500) ? g2[k] : 0.f;
    bv[e] = (k < 500) ? b2[k] : 0.f;
  }
#pragma unroll
  for (int r = 0; r < 4; ++r) {
    float mu = s[r] / 500.f;
    float rstd = rsqrtf(s2[r] / 500.f - mu * mu + EPSF);
    u16x8 o;
#pragma unroll
    for (int e = 0; e < 8; ++e)
      o[e] = (k0 + e < 500) ? f2bf(fmaxf((xv[r][e] - mu) * rstd * gv[e] + bv[e], 0.f)) : (u16)0;
    *reinterpret_cast<u16x8*>(core + (size_t)(id0 + r) * 512 + k0) = o;
  }
}

// -------- fused chunk tail -> esum in PADDED BF16 (feeds fc6 split-A) --------
__global__ __launch_bounds__(256) void chunk_post3(
    const u16* __restrict__ V,
    const float* __restrict__ g3, const float* __restrict__ b3,
    const float* __restrict__ g4, const float* __restrict__ b4,
    const float* __restrict__ w5, const float* __restrict__ b5,
    u16* __restrict__ esum16, int c0)
{
  __shared__ u16 rows[15][512];
  __shared__ float st[15][4];   // mu, rstd, att
  int pp = blockIdx.x, t = threadIdx.x;
  int lane = t & 63, w = t >> 6;
  int k0 = lane * 8;
  int kk = lane * 2;

  u16x8 u[4]; ushort2 ua[4];
#pragma unroll
  for (int r = 0; r < 4; ++r) {
    int j = w * 4 + r;
    if (j < 15) {
      const u16* vr = V + (size_t)(pp * 15 + j) * 640;
      u[r] = *reinterpret_cast<const u16x8*>(vr + k0);
      ua[r] = *reinterpret_cast<const ushort2*>(vr + 512 + kk);
    }
  }
  float s[4], s2[4], sa[4], sa2[4], y0[4], y1[4];
#pragma unroll
  for (int r = 0; r < 4; ++r) {
    s[r] = s2[r] = sa[r] = sa2[r] = 0.f; y0[r] = y1[r] = 0.f;
    int j = w * 4 + r;
    if (j < 15) {
#pragma unroll
      for (int e = 0; e < 8; ++e) { float v = bf2f(u[r][e]); s[r] += v; s2[r] += v * v; }
      y0[r] = bf2f(ua[r].x); y1[r] = bf2f(ua[r].y);
      sa[r] = y0[r] + y1[r]; sa2[r] = y0[r] * y0[r] + y1[r] * y1[r];
      *reinterpret_cast<u16x8*>(&rows[j][k0]) = u[r];
    }
  }
#pragma unroll
  for (int m = 32; m; m >>= 1)
#pragma unroll
    for (int r = 0; r < 4; ++r) {
      s[r]   += __shfl_xor(s[r], m);
      s2[r]  += __shfl_xor(s2[r], m);
      sa[r]  += __shfl_xor(sa[r], m);
      sa2[r] += __shfl_xor(sa2[r], m);
    }
  float dv[4];
#pragma unroll
  for (int r = 0; r < 4; ++r) {
    float mu4 = sa[r] / 100.f;
    float rstd4 = rsqrtf(sa2[r] / 100.f - mu4 * mu4 + EPSF);
    float d = 0.f;
    if (kk < 100)     d += tanhf((y0[r] - mu4) * rstd4 * g4[kk] + b4[kk]) * w5[kk];
    if (kk + 1 < 100) d += tanhf((y1[r] - mu4) * rstd4 * g4[kk + 1] + b4[kk + 1]) * w5[kk + 1];
    dv[r] = d;
  }
#pragma unroll
  for (int m = 32; m; m >>= 1)
#pragma unroll
    for (int r = 0; r < 4; ++r) dv[r] += __shfl_xor(dv[r], m);
  if (lane == 0) {
#pragma unroll
    for (int r = 0; r < 4; ++r) {
      int j = w * 4 + r;
      if (j < 15) {
        float mu = s[r] / 500.f;
        st[j][0] = mu;
        st[j][1] = rsqrtf(s2[r] / 500.f - mu * mu + EPSF);
        st[j][2] = 1.f / (1.f + expf(-(dv[r] + b5[0])));
      }
    }
  }
  __syncthreads();

  u16* o = esum16 + (size_t)(c0 + pp) * 512;
  for (int n = t; n < 500; n += 256) {
    float gg = g3[n], bb = b3[n], acc = 0.f;
#pragma unroll
    for (int j = 0; j < 15; ++j) {
      float v = bf2f(rows[j][n]);
      acc += fmaxf((v - st[j][0]) * st[j][1] * gg + bb, 0.f) * st[j][2];
    }
    o[n] = f2bf(acc);
  }
  if (t < 12) o[500 + t] = 0;
}

// -------- merged transpose+pack: all 9 weight jobs in one dispatch -----------
struct TJob {
  const float* src; u16* dst;
  int K, N, srcLd, ldDst, nOff, kOff, tileBase, tilesX;
};
struct TJobs { TJob j[9]; int total; };

__global__ void pack_weights(TJobs jobs)
{
  __shared__ float tl[32][33];
  int bid = blockIdx.x;
  int ji = 0;
#pragma unroll
  for (int q = 1; q < 9; ++q) if (bid >= jobs.j[q].tileBase) ji = q;
  const TJob& J = jobs.j[ji];
  int t = bid - J.tileBase;
  int bx = t % J.tilesX, by = t / J.tilesX;
  int tx = threadIdx.x, ty = threadIdx.y;   // 32 x 8
  int k0 = by * 32, n0 = bx * 32;
#pragma unroll
  for (int r = 0; r < 4; ++r) {
    int row = k0 + ty + r * 8;
    if (row < J.K && n0 + tx < J.N) tl[ty + r * 8][tx] = J.src[(size_t)row * J.srcLd + n0 + tx];
  }
  __syncthreads();
#pragma unroll
  for (int r = 0; r < 4; ++r) {
    int n = n0 + ty + r * 8, k = k0 + tx;
    if (n < J.N && k < J.K)
      J.dst[(size_t)(n + J.nOff) * J.ldDst + J.kOff + k] = f2bf(tl[tx][ty + r * 8]);
  }
}

// -------- pack padded biases --------------------------------------------------
__global__ void pack_biases(
    const float* ac2, const float* lnf2, const float* f1, const float* f2,
    const float* f3, const float* f4, const float* f6,
    float* b_ac2p, float* b_lnf2p, float* b_f1p, float* b2p, float* b34p, float* b_f6p)
{
  int t = threadIdx.x;  // 1024
  switch (blockIdx.x) {
    case 0: if (t < 512) b_ac2p[t]  = (t < 500) ? ac2[t]  : 0.f; break;
    case 1: if (t < 512) b_lnf2p[t] = (t < 500) ? lnf2[t] : 0.f; break;
    case 2: if (t < 512) b_f1p[t]   = (t < 500) ? f1[t]   : 0.f; break;
    case 3: b2p[t] = (t < 500) ? f2[t] : 0.f; break;
    case 4: if (t < 640) b34p[t] = (t < 500) ? f3[t] : ((t >= 512 && t < 612) ? f4[t - 512] : 0.f); break;
    case 5: if (t < 512) b_f6p[t]   = (t < 500) ? f6[t]   : 0.f; break;
  }
}

extern "C" void kernel_launch(void* const* d_in, const int* in_sizes, int n_in,
                              void* d_out, int out_size, void* d_ws, size_t ws_size,
                              hipStream_t stream)
{
  const float* state    = (const float*)d_in[0];
  const float* actions  = (const float*)d_in[1];
  const float* ac_fc1_w = (const float*)d_in[2];
  const float* ac_fc1_b = (const float*)d_in[3];
  const float* ac_ln1_g = (const float*)d_in[4];
  const float* ac_ln1_b = (const float*)d_in[5];
  const float* ac_fc2_w = (const float*)d_in[6];
  const float* ac_fc2_b = (const float*)d_in[7];
  const float* ac_lnf2_w= (const float*)d_in[8];
  const float* ac_lnf2_b= (const float*)d_in[9];
  const float* ac_fc3_w = (const float*)d_in[10];
  const float* ac_fc3_b = (const float*)d_in[11];
  const float* fc1_w = (const float*)d_in[12];
  const float* fc1_b = (const float*)d_in[13];
  const float* ln1_g = (const float*)d_in[14];
  const float* ln1_b = (const float*)d_in[15];
  const float* fc2_w = (const float*)d_in[16];
  const float* fc2_b = (const float*)d_in[17];
  const float* ln2_g = (const float*)d_in[18];
  const float* ln2_b = (const float*)d_in[19];
  const float* fc3_w = (const float*)d_in[20];
  const float* fc3_b = (const float*)d_in[21];
  const float* ln3_g = (const float*)d_in[22];
  const float* ln3_b = (const float*)d_in[23];
  const float* fc4_w = (const float*)d_in[24];
  const float* fc4_b = (const float*)d_in[25];
  const float* ln4_g = (const float*)d_in[26];
  const float* ln4_b = (const float*)d_in[27];
  const float* fc5_w = (const float*)d_in[28];
  const float* fc5_b = (const float*)d_in[29];
  const float* fc6_w = (const float*)d_in[30];
  const float* fc6_b = (const float*)d_in[31];
  const float* ln6_g = (const float*)d_in[32];
  const float* ln6_b = (const float*)d_in[33];
  float* out = (float*)d_out;

  // ---- ws carve (bytes, 256-aligned); total ~215 MB ----
  char* p = (char*)d_ws;
  auto carve = [&](size_t bytes) { char* r = p; p += (bytes + 255) & ~(size_t)255; return r; };
  u16*   cat    = (u16*)  carve(8192ull * 1024 * 2);
  u16*   t1     = (u16*)  carve(8192ull * 512 * 2);    // ac_fc2 out, later fc1/fc6 pre-LN
  u16*   s2     = (u16*)  carve(8192ull * 512 * 2);
  u16*   s1     = (u16*)  carve(8192ull * 512 * 2);
  u16*   core   = (u16*)  carve(61440ull * 512 * 2);
  u16*   v      = (u16*)  carve(61440ull * 640 * 2);
  u16*   PQ     = (u16*)  carve(8192ull * 1024 * 2);
  u16*   esum16 = (u16*)  carve(8192ull * 512 * 2);
  u16*   a_buf  = (u16*)  carve(512ull * 512 * 2);
  float* tmp_a  = (float*)carve(512ull * 500 * 4);
  float* att_a  = (float*)carve(8192ull * 4);
  char*  wT0    =         carve(0);
  u16*   ac_fc2T  = (u16*)carve(512ull * 1024 * 2);
  u16*   ac_lnf2T = (u16*)carve(512ull * 512 * 2);
  u16*   fc1T     = (u16*)carve(512ull * 512 * 2);
  u16*   B2T      = (u16*)carve(1024ull * 512 * 2);
  u16*   B34T     = (u16*)carve(640ull * 512 * 2);
  u16*   fc6T     = (u16*)carve(512ull * 1024 * 2);
  size_t wTbytes  = (size_t)((char*)carve(0) - wT0);
  float* b_ac2p  = (float*)carve(512 * 4);
  float* b_lnf2p = (float*)carve(512 * 4);
  float* b_f1p   = (float*)carve(512 * 4);
  float* b2p     = (float*)carve(1024 * 4);
  float* b34p    = (float*)carve(640 * 4);
  float* b_f6p   = (float*)carve(512 * 4);

  dim3 blk(256);
  dim3 tblk(32, 8);

  // ---- weight packing: one memset + one merged transpose dispatch ----
  hipMemsetAsync(wT0, 0, wTbytes, stream);
  TJobs jobs;
  int base = 0;
  auto addjob = [&](int idx, const float* src, u16* dst, int K, int N, int srcLd,
                    int ldDst, int nOff, int kOff) {
    int tx = (N + 31) / 32, ty = (K + 31) / 32;
    jobs.j[idx] = {src, dst, K, N, srcLd, ldDst, nOff, kOff, base, tx};
    base += tx * ty;
  };
  addjob(0, ac_fc2_w,         ac_fc2T,  1000, 500, 500, 1024, 0, 0);
  addjob(1, ac_lnf2_w,        ac_lnf2T,  500, 500, 500,  512, 0, 0);
  addjob(2, fc1_w,            fc1T,      500, 500, 500,  512, 0, 0);
  addjob(3, fc2_w,            B2T,       500, 500, 500,  512, 0, 0);
  addjob(4, fc2_w + 250000,   B2T,       500, 500, 500,  512, 512, 0);
  addjob(5, fc3_w,            B34T,      500, 500, 500,  512, 0, 0);
  addjob(6, fc4_w,            B34T,      500, 100, 100,  512, 512, 0);
  addjob(7, fc6_w,            fc6T,      500, 500, 500, 1024, 0, 0);
  addjob(8, fc6_w + 250000,   fc6T,      500, 500, 500, 1024, 0, 512);
  jobs.total = base;
  pack_weights<<<base, tblk, 0, stream>>>(jobs);
  pack_biases<<<6, 1024, 0, stream>>>(ac_fc2_b, ac_lnf2_b, fc1_b, fc2_b, fc3_b, fc4_b, fc6_b,
                                      b_ac2p, b_lnf2p, b_f1p, b2p, b34p, b_f6p);

  // ---- a = LN(actions @ ac_fc1_w + b) ----
  gemm128<<<dim3(4, 4), blk, 0, stream>>>(actions, ac_fc1_w, ac_fc1_b, tmp_a, 512, 500, 64);
  ln_wave4<0, float, u16><<<32, blk, 0, stream>>>(tmp_a, a_buf, ac_ln1_g, ac_ln1_b, 500, 512);
  build_concat<<<8192, blk, 0, stream>>>(state, a_buf, cat);

  // ---- t1 = cat @ ac_fc2_w + b (bf16); att_a ----
  gemm_mfma<u16><<<dim3(8, 64), blk, 0, stream>>>(cat, nullptr, ac_fc2T, b_ac2p, nullptr,
                                                  t1, 8192, 512, 1024, 1024, 0);
  dot_sig4<<<512, blk, 0, stream>>>(cat, ac_fc3_w, ac_fc3_b, att_a);
  // ---- s2 = (t1 @ ac_lnf2_w + b) * att_a ----
  gemm_mfma<u16><<<dim3(8, 64), blk, 0, stream>>>(t1, nullptr, ac_lnf2T, b_lnf2p, att_a,
                                                  s2, 8192, 512, 512, 512, 0);
  // ---- s1 = relu(LN(s2 @ fc1_w + b, ln1)); pre-LN in bf16 (t1 reused) ----
  gemm_mfma<u16><<<dim3(8, 64), blk, 0, stream>>>(s2, nullptr, fc1T, b_f1p, nullptr,
                                                  t1, 8192, 512, 512, 512, 0);
  ln_wave4<1, u16, u16><<<512, blk, 0, stream>>>(t1, s1, ln1_g, ln1_b, 512, 512);
  // ---- PQ = s1 @ [fc2_w[:500] | fc2_w[500:]] (bf16) ----
  gemm_mfma<u16><<<dim3(16, 64), blk, 0, stream>>>(s1, nullptr, B2T, b2p, nullptr,
                                                   PQ, 8192, 1024, 512, 512, 0);

  for (int c = 0; c < 2; ++c) {
    int c0 = c * 4096;
    core_build3<<<3840, blk, 0, stream>>>(PQ, core, ln2_g, ln2_b, c0);
    gemm_mfma<u16><<<dim3(10, 480), blk, 0, stream>>>(core, nullptr, B34T, b34p, nullptr,
                                                      v, 61440, 640, 512, 512, 0);
    chunk_post3<<<4096, blk, 0, stream>>>(v, ln3_g, ln3_b, ln4_g, ln4_b, fc5_w, fc5_b,
                                          esum16, c0);
  }

  // ---- h = LN([s1 | esum] @ fc6_w + b, ln6) — split-A GEMM, no concat ----
  gemm_mfma<u16><<<dim3(8, 64), blk, 0, stream>>>(s1, esum16, fc6T, b_f6p, nullptr,
                                                  t1, 8192, 512, 1024, 512, 512);
  ln_wave4<0, u16, float><<<512, blk, 0, stream>>>(t1, out, ln6_g, ln6_b, 512, 500);
}